// Round 1
// 1079.293 us; speedup vs baseline: 1.0256x; 1.0256x over previous
//
#include <hip/hip_runtime.h>
#include <math.h>

// ---------------------------------------------------------------------------
// TransformerBlock: x + attn(LN1(x)) -> x1 ; x1 + top2-MoE(LN2(x1)) ; aux loss
// R3: k_flash LDS bank-conflict fix (SQ_LDS_BANK_CONFLICT was 3.3e7 =~26% of
// CU-cycles) via XOR swizzle el = row*64 + (col ^ (((row^(row>>3))&7)<<3))
// applied to BOTH sides of every flash LDS tile (Q/K/V/P). Combined
// (row ^ row>>3) term makes the V-transpose scalar writes (d&7 uniform,
// d>>3 lane-varying) AND the 128B-stride fragment reads conflict-free.
// Also: P tiles aliased onto the (read-once) Q tiles -> LDS 64KB -> 48KB,
// 2 -> 3 blocks/CU.
// ---------------------------------------------------------------------------

typedef __bf16 bf16;
typedef __bf16 bf16x8 __attribute__((ext_vector_type(8)));
typedef float  f32x4  __attribute__((ext_vector_type(4)));

#define D_MODEL 1024
#define SEQ     1024
#define NTOK    4096
#define DFF     4096
#define NEXP    8

__device__ __forceinline__ f32x4 mfma16(bf16x8 a, bf16x8 b, f32x4 c) {
  return __builtin_amdgcn_mfma_f32_16x16x32_bf16(a, b, c, 0, 0, 0);
}

__device__ __forceinline__ void async_cp16(void* lds, const void* g) {
  __builtin_amdgcn_global_load_lds(
      (__attribute__((address_space(1))) void*)(void*)g,
      (__attribute__((address_space(3))) void*)lds, 16, 0, 0);
}

// Bank-conflict-free index into a [R][64] bf16 LDS tile. XOR of element bits
// 3..5 (byte bits 4..6) with (row ^ row>>3): spreads both the fragment reads
// (row varies per lane, col-block uniform) and the V-transpose writes
// (row&7 uniform, row>>3 per-lane) across all 32 banks. Preserves 16B blocks.
__device__ __forceinline__ int swz(int row, int col) {
  return row * 64 + (col ^ (((row ^ (row >> 3)) & 7) << 3));
}

// ---------------------------------------------------------------------------
// Shared MFMA GEMM core: C[128x128] tile, A [M][K] rows via per-lane offsets,
// B stored transposed [N][K]. SPLIT => 3 phases (Ah*Bh, Al*Bh, Ah*Bl).
// (BK=32 => 64B LDS rows: fragment reads are already conflict-free here.)
// ---------------------------------------------------------------------------
template<bool SPLIT>
__device__ __forceinline__ void gemm_core(
    const bf16* __restrict__ Ahi, const bf16* __restrict__ Alo,
    const bf16* __restrict__ Bhi, const bf16* __restrict__ Blo,
    long aOff0, long aOff1, long bOff0, long bOff1,
    int K, bf16* As, bf16* Bs, f32x4 acc[4][4])
{
  const int tid  = threadIdx.x;
  const int lane = tid & 63, w = tid >> 6;
  const int fr   = lane & 15, quad = lane >> 4;
  const int wm   = w >> 1,    wn   = w & 1;
  bf16* AsD0 = As + (w * 16) * 32;
  bf16* AsD1 = As + (64 + w * 16) * 32;
  bf16* BsD0 = Bs + (w * 16) * 32;
  bf16* BsD1 = Bs + (64 + w * 16) * 32;
  const int nph = SPLIT ? 3 : 1;
  for (int ph = 0; ph < nph; ++ph) {
    const bf16* Ap = (ph == 1) ? Alo : Ahi;
    const bf16* Bp = (ph == 2) ? Blo : Bhi;
    for (int k0 = 0; k0 < K; k0 += 32) {
      async_cp16(AsD0, Ap + aOff0 + k0);
      async_cp16(AsD1, Ap + aOff1 + k0);
      async_cp16(BsD0, Bp + bOff0 + k0);
      async_cp16(BsD1, Bp + bOff1 + k0);
      __syncthreads();
      bf16x8 af[4], bfv[4];
#pragma unroll
      for (int mi = 0; mi < 4; ++mi)
        af[mi] = *(const bf16x8*)&As[(wm * 64 + mi * 16 + fr) * 32 + quad * 8];
#pragma unroll
      for (int ni = 0; ni < 4; ++ni)
        bfv[ni] = *(const bf16x8*)&Bs[(wn * 64 + ni * 16 + fr) * 32 + quad * 8];
#pragma unroll
      for (int mi = 0; mi < 4; ++mi)
#pragma unroll
        for (int ni = 0; ni < 4; ++ni)
          acc[mi][ni] = mfma16(af[mi], bfv[ni], acc[mi][ni]);
      __syncthreads();
    }
  }
}

// ---------------------------------------------------------------------------
// Weight transpose + fp32->bf16(hi[,lo]) cast: in [Z][K][N] -> out [Z][N][K]
// ---------------------------------------------------------------------------
__global__ void k_transpose_cast(const float* __restrict__ in,
                                 bf16* __restrict__ oh, bf16* __restrict__ ol,
                                 int K, int N)
{
  const long zo = (long)blockIdx.z * K * N;
  __shared__ float tile[32][33];
  const int tx = threadIdx.x & 31, ty = threadIdx.x >> 5;
  const int r0 = blockIdx.y * 32, c0 = blockIdx.x * 32;
#pragma unroll
  for (int j = 0; j < 4; ++j)
    tile[ty + 8 * j][tx] = in[zo + (long)(r0 + ty + 8 * j) * N + (c0 + tx)];
  __syncthreads();
#pragma unroll
  for (int j = 0; j < 4; ++j) {
    float v = tile[tx][ty + 8 * j];
    long  o = zo + (long)(c0 + ty + 8 * j) * K + (r0 + tx);
    bf16 hh = (bf16)v;
    oh[o] = hh;
    if (ol) ol[o] = (bf16)(v - (float)hh);
  }
}

// ---------------------------------------------------------------------------
// LayerNorm: one block per token, writes bf16 hi (and lo if non-null)
// ---------------------------------------------------------------------------
__global__ __launch_bounds__(256) void k_layernorm(
    const float* __restrict__ x, const float* __restrict__ g,
    const float* __restrict__ b, bf16* __restrict__ oh, bf16* __restrict__ ol)
{
  const int tok = blockIdx.x, tid = threadIdx.x;
  const float4 v = ((const float4*)(x + (long)tok * D_MODEL))[tid];
  float s  = v.x + v.y + v.z + v.w;
  float s2 = v.x * v.x + v.y * v.y + v.z * v.z + v.w * v.w;
#pragma unroll
  for (int off = 1; off < 64; off <<= 1) {
    s  += __shfl_xor(s, off);
    s2 += __shfl_xor(s2, off);
  }
  __shared__ float red[8];
  if ((tid & 63) == 0) { red[tid >> 6] = s; red[4 + (tid >> 6)] = s2; }
  __syncthreads();
  s  = red[0] + red[1] + red[2] + red[3];
  s2 = red[4] + red[5] + red[6] + red[7];
  const float mu   = s * (1.0f / D_MODEL);
  const float var  = s2 * (1.0f / D_MODEL) - mu * mu;
  const float rstd = 1.0f / sqrtf(var + 1e-5f);
  const float4 gg = ((const float4*)g)[tid];
  const float4 bb = ((const float4*)b)[tid];
  float o0 = (v.x - mu) * rstd * gg.x + bb.x;
  float o1 = (v.y - mu) * rstd * gg.y + bb.y;
  float o2 = (v.z - mu) * rstd * gg.z + bb.z;
  float o3 = (v.w - mu) * rstd * gg.w + bb.w;
  const long base = (long)tok * D_MODEL + tid * 4;
  bf16 h0 = (bf16)o0, h1 = (bf16)o1, h2 = (bf16)o2, h3 = (bf16)o3;
  oh[base + 0] = h0; oh[base + 1] = h1; oh[base + 2] = h2; oh[base + 3] = h3;
  if (ol) {
    ol[base + 0] = (bf16)(o0 - (float)h0);
    ol[base + 1] = (bf16)(o1 - (float)h1);
    ol[base + 2] = (bf16)(o2 - (float)h2);
    ol[base + 3] = (bf16)(o3 - (float)h3);
  }
}

// ---------------------------------------------------------------------------
// QKV GEMM (split): ln1[4096][1024] @ wqkvT -> qkv fp32 [4096][3072]
// ---------------------------------------------------------------------------
__global__ __launch_bounds__(256, 2) void k_gemm_qkv(
    const bf16* __restrict__ Ah, const bf16* __restrict__ Al,
    const bf16* __restrict__ Bh, const bf16* __restrict__ Bl,
    float* __restrict__ out)
{
  __shared__ __align__(16) bf16 As[128 * 32];
  __shared__ __align__(16) bf16 Bs[128 * 32];
  const int tid = threadIdx.x, lane = tid & 63, w = tid >> 6;
  const int fr = lane & 15, quad = lane >> 4;
  const int wm = w >> 1, wn = w & 1;
  const int m0 = blockIdx.y * 128, n0 = blockIdx.x * 128;
  const int lrow = w * 16 + (lane >> 2), colk = (lane & 3) * 8;
  long aOff0 = (long)(m0 + lrow) * D_MODEL + colk;
  long aOff1 = aOff0 + 64L * D_MODEL;
  long bOff0 = (long)(n0 + lrow) * D_MODEL + colk;
  long bOff1 = bOff0 + 64L * D_MODEL;
  f32x4 acc[4][4];
  f32x4 zv = {0.f, 0.f, 0.f, 0.f};
#pragma unroll
  for (int i = 0; i < 4; ++i)
#pragma unroll
    for (int j = 0; j < 4; ++j) acc[i][j] = zv;
  gemm_core<true>(Ah, Al, Bh, Bl, aOff0, aOff1, bOff0, bOff1, D_MODEL, As, Bs, acc);
#pragma unroll
  for (int mi = 0; mi < 4; ++mi)
#pragma unroll
    for (int ni = 0; ni < 4; ++ni) {
      const int col = n0 + wn * 64 + ni * 16 + fr;
#pragma unroll
      for (int r = 0; r < 4; ++r) {
        const int row = m0 + wm * 64 + mi * 16 + quad * 4 + r;
        out[(long)row * 3072 + col] = acc[mi][ni][r];
      }
    }
}

// ---------------------------------------------------------------------------
// RoPE + layout: qkv fp32 [tok][3072] -> q,k (rotated), v ; split hi/lo,
// head-major [bh][t][64]
// ---------------------------------------------------------------------------
__global__ __launch_bounds__(256) void k_rope(
    const float* __restrict__ qkv,
    bf16* __restrict__ qh, bf16* __restrict__ ql,
    bf16* __restrict__ kh, bf16* __restrict__ kl,
    bf16* __restrict__ vh, bf16* __restrict__ vl)
{
  const int tok = blockIdx.x;
  const int t = tok & (SEQ - 1), bb = tok >> 10;
  const int tid = threadIdx.x;
  const float ft = (float)t;
  for (int it = tid; it < 512; it += 256) {
    const int hh = it >> 5, i = it & 31;
    const float inv = powf(10000.0f, -(float)i * (1.0f / 32.0f));
    const float ang = ft * inv;
    float sn, cs;
    sincosf(ang, &sn, &cs);
    const long src = (long)tok * 3072 + hh * 64 + i;
    const float q0 = qkv[src], q1 = qkv[src + 32];
    const float k0 = qkv[src + 1024], k1 = qkv[src + 1024 + 32];
    const float qo0 = q0 * cs - q1 * sn, qo1 = q1 * cs + q0 * sn;
    const float ko0 = k0 * cs - k1 * sn, ko1 = k1 * cs + k0 * sn;
    const long dst = ((long)(bb * 16 + hh) * SEQ + t) * 64 + i;
    bf16 x;
    x = (bf16)qo0; qh[dst] = x;      ql[dst] = (bf16)(qo0 - (float)x);
    x = (bf16)qo1; qh[dst + 32] = x; ql[dst + 32] = (bf16)(qo1 - (float)x);
    x = (bf16)ko0; kh[dst] = x;      kl[dst] = (bf16)(ko0 - (float)x);
    x = (bf16)ko1; kh[dst + 32] = x; kl[dst + 32] = (bf16)(ko1 - (float)x);
  }
  for (int it = tid; it < 1024; it += 256) {
    const int hh = it >> 6, d = it & 63;
    const float vv = qkv[(long)tok * 3072 + 2048 + it];
    const long dst = ((long)(bb * 16 + hh) * SEQ + t) * 64 + d;
    bf16 x = (bf16)vv;
    vh[dst] = x; vl[dst] = (bf16)(vv - (float)x);
  }
}

// ---------------------------------------------------------------------------
// Flash attention (causal), split-precision QK^T and PV. Block = 64 q-rows.
// All LDS tiles XOR-swizzled (see swz()); P tiles alias the read-once Q tiles
// => 48KB LDS, 3 blocks/CU.
// ---------------------------------------------------------------------------
__global__ __launch_bounds__(256, 3) void k_flash(
    const bf16* __restrict__ qh, const bf16* __restrict__ ql,
    const bf16* __restrict__ kh, const bf16* __restrict__ kl,
    const bf16* __restrict__ vh, const bf16* __restrict__ vl,
    bf16* __restrict__ oh, bf16* __restrict__ ol)
{
  const int qt = blockIdx.x, bhid = blockIdx.y;
  const int tid = threadIdx.x, lane = tid & 63, w = tid >> 6;
  const int fr = lane & 15, quad = lane >> 4;
  // QP0/QP1 hold Q hi/lo during init (read once into regs), then act as the
  // per-wave P hi/lo buffers (wave w uses [w*1024 .. w*1024+1023]).
  __shared__ __align__(16) bf16 QP0[64 * 64];
  __shared__ __align__(16) bf16 QP1[64 * 64];
  __shared__ __align__(16) bf16 Kh[64 * 64], Kl[64 * 64];
  __shared__ __align__(16) bf16 Vh[64 * 64], Vl[64 * 64];

  const long qbase = ((long)bhid * SEQ + qt * 64) * 64;
  for (int c = tid; c < 512; c += 256) {
    const int row = c >> 3, c8 = (c & 7) << 3;
    *(uint4*)&QP0[swz(row, c8)] = *(const uint4*)&qh[qbase + row * 64 + c8];
    *(uint4*)&QP1[swz(row, c8)] = *(const uint4*)&ql[qbase + row * 64 + c8];
  }
  __syncthreads();
  bf16x8 aQh[2], aQl[2];
#pragma unroll
  for (int kk = 0; kk < 2; ++kk) {
    aQh[kk] = *(const bf16x8*)&QP0[swz(w * 16 + fr, kk * 32 + quad * 8)];
    aQl[kk] = *(const bf16x8*)&QP1[swz(w * 16 + fr, kk * 32 + quad * 8)];
  }
  f32x4 o[4];
  f32x4 zv = {0.f, 0.f, 0.f, 0.f};
#pragma unroll
  for (int ct = 0; ct < 4; ++ct) o[ct] = zv;
  float m_r[4], l_r[4];
#pragma unroll
  for (int r = 0; r < 4; ++r) { m_r[r] = -1e30f; l_r[r] = 0.f; }

  for (int kt = 0; kt <= qt; ++kt) {
    __syncthreads();
    const long kbase = ((long)bhid * SEQ + kt * 64) * 64;
    for (int c = tid; c < 512; c += 256) {
      const int row = c >> 3, c8 = (c & 7) << 3;
      *(uint4*)&Kh[swz(row, c8)] = *(const uint4*)&kh[kbase + row * 64 + c8];
      *(uint4*)&Kl[swz(row, c8)] = *(const uint4*)&kl[kbase + row * 64 + c8];
      uint4 uh = *(const uint4*)&vh[kbase + row * 64 + c8];
      uint4 ul = *(const uint4*)&vl[kbase + row * 64 + c8];
      const bf16* vph = (const bf16*)&uh;
      const bf16* vpl = (const bf16*)&ul;
#pragma unroll
      for (int j = 0; j < 8; ++j) {   // transpose V into [d][key], swizzled
        Vh[swz(c8 + j, row)] = vph[j];
        Vl[swz(c8 + j, row)] = vpl[j];
      }
    }
    __syncthreads();

    f32x4 s[4];
#pragma unroll
    for (int nt = 0; nt < 4; ++nt) s[nt] = zv;
#pragma unroll
    for (int nt = 0; nt < 4; ++nt)
#pragma unroll
      for (int kk = 0; kk < 2; ++kk) {
        bf16x8 bh8 = *(const bf16x8*)&Kh[swz(nt * 16 + fr, kk * 32 + quad * 8)];
        bf16x8 bl8 = *(const bf16x8*)&Kl[swz(nt * 16 + fr, kk * 32 + quad * 8)];
        s[nt] = mfma16(aQh[kk], bh8, s[nt]);
        s[nt] = mfma16(aQl[kk], bh8, s[nt]);
        s[nt] = mfma16(aQh[kk], bl8, s[nt]);
      }
    const int qloc = w * 16 + quad * 4;  // + r
#pragma unroll
    for (int nt = 0; nt < 4; ++nt)
#pragma unroll
      for (int r = 0; r < 4; ++r) {
        float sv = s[nt][r] * 0.125f;
        if (kt == qt && (nt * 16 + fr) > (qloc + r)) sv = -1e30f;
        s[nt][r] = sv;
      }
    float al4[4];
#pragma unroll
    for (int r = 0; r < 4; ++r) {
      float m = fmaxf(fmaxf(s[0][r], s[1][r]), fmaxf(s[2][r], s[3][r]));
#pragma unroll
      for (int off = 1; off < 16; off <<= 1) m = fmaxf(m, __shfl_xor(m, off));
      const float mn = fmaxf(m_r[r], m);
      al4[r] = expf(m_r[r] - mn);
      m_r[r] = mn;
    }
    float pmat[4][4], ls4[4];
#pragma unroll
    for (int r = 0; r < 4; ++r) ls4[r] = 0.f;
#pragma unroll
    for (int nt = 0; nt < 4; ++nt)
#pragma unroll
      for (int r = 0; r < 4; ++r) {
        const float p = expf(s[nt][r] - m_r[r]);
        pmat[nt][r] = p;
        ls4[r] += p;
      }
#pragma unroll
    for (int r = 0; r < 4; ++r) {
      float l = ls4[r];
#pragma unroll
      for (int off = 1; off < 16; off <<= 1) l += __shfl_xor(l, off);
      l_r[r] = l_r[r] * al4[r] + l;
      o[0][r] *= al4[r]; o[1][r] *= al4[r]; o[2][r] *= al4[r]; o[3][r] *= al4[r];
    }
    bf16* Pw0 = QP0 + w * 1024;
    bf16* Pw1 = QP1 + w * 1024;
#pragma unroll
    for (int nt = 0; nt < 4; ++nt)
#pragma unroll
      for (int r = 0; r < 4; ++r) {
        const float p = pmat[nt][r];
        bf16 hh2 = (bf16)p;
        Pw0[swz(quad * 4 + r, nt * 16 + fr)] = hh2;
        Pw1[swz(quad * 4 + r, nt * 16 + fr)] = (bf16)(p - (float)hh2);
      }
    __syncthreads();
#pragma unroll
    for (int kk = 0; kk < 2; ++kk) {
      bf16x8 aPh = *(const bf16x8*)&Pw0[swz(fr, kk * 32 + quad * 8)];
      bf16x8 aPl = *(const bf16x8*)&Pw1[swz(fr, kk * 32 + quad * 8)];
#pragma unroll
      for (int ct = 0; ct < 4; ++ct) {
        bf16x8 bVh = *(const bf16x8*)&Vh[swz(ct * 16 + fr, kk * 32 + quad * 8)];
        bf16x8 bVl = *(const bf16x8*)&Vl[swz(ct * 16 + fr, kk * 32 + quad * 8)];
        o[ct] = mfma16(aPh, bVh, o[ct]);
        o[ct] = mfma16(aPl, bVh, o[ct]);
        o[ct] = mfma16(aPh, bVl, o[ct]);
      }
    }
  }
  const int b_ = bhid >> 4, h_ = bhid & 15;
#pragma unroll
  for (int ct = 0; ct < 4; ++ct)
#pragma unroll
    for (int r = 0; r < 4; ++r) {
      const int tokn = b_ * SEQ + qt * 64 + w * 16 + quad * 4 + r;
      const int col = h_ * 64 + ct * 16 + fr;
      const float val = o[ct][r] / l_r[r];
      bf16 hh3 = (bf16)val;
      oh[(long)tokn * D_MODEL + col] = hh3;
      ol[(long)tokn * D_MODEL + col] = (bf16)(val - (float)hh3);
    }
}

// ---------------------------------------------------------------------------
// Proj GEMM (split) + bias + residual -> d_out fp32 (= x1)
// ---------------------------------------------------------------------------
__global__ __launch_bounds__(256, 2) void k_gemm_proj(
    const bf16* __restrict__ Ah, const bf16* __restrict__ Al,
    const bf16* __restrict__ Bh, const bf16* __restrict__ Bl,
    const float* __restrict__ bproj, const float* __restrict__ xin,
    float* __restrict__ out)
{
  __shared__ __align__(16) bf16 As[128 * 32];
  __shared__ __align__(16) bf16 Bs[128 * 32];
  const int tid = threadIdx.x, lane = tid & 63, w = tid >> 6;
  const int fr = lane & 15, quad = lane >> 4;
  const int wm = w >> 1, wn = w & 1;
  const int m0 = blockIdx.y * 128, n0 = blockIdx.x * 128;
  const int lrow = w * 16 + (lane >> 2), colk = (lane & 3) * 8;
  long aOff0 = (long)(m0 + lrow) * D_MODEL + colk;
  long aOff1 = aOff0 + 64L * D_MODEL;
  long bOff0 = (long)(n0 + lrow) * D_MODEL + colk;
  long bOff1 = bOff0 + 64L * D_MODEL;
  f32x4 acc[4][4];
  f32x4 zv = {0.f, 0.f, 0.f, 0.f};
#pragma unroll
  for (int i = 0; i < 4; ++i)
#pragma unroll
    for (int j = 0; j < 4; ++j) acc[i][j] = zv;
  gemm_core<true>(Ah, Al, Bh, Bl, aOff0, aOff1, bOff0, bOff1, D_MODEL, As, Bs, acc);
#pragma unroll
  for (int mi = 0; mi < 4; ++mi)
#pragma unroll
    for (int ni = 0; ni < 4; ++ni) {
      const int col = n0 + wn * 64 + ni * 16 + fr;
#pragma unroll
      for (int r = 0; r < 4; ++r) {
        const int row = m0 + wm * 64 + mi * 16 + quad * 4 + r;
        out[(long)row * D_MODEL + col] =
            acc[mi][ni][r] + bproj[col] + xin[(long)row * D_MODEL + col];
      }
    }
}

// ---------------------------------------------------------------------------
// Router: own fp32 LN of x1, fp32 logits, softmax, strict top-2.
// NO global atomics: writes topi/topg per token + probs to pbuf.
// ---------------------------------------------------------------------------
__global__ __launch_bounds__(256) void k_router(
    const float* __restrict__ x1, const float* __restrict__ g,
    const float* __restrict__ b, const float* __restrict__ wr,
    int2* __restrict__ topi, float2* __restrict__ topg,
    float* __restrict__ pbuf)
{
  const int tok = blockIdx.x, tid = threadIdx.x;
  const float4 v = ((const float4*)(x1 + (long)tok * D_MODEL))[tid];
  float s  = v.x + v.y + v.z + v.w;
  float s2 = v.x * v.x + v.y * v.y + v.z * v.z + v.w * v.w;
#pragma unroll
  for (int off = 1; off < 64; off <<= 1) {
    s  += __shfl_xor(s, off);
    s2 += __shfl_xor(s2, off);
  }
  __shared__ float red[8];
  __shared__ float lr[4][8];
  if ((tid & 63) == 0) { red[tid >> 6] = s; red[4 + (tid >> 6)] = s2; }
  __syncthreads();
  s  = red[0] + red[1] + red[2] + red[3];
  s2 = red[4] + red[5] + red[6] + red[7];
  const float mu   = s * (1.0f / D_MODEL);
  const float var  = s2 * (1.0f / D_MODEL) - mu * mu;
  const float rstd = 1.0f / sqrtf(var + 1e-5f);
  const float4 gg = ((const float4*)g)[tid];
  const float4 bb = ((const float4*)b)[tid];
  float n4[4];
  n4[0] = (v.x - mu) * rstd * gg.x + bb.x;
  n4[1] = (v.y - mu) * rstd * gg.y + bb.y;
  n4[2] = (v.z - mu) * rstd * gg.z + bb.z;
  n4[3] = (v.w - mu) * rstd * gg.w + bb.w;
  float part[8];
#pragma unroll
  for (int e = 0; e < 8; ++e) part[e] = 0.f;
  const float* wrow = wr + (long)tid * 4 * 8;
#pragma unroll
  for (int c = 0; c < 4; ++c)
#pragma unroll
    for (int e = 0; e < 8; ++e) part[e] += n4[c] * wrow[c * 8 + e];
#pragma unroll
  for (int off = 1; off < 64; off <<= 1)
#pragma unroll
    for (int e = 0; e < 8; ++e) part[e] += __shfl_xor(part[e], off);
  if ((tid & 63) == 0)
#pragma unroll
    for (int e = 0; e < 8; ++e) lr[tid >> 6][e] = part[e];
  __syncthreads();
  if (tid == 0) {
    float lg[8];
#pragma unroll
    for (int e = 0; e < 8; ++e) lg[e] = lr[0][e] + lr[1][e] + lr[2][e] + lr[3][e];
    float mx = lg[0];
#pragma unroll
    for (int e = 1; e < 8; ++e) mx = fmaxf(mx, lg[e]);
    float pe[8], ssum = 0.f;
#pragma unroll
    for (int e = 0; e < 8; ++e) { pe[e] = expf(lg[e] - mx); ssum += pe[e]; }
    const float inv = 1.0f / ssum;
    int i1 = -1, i2 = -1;
    float v1 = -1.f, v2 = -1.f;
#pragma unroll
    for (int e = 0; e < 8; ++e) {
      const float p = pe[e] * inv;
      pbuf[(long)tok * 8 + e] = p;
      if (p > v1)      { v2 = v1; i2 = i1; v1 = p; i1 = e; }
      else if (p > v2) { v2 = p; i2 = e; }
    }
    const float wsum = v1 + v2;
    topi[tok] = make_int2(i1, i2);
    topg[tok] = make_float2(v1 / wsum, v2 / wsum);
  }
}

// ---------------------------------------------------------------------------
// Scatter: build per-expert token lists. 16 blocks x 256 tokens; LDS
// histogram + local ranks, then 8 global atomics per block to claim ranges.
// ---------------------------------------------------------------------------
__global__ __launch_bounds__(256) void k_scatter(
    const int2* __restrict__ topi, const float2* __restrict__ topg,
    int* __restrict__ ecnt, int* __restrict__ perm, float* __restrict__ gatew)
{
  __shared__ int hcnt[NEXP];
  __shared__ int hbase[NEXP];
  const int tid = threadIdx.x;
  const int tok = blockIdx.x * 256 + tid;
  if (tid < NEXP) hcnt[tid] = 0;
  __syncthreads();
  const int2 ti = topi[tok];
  const float2 tg = topg[tok];
  const int r1 = atomicAdd(&hcnt[ti.x], 1);
  const int r2 = atomicAdd(&hcnt[ti.y], 1);
  __syncthreads();
  if (tid < NEXP) hbase[tid] = atomicAdd(&ecnt[tid], hcnt[tid]);
  __syncthreads();
  const int p1 = hbase[ti.x] + r1;
  perm[ti.x * NTOK + p1] = tok; gatew[ti.x * NTOK + p1] = tg.x;
  const int p2 = hbase[ti.y] + r2;
  perm[ti.y * NTOK + p2] = tok; gatew[ti.y * NTOK + p2] = tg.y;
}

// ---------------------------------------------------------------------------
// Finalize: reduce pbuf -> psum, compute eoff + aux loss.
// ---------------------------------------------------------------------------
__global__ __launch_bounds__(256) void k_finalize(
    const int* __restrict__ ecnt, const float* __restrict__ pbuf,
    int* __restrict__ eoff, float* __restrict__ aux_out)
{
  __shared__ float partial[256];
  const int tid = threadIdx.x;
  const int e = tid & 7, i0 = tid >> 3;
  float sum = 0.f;
  for (int i = i0; i < NTOK; i += 32) sum += pbuf[(long)i * 8 + e];
  partial[tid] = sum;
  __syncthreads();
  if (tid < 8) {
    float ps = 0.f;
#pragma unroll
    for (int j = 0; j < 32; ++j) ps += partial[j * 8 + tid];
    partial[tid] = ps;   // psum[e]
  }
  __syncthreads();
  if (tid == 0) {
    int off = 0;
    float aux = 0.f;
    for (int e2 = 0; e2 < 8; ++e2) {
      eoff[e2] = off;
      off += (ecnt[e2] + 127) & ~127;
      aux += ((float)ecnt[e2] * (1.0f / (NTOK * 2.0f))) * (partial[e2] * (1.0f / NTOK));
    }
    aux_out[0] = 8.0f * aux;
  }
}

// ---------------------------------------------------------------------------
// FFN1: gathered ln2 rows @ w1T[e] + b1 -> exact GELU -> h (bf16)
// ---------------------------------------------------------------------------
__global__ __launch_bounds__(256, 2) void k_gemm_ffn1(
    const bf16* __restrict__ A, const bf16* __restrict__ w1t,
    const float* __restrict__ b1, const int* __restrict__ ecnt,
    const int* __restrict__ eoff, const int* __restrict__ perm,
    bf16* __restrict__ h)
{
  const int e = blockIdx.y >> 5, mt = blockIdx.y & 31;
  const int cnt = ecnt[e];
  if (mt * 128 >= cnt) return;
  __shared__ __align__(16) bf16 As[128 * 32];
  __shared__ __align__(16) bf16 Bs[128 * 32];
  const int tid = threadIdx.x, lane = tid & 63, w = tid >> 6;
  const int fr = lane & 15, quad = lane >> 4;
  const int wm = w >> 1, wn = w & 1;
  const int n0 = blockIdx.x * 128;
  const int lrow = w * 16 + (lane >> 2), colk = (lane & 3) * 8;
  int i0 = mt * 128 + lrow;
  int i1 = i0 + 64;
  i0 = min(i0, cnt - 1);
  i1 = min(i1, cnt - 1);
  const int* pe = perm + e * NTOK;
  long aOff0 = (long)pe[i0] * D_MODEL + colk;
  long aOff1 = (long)pe[i1] * D_MODEL + colk;
  const bf16* B = w1t + (long)e * DFF * D_MODEL;
  long bOff0 = (long)(n0 + lrow) * D_MODEL + colk;
  long bOff1 = bOff0 + 64L * D_MODEL;
  f32x4 acc[4][4];
  f32x4 zv = {0.f, 0.f, 0.f, 0.f};
#pragma unroll
  for (int i = 0; i < 4; ++i)
#pragma unroll
    for (int j = 0; j < 4; ++j) acc[i][j] = zv;
  gemm_core<false>(A, A, B, B, aOff0, aOff1, bOff0, bOff1, D_MODEL, As, Bs, acc);
  const int hbase = eoff[e] + mt * 128;
#pragma unroll
  for (int mi = 0; mi < 4; ++mi)
#pragma unroll
    for (int ni = 0; ni < 4; ++ni) {
      const int col = n0 + wn * 64 + ni * 16 + fr;
#pragma unroll
      for (int r = 0; r < 4; ++r) {
        const int irow = wm * 64 + mi * 16 + quad * 4 + r;
        const float vv = acc[mi][ni][r] + b1[e * DFF + col];
        const float ge = 0.5f * vv * (1.0f + erff(vv * 0.70710678118654752f));
        h[(long)(hbase + irow) * DFF + col] = (bf16)ge;
      }
    }
}

// ---------------------------------------------------------------------------
// FFN2: h rows @ w2T[e] + b2, gated atomic scatter-add into d_out
// ---------------------------------------------------------------------------
__global__ __launch_bounds__(256, 2) void k_gemm_ffn2(
    const bf16* __restrict__ hbuf, const bf16* __restrict__ w2t,
    const float* __restrict__ b2, const int* __restrict__ ecnt,
    const int* __restrict__ eoff, const int* __restrict__ perm,
    const float* __restrict__ gatew, float* __restrict__ out)
{
  const int e = blockIdx.y >> 5, mt = blockIdx.y & 31;
  const int cnt = ecnt[e];
  if (mt * 128 >= cnt) return;
  __shared__ __align__(16) bf16 As[128 * 32];
  __shared__ __align__(16) bf16 Bs[128 * 32];
  const int tid = threadIdx.x, lane = tid & 63, w = tid >> 6;
  const int fr = lane & 15, quad = lane >> 4;
  const int wm = w >> 1, wn = w & 1;
  const int n0 = blockIdx.x * 128;
  const int lrow = w * 16 + (lane >> 2), colk = (lane & 3) * 8;
  const bf16* A = hbuf + (long)(eoff[e] + mt * 128) * DFF;
  long aOff0 = (long)lrow * DFF + colk;
  long aOff1 = aOff0 + 64L * DFF;
  const bf16* B = w2t + (long)e * D_MODEL * DFF;
  long bOff0 = (long)(n0 + lrow) * DFF + colk;
  long bOff1 = bOff0 + 64L * DFF;
  f32x4 acc[4][4];
  f32x4 zv = {0.f, 0.f, 0.f, 0.f};
#pragma unroll
  for (int i = 0; i < 4; ++i)
#pragma unroll
    for (int j = 0; j < 4; ++j) acc[i][j] = zv;
  gemm_core<false>(A, A, B, B, aOff0, aOff1, bOff0, bOff1, DFF, As, Bs, acc);
#pragma unroll
  for (int mi = 0; mi < 4; ++mi)
#pragma unroll
    for (int ni = 0; ni < 4; ++ni) {
      const int col = n0 + wn * 64 + ni * 16 + fr;
#pragma unroll
      for (int r = 0; r < 4; ++r) {
        const int irow = wm * 64 + mi * 16 + quad * 4 + r;
        const int gi = mt * 128 + irow;
        if (gi < cnt) {
          const int tok = perm[e * NTOK + gi];
          const float gw = gatew[e * NTOK + gi];
          const float vv = acc[mi][ni][r] + b2[e * D_MODEL + col];
          atomicAdd(&out[(long)tok * D_MODEL + col], vv * gw);
        }
      }
    }
}

// ---------------------------------------------------------------------------
extern "C" void kernel_launch(void* const* d_in, const int* in_sizes, int n_in,
                              void* d_out, int out_size, void* d_ws, size_t ws_size,
                              hipStream_t stream) {
  const float* x     = (const float*)d_in[0];
  // d_in[1] = mask (causal structure reproduced in-kernel)
  const float* ln1g  = (const float*)d_in[2];
  const float* ln1b  = (const float*)d_in[3];
  const float* wqkv  = (const float*)d_in[4];
  const float* wproj = (const float*)d_in[5];
  const float* bproj = (const float*)d_in[6];
  const float* ln2g  = (const float*)d_in[7];
  const float* ln2b  = (const float*)d_in[8];
  const float* wrout = (const float*)d_in[9];
  const float* w1    = (const float*)d_in[10];
  const float* b1    = (const float*)d_in[11];
  const float* w2    = (const float*)d_in[12];
  const float* b2    = (const float*)d_in[13];
  float* out = (float*)d_out;

  char* p = (char*)d_ws;
  auto alloc = [&](size_t n) { char* r = p; p += (n + 255) & ~(size_t)255; return r; };

  bf16* wqkvT_h = (bf16*)alloc(3072L * 1024 * 2);
  bf16* wqkvT_l = (bf16*)alloc(3072L * 1024 * 2);
  bf16* wprojT_h = (bf16*)alloc(1024L * 1024 * 2);
  bf16* wprojT_l = (bf16*)alloc(1024L * 1024 * 2);
  bf16* w1T = (bf16*)alloc(8L * 4096 * 1024 * 2);
  bf16* w2T = (bf16*)alloc(8L * 1024 * 4096 * 2);
  bf16* ln_h = (bf16*)alloc(4096L * 1024 * 2);  // ln1 then reused for ln2
  bf16* ln_l = (bf16*)alloc(4096L * 1024 * 2);
  bf16* attn_h = (bf16*)alloc(4096L * 1024 * 2);
  bf16* attn_l = (bf16*)alloc(4096L * 1024 * 2);
  int*   perm  = (int*)alloc(8L * 4096 * 4);
  float* gatew = (float*)alloc(8L * 4096 * 4);
  int2*  topi  = (int2*)alloc(4096L * 8);
  float2* topg = (float2*)alloc(4096L * 8);
  float* pbuf  = (float*)alloc(4096L * 8 * 4);
  char*  ctrl  = alloc(256);                 // ecnt[8] | eoff[8]
  int*   ecnt  = (int*)ctrl;
  int*   eoff  = (int*)(ctrl + 64);
  // big overlay region: [qkv fp32 48MB | rope hi/lo bufs 48MB] then h (73MB)
  char* big = alloc(100663296);
  float* qkvf = (float*)big;                           // 4096*3072*4
  bf16* qh = (bf16*)(big + 50331648);
  bf16* ql = qh + 4194304;
  bf16* kh = ql + 4194304;
  bf16* kl = kh + 4194304;
  bf16* vh = kl + 4194304;
  bf16* vl = vh + 4194304;
  bf16* hbuf = (bf16*)big;                             // 9216*4096*2, after attn

  dim3 blk(256);

  // 1) weight transpose + cast
  k_transpose_cast<<<dim3(3072 / 32, 1024 / 32, 1), blk, 0, stream>>>(wqkv, wqkvT_h, wqkvT_l, 1024, 3072);
  k_transpose_cast<<<dim3(1024 / 32, 1024 / 32, 1), blk, 0, stream>>>(wproj, wprojT_h, wprojT_l, 1024, 1024);
  k_transpose_cast<<<dim3(4096 / 32, 1024 / 32, 8), blk, 0, stream>>>(w1, w1T, nullptr, 1024, 4096);
  k_transpose_cast<<<dim3(1024 / 32, 4096 / 32, 8), blk, 0, stream>>>(w2, w2T, nullptr, 4096, 1024);
  hipMemsetAsync(ctrl, 0, 256, stream);

  // 2) attention path (split precision)
  k_layernorm<<<4096, blk, 0, stream>>>(x, ln1g, ln1b, ln_h, ln_l);
  k_gemm_qkv<<<dim3(24, 32), blk, 0, stream>>>(ln_h, ln_l, wqkvT_h, wqkvT_l, qkvf);
  k_rope<<<4096, blk, 0, stream>>>(qkvf, qh, ql, kh, kl, vh, vl);
  k_flash<<<dim3(16, 64), blk, 0, stream>>>(qh, ql, kh, kl, vh, vl, attn_h, attn_l);
  k_gemm_proj<<<dim3(8, 32), blk, 0, stream>>>(attn_h, attn_l, wprojT_h, wprojT_l, bproj, x, out);

  // 3) MoE
  k_layernorm<<<4096, blk, 0, stream>>>(out, ln2g, ln2b, ln_h, nullptr);
  k_router<<<4096, blk, 0, stream>>>(out, ln2g, ln2b, wrout, topi, topg, pbuf);
  k_scatter<<<16, blk, 0, stream>>>(topi, topg, ecnt, perm, gatew);
  k_finalize<<<1, blk, 0, stream>>>(ecnt, pbuf, eoff, out + 4194304);
  k_gemm_ffn1<<<dim3(32, 256), blk, 0, stream>>>(ln_h, w1T, b1, ecnt, eoff, perm, hbuf);
  k_gemm_ffn2<<<dim3(8, 256), blk, 0, stream>>>(hbuf, w2T, b2, ecnt, eoff, perm, gatew, out);
}

// Round 2
// 1057.704 us; speedup vs baseline: 1.0466x; 1.0204x over previous
//
#include <hip/hip_runtime.h>
#include <math.h>

// ---------------------------------------------------------------------------
// TransformerBlock: x + attn(LN1(x)) -> x1 ; x1 + top2-MoE(LN2(x1)) ; aux loss
// R4: FFN2 de-atomicized. Was 33.5M fp32 global atomicAdds in the epilogue
// (MfmaUtil 13.8%, 206us, nothing-busy => epilogue-serialization-bound).
// Now: ffn2 writes fp32 staging ybuf[row][col] (plain coalesced stores,
// bias folded), k_scatter records per-token rank-in-expert (pos), and a new
// memory-bound k_combine does out[tok] += g1*y[row1] + g2*y[row2].
// R3 (kept): flash LDS XOR swizzle + P-aliased-on-Q (48KB LDS).
// ---------------------------------------------------------------------------

typedef __bf16 bf16;
typedef __bf16 bf16x8 __attribute__((ext_vector_type(8)));
typedef float  f32x4  __attribute__((ext_vector_type(4)));

#define D_MODEL 1024
#define SEQ     1024
#define NTOK    4096
#define DFF     4096
#define NEXP    8

__device__ __forceinline__ f32x4 mfma16(bf16x8 a, bf16x8 b, f32x4 c) {
  return __builtin_amdgcn_mfma_f32_16x16x32_bf16(a, b, c, 0, 0, 0);
}

__device__ __forceinline__ void async_cp16(void* lds, const void* g) {
  __builtin_amdgcn_global_load_lds(
      (__attribute__((address_space(1))) void*)(void*)g,
      (__attribute__((address_space(3))) void*)lds, 16, 0, 0);
}

// Bank-conflict-free index into a [R][64] bf16 LDS tile (flash tiles).
__device__ __forceinline__ int swz(int row, int col) {
  return row * 64 + (col ^ (((row ^ (row >> 3)) & 7) << 3));
}

// ---------------------------------------------------------------------------
// Shared MFMA GEMM core: C[128x128] tile, A [M][K] rows via per-lane offsets,
// B stored transposed [N][K]. SPLIT => 3 phases (Ah*Bh, Al*Bh, Ah*Bl).
// ---------------------------------------------------------------------------
template<bool SPLIT>
__device__ __forceinline__ void gemm_core(
    const bf16* __restrict__ Ahi, const bf16* __restrict__ Alo,
    const bf16* __restrict__ Bhi, const bf16* __restrict__ Blo,
    long aOff0, long aOff1, long bOff0, long bOff1,
    int K, bf16* As, bf16* Bs, f32x4 acc[4][4])
{
  const int tid  = threadIdx.x;
  const int lane = tid & 63, w = tid >> 6;
  const int fr   = lane & 15, quad = lane >> 4;
  const int wm   = w >> 1,    wn   = w & 1;
  bf16* AsD0 = As + (w * 16) * 32;
  bf16* AsD1 = As + (64 + w * 16) * 32;
  bf16* BsD0 = Bs + (w * 16) * 32;
  bf16* BsD1 = Bs + (64 + w * 16) * 32;
  const int nph = SPLIT ? 3 : 1;
  for (int ph = 0; ph < nph; ++ph) {
    const bf16* Ap = (ph == 1) ? Alo : Ahi;
    const bf16* Bp = (ph == 2) ? Blo : Bhi;
    for (int k0 = 0; k0 < K; k0 += 32) {
      async_cp16(AsD0, Ap + aOff0 + k0);
      async_cp16(AsD1, Ap + aOff1 + k0);
      async_cp16(BsD0, Bp + bOff0 + k0);
      async_cp16(BsD1, Bp + bOff1 + k0);
      __syncthreads();
      bf16x8 af[4], bfv[4];
#pragma unroll
      for (int mi = 0; mi < 4; ++mi)
        af[mi] = *(const bf16x8*)&As[(wm * 64 + mi * 16 + fr) * 32 + quad * 8];
#pragma unroll
      for (int ni = 0; ni < 4; ++ni)
        bfv[ni] = *(const bf16x8*)&Bs[(wn * 64 + ni * 16 + fr) * 32 + quad * 8];
#pragma unroll
      for (int mi = 0; mi < 4; ++mi)
#pragma unroll
        for (int ni = 0; ni < 4; ++ni)
          acc[mi][ni] = mfma16(af[mi], bfv[ni], acc[mi][ni]);
      __syncthreads();
    }
  }
}

// ---------------------------------------------------------------------------
// Weight transpose + fp32->bf16(hi[,lo]) cast: in [Z][K][N] -> out [Z][N][K]
// ---------------------------------------------------------------------------
__global__ void k_transpose_cast(const float* __restrict__ in,
                                 bf16* __restrict__ oh, bf16* __restrict__ ol,
                                 int K, int N)
{
  const long zo = (long)blockIdx.z * K * N;
  __shared__ float tile[32][33];
  const int tx = threadIdx.x & 31, ty = threadIdx.x >> 5;
  const int r0 = blockIdx.y * 32, c0 = blockIdx.x * 32;
#pragma unroll
  for (int j = 0; j < 4; ++j)
    tile[ty + 8 * j][tx] = in[zo + (long)(r0 + ty + 8 * j) * N + (c0 + tx)];
  __syncthreads();
#pragma unroll
  for (int j = 0; j < 4; ++j) {
    float v = tile[tx][ty + 8 * j];
    long  o = zo + (long)(c0 + ty + 8 * j) * K + (r0 + tx);
    bf16 hh = (bf16)v;
    oh[o] = hh;
    if (ol) ol[o] = (bf16)(v - (float)hh);
  }
}

// ---------------------------------------------------------------------------
// LayerNorm: one block per token, writes bf16 hi (and lo if non-null)
// ---------------------------------------------------------------------------
__global__ __launch_bounds__(256) void k_layernorm(
    const float* __restrict__ x, const float* __restrict__ g,
    const float* __restrict__ b, bf16* __restrict__ oh, bf16* __restrict__ ol)
{
  const int tok = blockIdx.x, tid = threadIdx.x;
  const float4 v = ((const float4*)(x + (long)tok * D_MODEL))[tid];
  float s  = v.x + v.y + v.z + v.w;
  float s2 = v.x * v.x + v.y * v.y + v.z * v.z + v.w * v.w;
#pragma unroll
  for (int off = 1; off < 64; off <<= 1) {
    s  += __shfl_xor(s, off);
    s2 += __shfl_xor(s2, off);
  }
  __shared__ float red[8];
  if ((tid & 63) == 0) { red[tid >> 6] = s; red[4 + (tid >> 6)] = s2; }
  __syncthreads();
  s  = red[0] + red[1] + red[2] + red[3];
  s2 = red[4] + red[5] + red[6] + red[7];
  const float mu   = s * (1.0f / D_MODEL);
  const float var  = s2 * (1.0f / D_MODEL) - mu * mu;
  const float rstd = 1.0f / sqrtf(var + 1e-5f);
  const float4 gg = ((const float4*)g)[tid];
  const float4 bb = ((const float4*)b)[tid];
  float o0 = (v.x - mu) * rstd * gg.x + bb.x;
  float o1 = (v.y - mu) * rstd * gg.y + bb.y;
  float o2 = (v.z - mu) * rstd * gg.z + bb.z;
  float o3 = (v.w - mu) * rstd * gg.w + bb.w;
  const long base = (long)tok * D_MODEL + tid * 4;
  bf16 h0 = (bf16)o0, h1 = (bf16)o1, h2 = (bf16)o2, h3 = (bf16)o3;
  oh[base + 0] = h0; oh[base + 1] = h1; oh[base + 2] = h2; oh[base + 3] = h3;
  if (ol) {
    ol[base + 0] = (bf16)(o0 - (float)h0);
    ol[base + 1] = (bf16)(o1 - (float)h1);
    ol[base + 2] = (bf16)(o2 - (float)h2);
    ol[base + 3] = (bf16)(o3 - (float)h3);
  }
}

// ---------------------------------------------------------------------------
// QKV GEMM (split): ln1[4096][1024] @ wqkvT -> qkv fp32 [4096][3072]
// ---------------------------------------------------------------------------
__global__ __launch_bounds__(256, 2) void k_gemm_qkv(
    const bf16* __restrict__ Ah, const bf16* __restrict__ Al,
    const bf16* __restrict__ Bh, const bf16* __restrict__ Bl,
    float* __restrict__ out)
{
  __shared__ __align__(16) bf16 As[128 * 32];
  __shared__ __align__(16) bf16 Bs[128 * 32];
  const int tid = threadIdx.x, lane = tid & 63, w = tid >> 6;
  const int fr = lane & 15, quad = lane >> 4;
  const int wm = w >> 1, wn = w & 1;
  const int m0 = blockIdx.y * 128, n0 = blockIdx.x * 128;
  const int lrow = w * 16 + (lane >> 2), colk = (lane & 3) * 8;
  long aOff0 = (long)(m0 + lrow) * D_MODEL + colk;
  long aOff1 = aOff0 + 64L * D_MODEL;
  long bOff0 = (long)(n0 + lrow) * D_MODEL + colk;
  long bOff1 = bOff0 + 64L * D_MODEL;
  f32x4 acc[4][4];
  f32x4 zv = {0.f, 0.f, 0.f, 0.f};
#pragma unroll
  for (int i = 0; i < 4; ++i)
#pragma unroll
    for (int j = 0; j < 4; ++j) acc[i][j] = zv;
  gemm_core<true>(Ah, Al, Bh, Bl, aOff0, aOff1, bOff0, bOff1, D_MODEL, As, Bs, acc);
#pragma unroll
  for (int mi = 0; mi < 4; ++mi)
#pragma unroll
    for (int ni = 0; ni < 4; ++ni) {
      const int col = n0 + wn * 64 + ni * 16 + fr;
#pragma unroll
      for (int r = 0; r < 4; ++r) {
        const int row = m0 + wm * 64 + mi * 16 + quad * 4 + r;
        out[(long)row * 3072 + col] = acc[mi][ni][r];
      }
    }
}

// ---------------------------------------------------------------------------
// RoPE + layout: qkv fp32 [tok][3072] -> q,k (rotated), v ; split hi/lo,
// head-major [bh][t][64]
// ---------------------------------------------------------------------------
__global__ __launch_bounds__(256) void k_rope(
    const float* __restrict__ qkv,
    bf16* __restrict__ qh, bf16* __restrict__ ql,
    bf16* __restrict__ kh, bf16* __restrict__ kl,
    bf16* __restrict__ vh, bf16* __restrict__ vl)
{
  const int tok = blockIdx.x;
  const int t = tok & (SEQ - 1), bb = tok >> 10;
  const int tid = threadIdx.x;
  const float ft = (float)t;
  for (int it = tid; it < 512; it += 256) {
    const int hh = it >> 5, i = it & 31;
    const float inv = powf(10000.0f, -(float)i * (1.0f / 32.0f));
    const float ang = ft * inv;
    float sn, cs;
    sincosf(ang, &sn, &cs);
    const long src = (long)tok * 3072 + hh * 64 + i;
    const float q0 = qkv[src], q1 = qkv[src + 32];
    const float k0 = qkv[src + 1024], k1 = qkv[src + 1024 + 32];
    const float qo0 = q0 * cs - q1 * sn, qo1 = q1 * cs + q0 * sn;
    const float ko0 = k0 * cs - k1 * sn, ko1 = k1 * cs + k0 * sn;
    const long dst = ((long)(bb * 16 + hh) * SEQ + t) * 64 + i;
    bf16 x;
    x = (bf16)qo0; qh[dst] = x;      ql[dst] = (bf16)(qo0 - (float)x);
    x = (bf16)qo1; qh[dst + 32] = x; ql[dst + 32] = (bf16)(qo1 - (float)x);
    x = (bf16)ko0; kh[dst] = x;      kl[dst] = (bf16)(ko0 - (float)x);
    x = (bf16)ko1; kh[dst + 32] = x; kl[dst + 32] = (bf16)(ko1 - (float)x);
  }
  for (int it = tid; it < 1024; it += 256) {
    const int hh = it >> 6, d = it & 63;
    const float vv = qkv[(long)tok * 3072 + 2048 + it];
    const long dst = ((long)(bb * 16 + hh) * SEQ + t) * 64 + d;
    bf16 x = (bf16)vv;
    vh[dst] = x; vl[dst] = (bf16)(vv - (float)x);
  }
}

// ---------------------------------------------------------------------------
// Flash attention (causal), split-precision QK^T and PV. Block = 64 q-rows.
// All LDS tiles XOR-swizzled; P tiles alias the read-once Q tiles (48KB LDS).
// ---------------------------------------------------------------------------
__global__ __launch_bounds__(256, 3) void k_flash(
    const bf16* __restrict__ qh, const bf16* __restrict__ ql,
    const bf16* __restrict__ kh, const bf16* __restrict__ kl,
    const bf16* __restrict__ vh, const bf16* __restrict__ vl,
    bf16* __restrict__ oh, bf16* __restrict__ ol)
{
  const int qt = blockIdx.x, bhid = blockIdx.y;
  const int tid = threadIdx.x, lane = tid & 63, w = tid >> 6;
  const int fr = lane & 15, quad = lane >> 4;
  __shared__ __align__(16) bf16 QP0[64 * 64];
  __shared__ __align__(16) bf16 QP1[64 * 64];
  __shared__ __align__(16) bf16 Kh[64 * 64], Kl[64 * 64];
  __shared__ __align__(16) bf16 Vh[64 * 64], Vl[64 * 64];

  const long qbase = ((long)bhid * SEQ + qt * 64) * 64;
  for (int c = tid; c < 512; c += 256) {
    const int row = c >> 3, c8 = (c & 7) << 3;
    *(uint4*)&QP0[swz(row, c8)] = *(const uint4*)&qh[qbase + row * 64 + c8];
    *(uint4*)&QP1[swz(row, c8)] = *(const uint4*)&ql[qbase + row * 64 + c8];
  }
  __syncthreads();
  bf16x8 aQh[2], aQl[2];
#pragma unroll
  for (int kk = 0; kk < 2; ++kk) {
    aQh[kk] = *(const bf16x8*)&QP0[swz(w * 16 + fr, kk * 32 + quad * 8)];
    aQl[kk] = *(const bf16x8*)&QP1[swz(w * 16 + fr, kk * 32 + quad * 8)];
  }
  f32x4 o[4];
  f32x4 zv = {0.f, 0.f, 0.f, 0.f};
#pragma unroll
  for (int ct = 0; ct < 4; ++ct) o[ct] = zv;
  float m_r[4], l_r[4];
#pragma unroll
  for (int r = 0; r < 4; ++r) { m_r[r] = -1e30f; l_r[r] = 0.f; }

  for (int kt = 0; kt <= qt; ++kt) {
    __syncthreads();
    const long kbase = ((long)bhid * SEQ + kt * 64) * 64;
    for (int c = tid; c < 512; c += 256) {
      const int row = c >> 3, c8 = (c & 7) << 3;
      *(uint4*)&Kh[swz(row, c8)] = *(const uint4*)&kh[kbase + row * 64 + c8];
      *(uint4*)&Kl[swz(row, c8)] = *(const uint4*)&kl[kbase + row * 64 + c8];
      uint4 uh = *(const uint4*)&vh[kbase + row * 64 + c8];
      uint4 ul = *(const uint4*)&vl[kbase + row * 64 + c8];
      const bf16* vph = (const bf16*)&uh;
      const bf16* vpl = (const bf16*)&ul;
#pragma unroll
      for (int j = 0; j < 8; ++j) {   // transpose V into [d][key], swizzled
        Vh[swz(c8 + j, row)] = vph[j];
        Vl[swz(c8 + j, row)] = vpl[j];
      }
    }
    __syncthreads();

    f32x4 s[4];
#pragma unroll
    for (int nt = 0; nt < 4; ++nt) s[nt] = zv;
#pragma unroll
    for (int nt = 0; nt < 4; ++nt)
#pragma unroll
      for (int kk = 0; kk < 2; ++kk) {
        bf16x8 bh8 = *(const bf16x8*)&Kh[swz(nt * 16 + fr, kk * 32 + quad * 8)];
        bf16x8 bl8 = *(const bf16x8*)&Kl[swz(nt * 16 + fr, kk * 32 + quad * 8)];
        s[nt] = mfma16(aQh[kk], bh8, s[nt]);
        s[nt] = mfma16(aQl[kk], bh8, s[nt]);
        s[nt] = mfma16(aQh[kk], bl8, s[nt]);
      }
    const int qloc = w * 16 + quad * 4;  // + r
#pragma unroll
    for (int nt = 0; nt < 4; ++nt)
#pragma unroll
      for (int r = 0; r < 4; ++r) {
        float sv = s[nt][r] * 0.125f;
        if (kt == qt && (nt * 16 + fr) > (qloc + r)) sv = -1e30f;
        s[nt][r] = sv;
      }
    float al4[4];
#pragma unroll
    for (int r = 0; r < 4; ++r) {
      float m = fmaxf(fmaxf(s[0][r], s[1][r]), fmaxf(s[2][r], s[3][r]));
#pragma unroll
      for (int off = 1; off < 16; off <<= 1) m = fmaxf(m, __shfl_xor(m, off));
      const float mn = fmaxf(m_r[r], m);
      al4[r] = expf(m_r[r] - mn);
      m_r[r] = mn;
    }
    float pmat[4][4], ls4[4];
#pragma unroll
    for (int r = 0; r < 4; ++r) ls4[r] = 0.f;
#pragma unroll
    for (int nt = 0; nt < 4; ++nt)
#pragma unroll
      for (int r = 0; r < 4; ++r) {
        const float p = expf(s[nt][r] - m_r[r]);
        pmat[nt][r] = p;
        ls4[r] += p;
      }
#pragma unroll
    for (int r = 0; r < 4; ++r) {
      float l = ls4[r];
#pragma unroll
      for (int off = 1; off < 16; off <<= 1) l += __shfl_xor(l, off);
      l_r[r] = l_r[r] * al4[r] + l;
      o[0][r] *= al4[r]; o[1][r] *= al4[r]; o[2][r] *= al4[r]; o[3][r] *= al4[r];
    }
    bf16* Pw0 = QP0 + w * 1024;
    bf16* Pw1 = QP1 + w * 1024;
#pragma unroll
    for (int nt = 0; nt < 4; ++nt)
#pragma unroll
      for (int r = 0; r < 4; ++r) {
        const float p = pmat[nt][r];
        bf16 hh2 = (bf16)p;
        Pw0[swz(quad * 4 + r, nt * 16 + fr)] = hh2;
        Pw1[swz(quad * 4 + r, nt * 16 + fr)] = (bf16)(p - (float)hh2);
      }
    __syncthreads();
#pragma unroll
    for (int kk = 0; kk < 2; ++kk) {
      bf16x8 aPh = *(const bf16x8*)&Pw0[swz(fr, kk * 32 + quad * 8)];
      bf16x8 aPl = *(const bf16x8*)&Pw1[swz(fr, kk * 32 + quad * 8)];
#pragma unroll
      for (int ct = 0; ct < 4; ++ct) {
        bf16x8 bVh = *(const bf16x8*)&Vh[swz(ct * 16 + fr, kk * 32 + quad * 8)];
        bf16x8 bVl = *(const bf16x8*)&Vl[swz(ct * 16 + fr, kk * 32 + quad * 8)];
        o[ct] = mfma16(aPh, bVh, o[ct]);
        o[ct] = mfma16(aPl, bVh, o[ct]);
        o[ct] = mfma16(aPh, bVl, o[ct]);
      }
    }
  }
  const int b_ = bhid >> 4, h_ = bhid & 15;
#pragma unroll
  for (int ct = 0; ct < 4; ++ct)
#pragma unroll
    for (int r = 0; r < 4; ++r) {
      const int tokn = b_ * SEQ + qt * 64 + w * 16 + quad * 4 + r;
      const int col = h_ * 64 + ct * 16 + fr;
      const float val = o[ct][r] / l_r[r];
      bf16 hh3 = (bf16)val;
      oh[(long)tokn * D_MODEL + col] = hh3;
      ol[(long)tokn * D_MODEL + col] = (bf16)(val - (float)hh3);
    }
}

// ---------------------------------------------------------------------------
// Proj GEMM (split) + bias + residual -> d_out fp32 (= x1)
// ---------------------------------------------------------------------------
__global__ __launch_bounds__(256, 2) void k_gemm_proj(
    const bf16* __restrict__ Ah, const bf16* __restrict__ Al,
    const bf16* __restrict__ Bh, const bf16* __restrict__ Bl,
    const float* __restrict__ bproj, const float* __restrict__ xin,
    float* __restrict__ out)
{
  __shared__ __align__(16) bf16 As[128 * 32];
  __shared__ __align__(16) bf16 Bs[128 * 32];
  const int tid = threadIdx.x, lane = tid & 63, w = tid >> 6;
  const int fr = lane & 15, quad = lane >> 4;
  const int wm = w >> 1, wn = w & 1;
  const int m0 = blockIdx.y * 128, n0 = blockIdx.x * 128;
  const int lrow = w * 16 + (lane >> 2), colk = (lane & 3) * 8;
  long aOff0 = (long)(m0 + lrow) * D_MODEL + colk;
  long aOff1 = aOff0 + 64L * D_MODEL;
  long bOff0 = (long)(n0 + lrow) * D_MODEL + colk;
  long bOff1 = bOff0 + 64L * D_MODEL;
  f32x4 acc[4][4];
  f32x4 zv = {0.f, 0.f, 0.f, 0.f};
#pragma unroll
  for (int i = 0; i < 4; ++i)
#pragma unroll
    for (int j = 0; j < 4; ++j) acc[i][j] = zv;
  gemm_core<true>(Ah, Al, Bh, Bl, aOff0, aOff1, bOff0, bOff1, D_MODEL, As, Bs, acc);
#pragma unroll
  for (int mi = 0; mi < 4; ++mi)
#pragma unroll
    for (int ni = 0; ni < 4; ++ni) {
      const int col = n0 + wn * 64 + ni * 16 + fr;
#pragma unroll
      for (int r = 0; r < 4; ++r) {
        const int row = m0 + wm * 64 + mi * 16 + quad * 4 + r;
        out[(long)row * D_MODEL + col] =
            acc[mi][ni][r] + bproj[col] + xin[(long)row * D_MODEL + col];
      }
    }
}

// ---------------------------------------------------------------------------
// Router: own fp32 LN of x1, fp32 logits, softmax, strict top-2.
// ---------------------------------------------------------------------------
__global__ __launch_bounds__(256) void k_router(
    const float* __restrict__ x1, const float* __restrict__ g,
    const float* __restrict__ b, const float* __restrict__ wr,
    int2* __restrict__ topi, float2* __restrict__ topg,
    float* __restrict__ pbuf)
{
  const int tok = blockIdx.x, tid = threadIdx.x;
  const float4 v = ((const float4*)(x1 + (long)tok * D_MODEL))[tid];
  float s  = v.x + v.y + v.z + v.w;
  float s2 = v.x * v.x + v.y * v.y + v.z * v.z + v.w * v.w;
#pragma unroll
  for (int off = 1; off < 64; off <<= 1) {
    s  += __shfl_xor(s, off);
    s2 += __shfl_xor(s2, off);
  }
  __shared__ float red[8];
  __shared__ float lr[4][8];
  if ((tid & 63) == 0) { red[tid >> 6] = s; red[4 + (tid >> 6)] = s2; }
  __syncthreads();
  s  = red[0] + red[1] + red[2] + red[3];
  s2 = red[4] + red[5] + red[6] + red[7];
  const float mu   = s * (1.0f / D_MODEL);
  const float var  = s2 * (1.0f / D_MODEL) - mu * mu;
  const float rstd = 1.0f / sqrtf(var + 1e-5f);
  const float4 gg = ((const float4*)g)[tid];
  const float4 bb = ((const float4*)b)[tid];
  float n4[4];
  n4[0] = (v.x - mu) * rstd * gg.x + bb.x;
  n4[1] = (v.y - mu) * rstd * gg.y + bb.y;
  n4[2] = (v.z - mu) * rstd * gg.z + bb.z;
  n4[3] = (v.w - mu) * rstd * gg.w + bb.w;
  float part[8];
#pragma unroll
  for (int e = 0; e < 8; ++e) part[e] = 0.f;
  const float* wrow = wr + (long)tid * 4 * 8;
#pragma unroll
  for (int c = 0; c < 4; ++c)
#pragma unroll
    for (int e = 0; e < 8; ++e) part[e] += n4[c] * wrow[c * 8 + e];
#pragma unroll
  for (int off = 1; off < 64; off <<= 1)
#pragma unroll
    for (int e = 0; e < 8; ++e) part[e] += __shfl_xor(part[e], off);
  if ((tid & 63) == 0)
#pragma unroll
    for (int e = 0; e < 8; ++e) lr[tid >> 6][e] = part[e];
  __syncthreads();
  if (tid == 0) {
    float lg[8];
#pragma unroll
    for (int e = 0; e < 8; ++e) lg[e] = lr[0][e] + lr[1][e] + lr[2][e] + lr[3][e];
    float mx = lg[0];
#pragma unroll
    for (int e = 1; e < 8; ++e) mx = fmaxf(mx, lg[e]);
    float pe[8], ssum = 0.f;
#pragma unroll
    for (int e = 0; e < 8; ++e) { pe[e] = expf(lg[e] - mx); ssum += pe[e]; }
    const float inv = 1.0f / ssum;
    int i1 = -1, i2 = -1;
    float v1 = -1.f, v2 = -1.f;
#pragma unroll
    for (int e = 0; e < 8; ++e) {
      const float p = pe[e] * inv;
      pbuf[(long)tok * 8 + e] = p;
      if (p > v1)      { v2 = v1; i2 = i1; v1 = p; i1 = e; }
      else if (p > v2) { v2 = p; i2 = e; }
    }
    const float wsum = v1 + v2;
    topi[tok] = make_int2(i1, i2);
    topg[tok] = make_float2(v1 / wsum, v2 / wsum);
  }
}

// ---------------------------------------------------------------------------
// Scatter: build per-expert token lists + per-token ranks (pos).
// ---------------------------------------------------------------------------
__global__ __launch_bounds__(256) void k_scatter(
    const int2* __restrict__ topi,
    int* __restrict__ ecnt, int* __restrict__ perm, int2* __restrict__ pos)
{
  __shared__ int hcnt[NEXP];
  __shared__ int hbase[NEXP];
  const int tid = threadIdx.x;
  const int tok = blockIdx.x * 256 + tid;
  if (tid < NEXP) hcnt[tid] = 0;
  __syncthreads();
  const int2 ti = topi[tok];
  const int r1 = atomicAdd(&hcnt[ti.x], 1);
  const int r2 = atomicAdd(&hcnt[ti.y], 1);
  __syncthreads();
  if (tid < NEXP) hbase[tid] = atomicAdd(&ecnt[tid], hcnt[tid]);
  __syncthreads();
  const int p1 = hbase[ti.x] + r1;
  perm[ti.x * NTOK + p1] = tok;
  const int p2 = hbase[ti.y] + r2;
  perm[ti.y * NTOK + p2] = tok;
  pos[tok] = make_int2(p1, p2);
}

// ---------------------------------------------------------------------------
// Finalize: reduce pbuf -> psum, compute eoff + aux loss.
// ---------------------------------------------------------------------------
__global__ __launch_bounds__(256) void k_finalize(
    const int* __restrict__ ecnt, const float* __restrict__ pbuf,
    int* __restrict__ eoff, float* __restrict__ aux_out)
{
  __shared__ float partial[256];
  const int tid = threadIdx.x;
  const int e = tid & 7, i0 = tid >> 3;
  float sum = 0.f;
  for (int i = i0; i < NTOK; i += 32) sum += pbuf[(long)i * 8 + e];
  partial[tid] = sum;
  __syncthreads();
  if (tid < 8) {
    float ps = 0.f;
#pragma unroll
    for (int j = 0; j < 32; ++j) ps += partial[j * 8 + tid];
    partial[tid] = ps;   // psum[e]
  }
  __syncthreads();
  if (tid == 0) {
    int off = 0;
    float aux = 0.f;
    for (int e2 = 0; e2 < 8; ++e2) {
      eoff[e2] = off;
      off += (ecnt[e2] + 127) & ~127;
      aux += ((float)ecnt[e2] * (1.0f / (NTOK * 2.0f))) * (partial[e2] * (1.0f / NTOK));
    }
    aux_out[0] = 8.0f * aux;
  }
}

// ---------------------------------------------------------------------------
// FFN1: gathered ln2 rows @ w1T[e] + b1 -> exact GELU -> h (bf16)
// ---------------------------------------------------------------------------
__global__ __launch_bounds__(256, 2) void k_gemm_ffn1(
    const bf16* __restrict__ A, const bf16* __restrict__ w1t,
    const float* __restrict__ b1, const int* __restrict__ ecnt,
    const int* __restrict__ eoff, const int* __restrict__ perm,
    bf16* __restrict__ h)
{
  const int e = blockIdx.y >> 5, mt = blockIdx.y & 31;
  const int cnt = ecnt[e];
  if (mt * 128 >= cnt) return;
  __shared__ __align__(16) bf16 As[128 * 32];
  __shared__ __align__(16) bf16 Bs[128 * 32];
  const int tid = threadIdx.x, lane = tid & 63, w = tid >> 6;
  const int fr = lane & 15, quad = lane >> 4;
  const int wm = w >> 1, wn = w & 1;
  const int n0 = blockIdx.x * 128;
  const int lrow = w * 16 + (lane >> 2), colk = (lane & 3) * 8;
  int i0 = mt * 128 + lrow;
  int i1 = i0 + 64;
  i0 = min(i0, cnt - 1);
  i1 = min(i1, cnt - 1);
  const int* pe = perm + e * NTOK;
  long aOff0 = (long)pe[i0] * D_MODEL + colk;
  long aOff1 = (long)pe[i1] * D_MODEL + colk;
  const bf16* B = w1t + (long)e * DFF * D_MODEL;
  long bOff0 = (long)(n0 + lrow) * D_MODEL + colk;
  long bOff1 = bOff0 + 64L * D_MODEL;
  f32x4 acc[4][4];
  f32x4 zv = {0.f, 0.f, 0.f, 0.f};
#pragma unroll
  for (int i = 0; i < 4; ++i)
#pragma unroll
    for (int j = 0; j < 4; ++j) acc[i][j] = zv;
  gemm_core<false>(A, A, B, B, aOff0, aOff1, bOff0, bOff1, D_MODEL, As, Bs, acc);
  const int hbase = eoff[e] + mt * 128;
#pragma unroll
  for (int mi = 0; mi < 4; ++mi)
#pragma unroll
    for (int ni = 0; ni < 4; ++ni) {
      const int col = n0 + wn * 64 + ni * 16 + fr;
#pragma unroll
      for (int r = 0; r < 4; ++r) {
        const int irow = wm * 64 + mi * 16 + quad * 4 + r;
        const float vv = acc[mi][ni][r] + b1[e * DFF + col];
        const float ge = 0.5f * vv * (1.0f + erff(vv * 0.70710678118654752f));
        h[(long)(hbase + irow) * DFF + col] = (bf16)ge;
      }
    }
}

// ---------------------------------------------------------------------------
// FFN2: h rows @ w2T[e] + b2 -> fp32 ybuf (plain coalesced stores; no atomics)
// ---------------------------------------------------------------------------
__global__ __launch_bounds__(256, 2) void k_gemm_ffn2(
    const bf16* __restrict__ hbuf, const bf16* __restrict__ w2t,
    const float* __restrict__ b2, const int* __restrict__ ecnt,
    const int* __restrict__ eoff, float* __restrict__ ybuf)
{
  const int e = blockIdx.y >> 5, mt = blockIdx.y & 31;
  const int cnt = ecnt[e];
  if (mt * 128 >= cnt) return;
  __shared__ __align__(16) bf16 As[128 * 32];
  __shared__ __align__(16) bf16 Bs[128 * 32];
  const int tid = threadIdx.x, lane = tid & 63, w = tid >> 6;
  const int fr = lane & 15, quad = lane >> 4;
  const int wm = w >> 1, wn = w & 1;
  const int n0 = blockIdx.x * 128;
  const int lrow = w * 16 + (lane >> 2), colk = (lane & 3) * 8;
  const int rbase = eoff[e] + mt * 128;
  const bf16* A = hbuf + (long)rbase * DFF;
  long aOff0 = (long)lrow * DFF + colk;
  long aOff1 = aOff0 + 64L * DFF;
  const bf16* B = w2t + (long)e * D_MODEL * DFF;
  long bOff0 = (long)(n0 + lrow) * DFF + colk;
  long bOff1 = bOff0 + 64L * DFF;
  f32x4 acc[4][4];
  f32x4 zv = {0.f, 0.f, 0.f, 0.f};
#pragma unroll
  for (int i = 0; i < 4; ++i)
#pragma unroll
    for (int j = 0; j < 4; ++j) acc[i][j] = zv;
  gemm_core<false>(A, A, B, B, aOff0, aOff1, bOff0, bOff1, DFF, As, Bs, acc);
#pragma unroll
  for (int mi = 0; mi < 4; ++mi)
#pragma unroll
    for (int ni = 0; ni < 4; ++ni) {
      const int col = n0 + wn * 64 + ni * 16 + fr;
      const float bias = b2[e * D_MODEL + col];
#pragma unroll
      for (int r = 0; r < 4; ++r) {
        const int irow = wm * 64 + mi * 16 + quad * 4 + r;
        ybuf[(long)(rbase + irow) * D_MODEL + col] = acc[mi][ni][r] + bias;
      }
    }
}

// ---------------------------------------------------------------------------
// Combine: out[tok] += g1*ybuf[row1] + g2*ybuf[row2]  (one block per token)
// ---------------------------------------------------------------------------
__global__ __launch_bounds__(256) void k_combine(
    const int2* __restrict__ topi, const float2* __restrict__ topg,
    const int2* __restrict__ pos, const int* __restrict__ eoff,
    const float* __restrict__ ybuf, float* __restrict__ out)
{
  const int tok = blockIdx.x, tid = threadIdx.x;
  const int2 ti = topi[tok];
  const int2 pp = pos[tok];
  const float2 tg = topg[tok];
  const long r1 = (long)eoff[ti.x] + pp.x;
  const long r2 = (long)eoff[ti.y] + pp.y;
  const float4 y1 = ((const float4*)(ybuf + r1 * D_MODEL))[tid];
  const float4 y2 = ((const float4*)(ybuf + r2 * D_MODEL))[tid];
  float4* po = (float4*)(out + (long)tok * D_MODEL) + tid;
  float4 o = *po;
  o.x += tg.x * y1.x + tg.y * y2.x;
  o.y += tg.x * y1.y + tg.y * y2.y;
  o.z += tg.x * y1.z + tg.y * y2.z;
  o.w += tg.x * y1.w + tg.y * y2.w;
  *po = o;
}

// ---------------------------------------------------------------------------
extern "C" void kernel_launch(void* const* d_in, const int* in_sizes, int n_in,
                              void* d_out, int out_size, void* d_ws, size_t ws_size,
                              hipStream_t stream) {
  const float* x     = (const float*)d_in[0];
  // d_in[1] = mask (causal structure reproduced in-kernel)
  const float* ln1g  = (const float*)d_in[2];
  const float* ln1b  = (const float*)d_in[3];
  const float* wqkv  = (const float*)d_in[4];
  const float* wproj = (const float*)d_in[5];
  const float* bproj = (const float*)d_in[6];
  const float* ln2g  = (const float*)d_in[7];
  const float* ln2b  = (const float*)d_in[8];
  const float* wrout = (const float*)d_in[9];
  const float* w1    = (const float*)d_in[10];
  const float* b1    = (const float*)d_in[11];
  const float* w2    = (const float*)d_in[12];
  const float* b2    = (const float*)d_in[13];
  float* out = (float*)d_out;

  char* p = (char*)d_ws;
  auto alloc = [&](size_t n) { char* r = p; p += (n + 255) & ~(size_t)255; return r; };

  bf16* wqkvT_h = (bf16*)alloc(3072L * 1024 * 2);
  bf16* wqkvT_l = (bf16*)alloc(3072L * 1024 * 2);
  bf16* wprojT_h = (bf16*)alloc(1024L * 1024 * 2);
  bf16* wprojT_l = (bf16*)alloc(1024L * 1024 * 2);
  bf16* w1T = (bf16*)alloc(8L * 4096 * 1024 * 2);
  bf16* w2T = (bf16*)alloc(8L * 1024 * 4096 * 2);
  bf16* ln_h = (bf16*)alloc(4096L * 1024 * 2);  // ln1 then reused for ln2
  bf16* ln_l = (bf16*)alloc(4096L * 1024 * 2);
  bf16* attn_h = (bf16*)alloc(4096L * 1024 * 2);
  bf16* attn_l = (bf16*)alloc(4096L * 1024 * 2);
  int*   perm  = (int*)alloc(8L * 4096 * 4);
  int2*  topi  = (int2*)alloc(4096L * 8);
  float2* topg = (float2*)alloc(4096L * 8);
  int2*  pos   = (int2*)alloc(4096L * 8);
  float* pbuf  = (float*)alloc(4096L * 8 * 4);
  char*  ctrl  = alloc(256);                 // ecnt[8] | eoff[8]
  int*   ecnt  = (int*)ctrl;
  int*   eoff  = (int*)(ctrl + 64);
  float* ybuf  = (float*)alloc(9216L * 1024 * 4);      // fp32 FFN2 staging
  // big overlay region: [qkv fp32 48MB | rope hi/lo bufs 48MB] then h (73MB)
  char* big = alloc(100663296);
  float* qkvf = (float*)big;                           // 4096*3072*4
  bf16* qh = (bf16*)(big + 50331648);
  bf16* ql = qh + 4194304;
  bf16* kh = ql + 4194304;
  bf16* kl = kh + 4194304;
  bf16* vh = kl + 4194304;
  bf16* vl = vh + 4194304;
  bf16* hbuf = (bf16*)big;                             // 9216*4096*2, after attn

  dim3 blk(256);

  // 1) weight transpose + cast
  k_transpose_cast<<<dim3(3072 / 32, 1024 / 32, 1), blk, 0, stream>>>(wqkv, wqkvT_h, wqkvT_l, 1024, 3072);
  k_transpose_cast<<<dim3(1024 / 32, 1024 / 32, 1), blk, 0, stream>>>(wproj, wprojT_h, wprojT_l, 1024, 1024);
  k_transpose_cast<<<dim3(4096 / 32, 1024 / 32, 8), blk, 0, stream>>>(w1, w1T, nullptr, 1024, 4096);
  k_transpose_cast<<<dim3(1024 / 32, 4096 / 32, 8), blk, 0, stream>>>(w2, w2T, nullptr, 4096, 1024);
  hipMemsetAsync(ctrl, 0, 256, stream);

  // 2) attention path (split precision)
  k_layernorm<<<4096, blk, 0, stream>>>(x, ln1g, ln1b, ln_h, ln_l);
  k_gemm_qkv<<<dim3(24, 32), blk, 0, stream>>>(ln_h, ln_l, wqkvT_h, wqkvT_l, qkvf);
  k_rope<<<4096, blk, 0, stream>>>(qkvf, qh, ql, kh, kl, vh, vl);
  k_flash<<<dim3(16, 64), blk, 0, stream>>>(qh, ql, kh, kl, vh, vl, attn_h, attn_l);
  k_gemm_proj<<<dim3(8, 32), blk, 0, stream>>>(attn_h, attn_l, wprojT_h, wprojT_l, bproj, x, out);

  // 3) MoE
  k_layernorm<<<4096, blk, 0, stream>>>(out, ln2g, ln2b, ln_h, nullptr);
  k_router<<<4096, blk, 0, stream>>>(out, ln2g, ln2b, wrout, topi, topg, pbuf);
  k_scatter<<<16, blk, 0, stream>>>(topi, ecnt, perm, pos);
  k_finalize<<<1, blk, 0, stream>>>(ecnt, pbuf, eoff, out + 4194304);
  k_gemm_ffn1<<<dim3(32, 256), blk, 0, stream>>>(ln_h, w1T, b1, ecnt, eoff, perm, hbuf);
  k_gemm_ffn2<<<dim3(8, 256), blk, 0, stream>>>(hbuf, w2T, b2, ecnt, eoff, ybuf);
  k_combine<<<4096, blk, 0, stream>>>(topi, topg, pos, eoff, ybuf, out);
}

// Round 3
// 1047.208 us; speedup vs baseline: 1.0571x; 1.0100x over previous
//
#include <hip/hip_runtime.h>
#include <math.h>

// ---------------------------------------------------------------------------
// TransformerBlock: x + attn(LN1(x)) -> x1 ; x1 + top2-MoE(LN2(x1)) ; aux loss
// R5: GEMM latency-hiding. FFN2 was 386 TF with MfmaUtil 16% / Occ 1.3
// blocks/CU: per-K-step vmcnt(0) drain of L3-latency loads, no overlap.
//  * gemm_core -> double-buffered LDS, prefetch tile t+1 before computing
//    tile t, ONE barrier per K-step (its implicit vmcnt(0) drains loads that
//    had the whole MFMA phase to land). Applies to qkv/proj/ffn1/ffn2.
//  * ffn2 split-K=2 (grid.z): 512 -> 1024 working blocks (~4/CU); fp32
//    partials in ybuf[2], summed in k_combine.
// R4 (kept): de-atomicized FFN2 epilogue. R3 (kept): flash LDS XOR swizzle.
// ---------------------------------------------------------------------------

typedef __bf16 bf16;
typedef __bf16 bf16x8 __attribute__((ext_vector_type(8)));
typedef float  f32x4  __attribute__((ext_vector_type(4)));

#define D_MODEL 1024
#define SEQ     1024
#define NTOK    4096
#define DFF     4096
#define NEXP    8
#define YSTRIDE (9216L * 1024)

__device__ __forceinline__ f32x4 mfma16(bf16x8 a, bf16x8 b, f32x4 c) {
  return __builtin_amdgcn_mfma_f32_16x16x32_bf16(a, b, c, 0, 0, 0);
}

__device__ __forceinline__ void async_cp16(void* lds, const void* g) {
  __builtin_amdgcn_global_load_lds(
      (__attribute__((address_space(1))) void*)(void*)g,
      (__attribute__((address_space(3))) void*)lds, 16, 0, 0);
}

// Bank-conflict-free index into a [R][64] bf16 LDS tile (flash tiles).
__device__ __forceinline__ int swz(int row, int col) {
  return row * 64 + (col ^ (((row ^ (row >> 3)) & 7) << 3));
}

// ---------------------------------------------------------------------------
// Shared MFMA GEMM core, double-buffered: C[128x128] tile, A [M][K] rows via
// per-lane offsets, B stored transposed [N][K]. SPLIT => 3 flattened phases
// (Ah*Bh, Al*Bh, Ah*Bl) so the pipeline runs across phase boundaries.
// As/Bs must each be 2*128*32 bf16 (double buffer). One __syncthreads per
// K-step: stage(t+1) issued BEFORE compute(t); the barrier's implicit
// vmcnt(0) drains loads that overlapped with the ds_read+MFMA phase.
// ---------------------------------------------------------------------------
template<bool SPLIT>
__device__ __forceinline__ void gemm_core(
    const bf16* __restrict__ Ahi, const bf16* __restrict__ Alo,
    const bf16* __restrict__ Bhi, const bf16* __restrict__ Blo,
    long aOff0, long aOff1, long bOff0, long bOff1,
    int K, bf16* As, bf16* Bs, f32x4 acc[4][4])
{
  const int tid  = threadIdx.x;
  const int lane = tid & 63, w = tid >> 6;
  const int fr   = lane & 15, quad = lane >> 4;
  const int wm   = w >> 1,    wn   = w & 1;
  const int ldst0 = (w * 16) * 32;
  const int ldst1 = (64 + w * 16) * 32;
  const int ksteps = K >> 5;
  const int nsteps = (SPLIT ? 3 : 1) * ksteps;

  auto stage = [&](int s, int buf) {
    const int ph = SPLIT ? (s / ksteps) : 0;
    const int k0 = (SPLIT ? (s - ph * ksteps) : s) << 5;
    const bf16* Ap = (ph == 1) ? Alo : Ahi;
    const bf16* Bp = (ph == 2) ? Blo : Bhi;
    bf16* Ab = As + buf * (128 * 32);
    bf16* Bb = Bs + buf * (128 * 32);
    async_cp16(Ab + ldst0, Ap + aOff0 + k0);
    async_cp16(Ab + ldst1, Ap + aOff1 + k0);
    async_cp16(Bb + ldst0, Bp + bOff0 + k0);
    async_cp16(Bb + ldst1, Bp + bOff1 + k0);
  };

  stage(0, 0);
  __syncthreads();          // drains prologue loads (vmcnt(0) + barrier)
  int cur = 0;
  for (int s = 0; s < nsteps; ++s) {
    if (s + 1 < nsteps) stage(s + 1, cur ^ 1);   // overlap with compute below
    const bf16* Ab = As + cur * (128 * 32);
    const bf16* Bb = Bs + cur * (128 * 32);
    bf16x8 af[4], bfv[4];
#pragma unroll
    for (int mi = 0; mi < 4; ++mi)
      af[mi] = *(const bf16x8*)&Ab[(wm * 64 + mi * 16 + fr) * 32 + quad * 8];
#pragma unroll
    for (int ni = 0; ni < 4; ++ni)
      bfv[ni] = *(const bf16x8*)&Bb[(wn * 64 + ni * 16 + fr) * 32 + quad * 8];
#pragma unroll
    for (int mi = 0; mi < 4; ++mi)
#pragma unroll
      for (int ni = 0; ni < 4; ++ni)
        acc[mi][ni] = mfma16(af[mi], bfv[ni], acc[mi][ni]);
    __syncthreads();        // drains stage(s+1) loads; protects buf reuse
    cur ^= 1;
  }
}

// ---------------------------------------------------------------------------
// Weight transpose + fp32->bf16(hi[,lo]) cast: in [Z][K][N] -> out [Z][N][K]
// ---------------------------------------------------------------------------
__global__ void k_transpose_cast(const float* __restrict__ in,
                                 bf16* __restrict__ oh, bf16* __restrict__ ol,
                                 int K, int N)
{
  const long zo = (long)blockIdx.z * K * N;
  __shared__ float tile[32][33];
  const int tx = threadIdx.x & 31, ty = threadIdx.x >> 5;
  const int r0 = blockIdx.y * 32, c0 = blockIdx.x * 32;
#pragma unroll
  for (int j = 0; j < 4; ++j)
    tile[ty + 8 * j][tx] = in[zo + (long)(r0 + ty + 8 * j) * N + (c0 + tx)];
  __syncthreads();
#pragma unroll
  for (int j = 0; j < 4; ++j) {
    float v = tile[tx][ty + 8 * j];
    long  o = zo + (long)(c0 + ty + 8 * j) * K + (r0 + tx);
    bf16 hh = (bf16)v;
    oh[o] = hh;
    if (ol) ol[o] = (bf16)(v - (float)hh);
  }
}

// ---------------------------------------------------------------------------
// LayerNorm: one block per token, writes bf16 hi (and lo if non-null)
// ---------------------------------------------------------------------------
__global__ __launch_bounds__(256) void k_layernorm(
    const float* __restrict__ x, const float* __restrict__ g,
    const float* __restrict__ b, bf16* __restrict__ oh, bf16* __restrict__ ol)
{
  const int tok = blockIdx.x, tid = threadIdx.x;
  const float4 v = ((const float4*)(x + (long)tok * D_MODEL))[tid];
  float s  = v.x + v.y + v.z + v.w;
  float s2 = v.x * v.x + v.y * v.y + v.z * v.z + v.w * v.w;
#pragma unroll
  for (int off = 1; off < 64; off <<= 1) {
    s  += __shfl_xor(s, off);
    s2 += __shfl_xor(s2, off);
  }
  __shared__ float red[8];
  if ((tid & 63) == 0) { red[tid >> 6] = s; red[4 + (tid >> 6)] = s2; }
  __syncthreads();
  s  = red[0] + red[1] + red[2] + red[3];
  s2 = red[4] + red[5] + red[6] + red[7];
  const float mu   = s * (1.0f / D_MODEL);
  const float var  = s2 * (1.0f / D_MODEL) - mu * mu;
  const float rstd = 1.0f / sqrtf(var + 1e-5f);
  const float4 gg = ((const float4*)g)[tid];
  const float4 bb = ((const float4*)b)[tid];
  float o0 = (v.x - mu) * rstd * gg.x + bb.x;
  float o1 = (v.y - mu) * rstd * gg.y + bb.y;
  float o2 = (v.z - mu) * rstd * gg.z + bb.z;
  float o3 = (v.w - mu) * rstd * gg.w + bb.w;
  const long base = (long)tok * D_MODEL + tid * 4;
  bf16 h0 = (bf16)o0, h1 = (bf16)o1, h2 = (bf16)o2, h3 = (bf16)o3;
  oh[base + 0] = h0; oh[base + 1] = h1; oh[base + 2] = h2; oh[base + 3] = h3;
  if (ol) {
    ol[base + 0] = (bf16)(o0 - (float)h0);
    ol[base + 1] = (bf16)(o1 - (float)h1);
    ol[base + 2] = (bf16)(o2 - (float)h2);
    ol[base + 3] = (bf16)(o3 - (float)h3);
  }
}

// ---------------------------------------------------------------------------
// QKV GEMM (split): ln1[4096][1024] @ wqkvT -> qkv fp32 [4096][3072]
// ---------------------------------------------------------------------------
__global__ __launch_bounds__(256, 2) void k_gemm_qkv(
    const bf16* __restrict__ Ah, const bf16* __restrict__ Al,
    const bf16* __restrict__ Bh, const bf16* __restrict__ Bl,
    float* __restrict__ out)
{
  __shared__ __align__(16) bf16 As[2 * 128 * 32];
  __shared__ __align__(16) bf16 Bs[2 * 128 * 32];
  const int tid = threadIdx.x, lane = tid & 63, w = tid >> 6;
  const int fr = lane & 15, quad = lane >> 4;
  const int wm = w >> 1, wn = w & 1;
  const int m0 = blockIdx.y * 128, n0 = blockIdx.x * 128;
  const int lrow = w * 16 + (lane >> 2), colk = (lane & 3) * 8;
  long aOff0 = (long)(m0 + lrow) * D_MODEL + colk;
  long aOff1 = aOff0 + 64L * D_MODEL;
  long bOff0 = (long)(n0 + lrow) * D_MODEL + colk;
  long bOff1 = bOff0 + 64L * D_MODEL;
  f32x4 acc[4][4];
  f32x4 zv = {0.f, 0.f, 0.f, 0.f};
#pragma unroll
  for (int i = 0; i < 4; ++i)
#pragma unroll
    for (int j = 0; j < 4; ++j) acc[i][j] = zv;
  gemm_core<true>(Ah, Al, Bh, Bl, aOff0, aOff1, bOff0, bOff1, D_MODEL, As, Bs, acc);
#pragma unroll
  for (int mi = 0; mi < 4; ++mi)
#pragma unroll
    for (int ni = 0; ni < 4; ++ni) {
      const int col = n0 + wn * 64 + ni * 16 + fr;
#pragma unroll
      for (int r = 0; r < 4; ++r) {
        const int row = m0 + wm * 64 + mi * 16 + quad * 4 + r;
        out[(long)row * 3072 + col] = acc[mi][ni][r];
      }
    }
}

// ---------------------------------------------------------------------------
// RoPE + layout: qkv fp32 [tok][3072] -> q,k (rotated), v ; split hi/lo,
// head-major [bh][t][64]
// ---------------------------------------------------------------------------
__global__ __launch_bounds__(256) void k_rope(
    const float* __restrict__ qkv,
    bf16* __restrict__ qh, bf16* __restrict__ ql,
    bf16* __restrict__ kh, bf16* __restrict__ kl,
    bf16* __restrict__ vh, bf16* __restrict__ vl)
{
  const int tok = blockIdx.x;
  const int t = tok & (SEQ - 1), bb = tok >> 10;
  const int tid = threadIdx.x;
  const float ft = (float)t;
  for (int it = tid; it < 512; it += 256) {
    const int hh = it >> 5, i = it & 31;
    const float inv = powf(10000.0f, -(float)i * (1.0f / 32.0f));
    const float ang = ft * inv;
    float sn, cs;
    sincosf(ang, &sn, &cs);
    const long src = (long)tok * 3072 + hh * 64 + i;
    const float q0 = qkv[src], q1 = qkv[src + 32];
    const float k0 = qkv[src + 1024], k1 = qkv[src + 1024 + 32];
    const float qo0 = q0 * cs - q1 * sn, qo1 = q1 * cs + q0 * sn;
    const float ko0 = k0 * cs - k1 * sn, ko1 = k1 * cs + k0 * sn;
    const long dst = ((long)(bb * 16 + hh) * SEQ + t) * 64 + i;
    bf16 x;
    x = (bf16)qo0; qh[dst] = x;      ql[dst] = (bf16)(qo0 - (float)x);
    x = (bf16)qo1; qh[dst + 32] = x; ql[dst + 32] = (bf16)(qo1 - (float)x);
    x = (bf16)ko0; kh[dst] = x;      kl[dst] = (bf16)(ko0 - (float)x);
    x = (bf16)ko1; kh[dst + 32] = x; kl[dst + 32] = (bf16)(ko1 - (float)x);
  }
  for (int it = tid; it < 1024; it += 256) {
    const int hh = it >> 6, d = it & 63;
    const float vv = qkv[(long)tok * 3072 + 2048 + it];
    const long dst = ((long)(bb * 16 + hh) * SEQ + t) * 64 + d;
    bf16 x = (bf16)vv;
    vh[dst] = x; vl[dst] = (bf16)(vv - (float)x);
  }
}

// ---------------------------------------------------------------------------
// Flash attention (causal), split-precision QK^T and PV. Block = 64 q-rows.
// All LDS tiles XOR-swizzled; P tiles alias the read-once Q tiles (48KB LDS).
// ---------------------------------------------------------------------------
__global__ __launch_bounds__(256, 3) void k_flash(
    const bf16* __restrict__ qh, const bf16* __restrict__ ql,
    const bf16* __restrict__ kh, const bf16* __restrict__ kl,
    const bf16* __restrict__ vh, const bf16* __restrict__ vl,
    bf16* __restrict__ oh, bf16* __restrict__ ol)
{
  const int qt = blockIdx.x, bhid = blockIdx.y;
  const int tid = threadIdx.x, lane = tid & 63, w = tid >> 6;
  const int fr = lane & 15, quad = lane >> 4;
  __shared__ __align__(16) bf16 QP0[64 * 64];
  __shared__ __align__(16) bf16 QP1[64 * 64];
  __shared__ __align__(16) bf16 Kh[64 * 64], Kl[64 * 64];
  __shared__ __align__(16) bf16 Vh[64 * 64], Vl[64 * 64];

  const long qbase = ((long)bhid * SEQ + qt * 64) * 64;
  for (int c = tid; c < 512; c += 256) {
    const int row = c >> 3, c8 = (c & 7) << 3;
    *(uint4*)&QP0[swz(row, c8)] = *(const uint4*)&qh[qbase + row * 64 + c8];
    *(uint4*)&QP1[swz(row, c8)] = *(const uint4*)&ql[qbase + row * 64 + c8];
  }
  __syncthreads();
  bf16x8 aQh[2], aQl[2];
#pragma unroll
  for (int kk = 0; kk < 2; ++kk) {
    aQh[kk] = *(const bf16x8*)&QP0[swz(w * 16 + fr, kk * 32 + quad * 8)];
    aQl[kk] = *(const bf16x8*)&QP1[swz(w * 16 + fr, kk * 32 + quad * 8)];
  }
  f32x4 o[4];
  f32x4 zv = {0.f, 0.f, 0.f, 0.f};
#pragma unroll
  for (int ct = 0; ct < 4; ++ct) o[ct] = zv;
  float m_r[4], l_r[4];
#pragma unroll
  for (int r = 0; r < 4; ++r) { m_r[r] = -1e30f; l_r[r] = 0.f; }

  for (int kt = 0; kt <= qt; ++kt) {
    __syncthreads();
    const long kbase = ((long)bhid * SEQ + kt * 64) * 64;
    for (int c = tid; c < 512; c += 256) {
      const int row = c >> 3, c8 = (c & 7) << 3;
      *(uint4*)&Kh[swz(row, c8)] = *(const uint4*)&kh[kbase + row * 64 + c8];
      *(uint4*)&Kl[swz(row, c8)] = *(const uint4*)&kl[kbase + row * 64 + c8];
      uint4 uh = *(const uint4*)&vh[kbase + row * 64 + c8];
      uint4 ul = *(const uint4*)&vl[kbase + row * 64 + c8];
      const bf16* vph = (const bf16*)&uh;
      const bf16* vpl = (const bf16*)&ul;
#pragma unroll
      for (int j = 0; j < 8; ++j) {   // transpose V into [d][key], swizzled
        Vh[swz(c8 + j, row)] = vph[j];
        Vl[swz(c8 + j, row)] = vpl[j];
      }
    }
    __syncthreads();

    f32x4 s[4];
#pragma unroll
    for (int nt = 0; nt < 4; ++nt) s[nt] = zv;
#pragma unroll
    for (int nt = 0; nt < 4; ++nt)
#pragma unroll
      for (int kk = 0; kk < 2; ++kk) {
        bf16x8 bh8 = *(const bf16x8*)&Kh[swz(nt * 16 + fr, kk * 32 + quad * 8)];
        bf16x8 bl8 = *(const bf16x8*)&Kl[swz(nt * 16 + fr, kk * 32 + quad * 8)];
        s[nt] = mfma16(aQh[kk], bh8, s[nt]);
        s[nt] = mfma16(aQl[kk], bh8, s[nt]);
        s[nt] = mfma16(aQh[kk], bl8, s[nt]);
      }
    const int qloc = w * 16 + quad * 4;  // + r
#pragma unroll
    for (int nt = 0; nt < 4; ++nt)
#pragma unroll
      for (int r = 0; r < 4; ++r) {
        float sv = s[nt][r] * 0.125f;
        if (kt == qt && (nt * 16 + fr) > (qloc + r)) sv = -1e30f;
        s[nt][r] = sv;
      }
    float al4[4];
#pragma unroll
    for (int r = 0; r < 4; ++r) {
      float m = fmaxf(fmaxf(s[0][r], s[1][r]), fmaxf(s[2][r], s[3][r]));
#pragma unroll
      for (int off = 1; off < 16; off <<= 1) m = fmaxf(m, __shfl_xor(m, off));
      const float mn = fmaxf(m_r[r], m);
      al4[r] = expf(m_r[r] - mn);
      m_r[r] = mn;
    }
    float pmat[4][4], ls4[4];
#pragma unroll
    for (int r = 0; r < 4; ++r) ls4[r] = 0.f;
#pragma unroll
    for (int nt = 0; nt < 4; ++nt)
#pragma unroll
      for (int r = 0; r < 4; ++r) {
        const float p = expf(s[nt][r] - m_r[r]);
        pmat[nt][r] = p;
        ls4[r] += p;
      }
#pragma unroll
    for (int r = 0; r < 4; ++r) {
      float l = ls4[r];
#pragma unroll
      for (int off = 1; off < 16; off <<= 1) l += __shfl_xor(l, off);
      l_r[r] = l_r[r] * al4[r] + l;
      o[0][r] *= al4[r]; o[1][r] *= al4[r]; o[2][r] *= al4[r]; o[3][r] *= al4[r];
    }
    bf16* Pw0 = QP0 + w * 1024;
    bf16* Pw1 = QP1 + w * 1024;
#pragma unroll
    for (int nt = 0; nt < 4; ++nt)
#pragma unroll
      for (int r = 0; r < 4; ++r) {
        const float p = pmat[nt][r];
        bf16 hh2 = (bf16)p;
        Pw0[swz(quad * 4 + r, nt * 16 + fr)] = hh2;
        Pw1[swz(quad * 4 + r, nt * 16 + fr)] = (bf16)(p - (float)hh2);
      }
    __syncthreads();
#pragma unroll
    for (int kk = 0; kk < 2; ++kk) {
      bf16x8 aPh = *(const bf16x8*)&Pw0[swz(fr, kk * 32 + quad * 8)];
      bf16x8 aPl = *(const bf16x8*)&Pw1[swz(fr, kk * 32 + quad * 8)];
#pragma unroll
      for (int ct = 0; ct < 4; ++ct) {
        bf16x8 bVh = *(const bf16x8*)&Vh[swz(ct * 16 + fr, kk * 32 + quad * 8)];
        bf16x8 bVl = *(const bf16x8*)&Vl[swz(ct * 16 + fr, kk * 32 + quad * 8)];
        o[ct] = mfma16(aPh, bVh, o[ct]);
        o[ct] = mfma16(aPl, bVh, o[ct]);
        o[ct] = mfma16(aPh, bVl, o[ct]);
      }
    }
  }
  const int b_ = bhid >> 4, h_ = bhid & 15;
#pragma unroll
  for (int ct = 0; ct < 4; ++ct)
#pragma unroll
    for (int r = 0; r < 4; ++r) {
      const int tokn = b_ * SEQ + qt * 64 + w * 16 + quad * 4 + r;
      const int col = h_ * 64 + ct * 16 + fr;
      const float val = o[ct][r] / l_r[r];
      bf16 hh3 = (bf16)val;
      oh[(long)tokn * D_MODEL + col] = hh3;
      ol[(long)tokn * D_MODEL + col] = (bf16)(val - (float)hh3);
    }
}

// ---------------------------------------------------------------------------
// Proj GEMM (split) + bias + residual -> d_out fp32 (= x1)
// ---------------------------------------------------------------------------
__global__ __launch_bounds__(256, 2) void k_gemm_proj(
    const bf16* __restrict__ Ah, const bf16* __restrict__ Al,
    const bf16* __restrict__ Bh, const bf16* __restrict__ Bl,
    const float* __restrict__ bproj, const float* __restrict__ xin,
    float* __restrict__ out)
{
  __shared__ __align__(16) bf16 As[2 * 128 * 32];
  __shared__ __align__(16) bf16 Bs[2 * 128 * 32];
  const int tid = threadIdx.x, lane = tid & 63, w = tid >> 6;
  const int fr = lane & 15, quad = lane >> 4;
  const int wm = w >> 1, wn = w & 1;
  const int m0 = blockIdx.y * 128, n0 = blockIdx.x * 128;
  const int lrow = w * 16 + (lane >> 2), colk = (lane & 3) * 8;
  long aOff0 = (long)(m0 + lrow) * D_MODEL + colk;
  long aOff1 = aOff0 + 64L * D_MODEL;
  long bOff0 = (long)(n0 + lrow) * D_MODEL + colk;
  long bOff1 = bOff0 + 64L * D_MODEL;
  f32x4 acc[4][4];
  f32x4 zv = {0.f, 0.f, 0.f, 0.f};
#pragma unroll
  for (int i = 0; i < 4; ++i)
#pragma unroll
    for (int j = 0; j < 4; ++j) acc[i][j] = zv;
  gemm_core<true>(Ah, Al, Bh, Bl, aOff0, aOff1, bOff0, bOff1, D_MODEL, As, Bs, acc);
#pragma unroll
  for (int mi = 0; mi < 4; ++mi)
#pragma unroll
    for (int ni = 0; ni < 4; ++ni) {
      const int col = n0 + wn * 64 + ni * 16 + fr;
#pragma unroll
      for (int r = 0; r < 4; ++r) {
        const int row = m0 + wm * 64 + mi * 16 + quad * 4 + r;
        out[(long)row * D_MODEL + col] =
            acc[mi][ni][r] + bproj[col] + xin[(long)row * D_MODEL + col];
      }
    }
}

// ---------------------------------------------------------------------------
// Router: own fp32 LN of x1, fp32 logits, softmax, strict top-2.
// ---------------------------------------------------------------------------
__global__ __launch_bounds__(256) void k_router(
    const float* __restrict__ x1, const float* __restrict__ g,
    const float* __restrict__ b, const float* __restrict__ wr,
    int2* __restrict__ topi, float2* __restrict__ topg,
    float* __restrict__ pbuf)
{
  const int tok = blockIdx.x, tid = threadIdx.x;
  const float4 v = ((const float4*)(x1 + (long)tok * D_MODEL))[tid];
  float s  = v.x + v.y + v.z + v.w;
  float s2 = v.x * v.x + v.y * v.y + v.z * v.z + v.w * v.w;
#pragma unroll
  for (int off = 1; off < 64; off <<= 1) {
    s  += __shfl_xor(s, off);
    s2 += __shfl_xor(s2, off);
  }
  __shared__ float red[8];
  __shared__ float lr[4][8];
  if ((tid & 63) == 0) { red[tid >> 6] = s; red[4 + (tid >> 6)] = s2; }
  __syncthreads();
  s  = red[0] + red[1] + red[2] + red[3];
  s2 = red[4] + red[5] + red[6] + red[7];
  const float mu   = s * (1.0f / D_MODEL);
  const float var  = s2 * (1.0f / D_MODEL) - mu * mu;
  const float rstd = 1.0f / sqrtf(var + 1e-5f);
  const float4 gg = ((const float4*)g)[tid];
  const float4 bb = ((const float4*)b)[tid];
  float n4[4];
  n4[0] = (v.x - mu) * rstd * gg.x + bb.x;
  n4[1] = (v.y - mu) * rstd * gg.y + bb.y;
  n4[2] = (v.z - mu) * rstd * gg.z + bb.z;
  n4[3] = (v.w - mu) * rstd * gg.w + bb.w;
  float part[8];
#pragma unroll
  for (int e = 0; e < 8; ++e) part[e] = 0.f;
  const float* wrow = wr + (long)tid * 4 * 8;
#pragma unroll
  for (int c = 0; c < 4; ++c)
#pragma unroll
    for (int e = 0; e < 8; ++e) part[e] += n4[c] * wrow[c * 8 + e];
#pragma unroll
  for (int off = 1; off < 64; off <<= 1)
#pragma unroll
    for (int e = 0; e < 8; ++e) part[e] += __shfl_xor(part[e], off);
  if ((tid & 63) == 0)
#pragma unroll
    for (int e = 0; e < 8; ++e) lr[tid >> 6][e] = part[e];
  __syncthreads();
  if (tid == 0) {
    float lg[8];
#pragma unroll
    for (int e = 0; e < 8; ++e) lg[e] = lr[0][e] + lr[1][e] + lr[2][e] + lr[3][e];
    float mx = lg[0];
#pragma unroll
    for (int e = 1; e < 8; ++e) mx = fmaxf(mx, lg[e]);
    float pe[8], ssum = 0.f;
#pragma unroll
    for (int e = 0; e < 8; ++e) { pe[e] = expf(lg[e] - mx); ssum += pe[e]; }
    const float inv = 1.0f / ssum;
    int i1 = -1, i2 = -1;
    float v1 = -1.f, v2 = -1.f;
#pragma unroll
    for (int e = 0; e < 8; ++e) {
      const float p = pe[e] * inv;
      pbuf[(long)tok * 8 + e] = p;
      if (p > v1)      { v2 = v1; i2 = i1; v1 = p; i1 = e; }
      else if (p > v2) { v2 = p; i2 = e; }
    }
    const float wsum = v1 + v2;
    topi[tok] = make_int2(i1, i2);
    topg[tok] = make_float2(v1 / wsum, v2 / wsum);
  }
}

// ---------------------------------------------------------------------------
// Scatter: build per-expert token lists + per-token ranks (pos).
// ---------------------------------------------------------------------------
__global__ __launch_bounds__(256) void k_scatter(
    const int2* __restrict__ topi,
    int* __restrict__ ecnt, int* __restrict__ perm, int2* __restrict__ pos)
{
  __shared__ int hcnt[NEXP];
  __shared__ int hbase[NEXP];
  const int tid = threadIdx.x;
  const int tok = blockIdx.x * 256 + tid;
  if (tid < NEXP) hcnt[tid] = 0;
  __syncthreads();
  const int2 ti = topi[tok];
  const int r1 = atomicAdd(&hcnt[ti.x], 1);
  const int r2 = atomicAdd(&hcnt[ti.y], 1);
  __syncthreads();
  if (tid < NEXP) hbase[tid] = atomicAdd(&ecnt[tid], hcnt[tid]);
  __syncthreads();
  const int p1 = hbase[ti.x] + r1;
  perm[ti.x * NTOK + p1] = tok;
  const int p2 = hbase[ti.y] + r2;
  perm[ti.y * NTOK + p2] = tok;
  pos[tok] = make_int2(p1, p2);
}

// ---------------------------------------------------------------------------
// Finalize: reduce pbuf -> psum, compute eoff + aux loss.
// ---------------------------------------------------------------------------
__global__ __launch_bounds__(256) void k_finalize(
    const int* __restrict__ ecnt, const float* __restrict__ pbuf,
    int* __restrict__ eoff, float* __restrict__ aux_out)
{
  __shared__ float partial[256];
  const int tid = threadIdx.x;
  const int e = tid & 7, i0 = tid >> 3;
  float sum = 0.f;
  for (int i = i0; i < NTOK; i += 32) sum += pbuf[(long)i * 8 + e];
  partial[tid] = sum;
  __syncthreads();
  if (tid < 8) {
    float ps = 0.f;
#pragma unroll
    for (int j = 0; j < 32; ++j) ps += partial[j * 8 + tid];
    partial[tid] = ps;   // psum[e]
  }
  __syncthreads();
  if (tid == 0) {
    int off = 0;
    float aux = 0.f;
    for (int e2 = 0; e2 < 8; ++e2) {
      eoff[e2] = off;
      off += (ecnt[e2] + 127) & ~127;
      aux += ((float)ecnt[e2] * (1.0f / (NTOK * 2.0f))) * (partial[e2] * (1.0f / NTOK));
    }
    aux_out[0] = 8.0f * aux;
  }
}

// ---------------------------------------------------------------------------
// FFN1: gathered ln2 rows @ w1T[e] + b1 -> exact GELU -> h (bf16)
// ---------------------------------------------------------------------------
__global__ __launch_bounds__(256, 2) void k_gemm_ffn1(
    const bf16* __restrict__ A, const bf16* __restrict__ w1t,
    const float* __restrict__ b1, const int* __restrict__ ecnt,
    const int* __restrict__ eoff, const int* __restrict__ perm,
    bf16* __restrict__ h)
{
  const int e = blockIdx.y >> 5, mt = blockIdx.y & 31;
  const int cnt = ecnt[e];
  if (mt * 128 >= cnt) return;
  __shared__ __align__(16) bf16 As[2 * 128 * 32];
  __shared__ __align__(16) bf16 Bs[2 * 128 * 32];
  const int tid = threadIdx.x, lane = tid & 63, w = tid >> 6;
  const int fr = lane & 15, quad = lane >> 4;
  const int wm = w >> 1, wn = w & 1;
  const int n0 = blockIdx.x * 128;
  const int lrow = w * 16 + (lane >> 2), colk = (lane & 3) * 8;
  int i0 = mt * 128 + lrow;
  int i1 = i0 + 64;
  i0 = min(i0, cnt - 1);
  i1 = min(i1, cnt - 1);
  const int* pe = perm + e * NTOK;
  long aOff0 = (long)pe[i0] * D_MODEL + colk;
  long aOff1 = (long)pe[i1] * D_MODEL + colk;
  const bf16* B = w1t + (long)e * DFF * D_MODEL;
  long bOff0 = (long)(n0 + lrow) * D_MODEL + colk;
  long bOff1 = bOff0 + 64L * D_MODEL;
  f32x4 acc[4][4];
  f32x4 zv = {0.f, 0.f, 0.f, 0.f};
#pragma unroll
  for (int i = 0; i < 4; ++i)
#pragma unroll
    for (int j = 0; j < 4; ++j) acc[i][j] = zv;
  gemm_core<false>(A, A, B, B, aOff0, aOff1, bOff0, bOff1, D_MODEL, As, Bs, acc);
  const int hbase = eoff[e] + mt * 128;
#pragma unroll
  for (int mi = 0; mi < 4; ++mi)
#pragma unroll
    for (int ni = 0; ni < 4; ++ni) {
      const int col = n0 + wn * 64 + ni * 16 + fr;
#pragma unroll
      for (int r = 0; r < 4; ++r) {
        const int irow = wm * 64 + mi * 16 + quad * 4 + r;
        const float vv = acc[mi][ni][r] + b1[e * DFF + col];
        const float ge = 0.5f * vv * (1.0f + erff(vv * 0.70710678118654752f));
        h[(long)(hbase + irow) * DFF + col] = (bf16)ge;
      }
    }
}

// ---------------------------------------------------------------------------
// FFN2 (split-K=2 via blockIdx.z): h rows @ w2T[e] halves -> fp32 partials in
// ybuf[z] (plain coalesced stores; bias folded into z==0 partial)
// ---------------------------------------------------------------------------
__global__ __launch_bounds__(256, 2) void k_gemm_ffn2(
    const bf16* __restrict__ hbuf, const bf16* __restrict__ w2t,
    const float* __restrict__ b2, const int* __restrict__ ecnt,
    const int* __restrict__ eoff, float* __restrict__ ybuf)
{
  const int e = blockIdx.y >> 5, mt = blockIdx.y & 31;
  const int cnt = ecnt[e];
  if (mt * 128 >= cnt) return;
  __shared__ __align__(16) bf16 As[2 * 128 * 32];
  __shared__ __align__(16) bf16 Bs[2 * 128 * 32];
  const int tid = threadIdx.x, lane = tid & 63, w = tid >> 6;
  const int fr = lane & 15, quad = lane >> 4;
  const int wm = w >> 1, wn = w & 1;
  const int n0 = blockIdx.x * 128;
  const int z = blockIdx.z;
  const long kOff = (long)z * (DFF / 2);
  const int lrow = w * 16 + (lane >> 2), colk = (lane & 3) * 8;
  const int rbase = eoff[e] + mt * 128;
  const bf16* A = hbuf + (long)rbase * DFF;
  long aOff0 = (long)lrow * DFF + colk + kOff;
  long aOff1 = aOff0 + 64L * DFF;
  const bf16* B = w2t + (long)e * D_MODEL * DFF;
  long bOff0 = (long)(n0 + lrow) * DFF + colk + kOff;
  long bOff1 = bOff0 + 64L * DFF;
  f32x4 acc[4][4];
  f32x4 zv = {0.f, 0.f, 0.f, 0.f};
#pragma unroll
  for (int i = 0; i < 4; ++i)
#pragma unroll
    for (int j = 0; j < 4; ++j) acc[i][j] = zv;
  gemm_core<false>(A, A, B, B, aOff0, aOff1, bOff0, bOff1, DFF / 2, As, Bs, acc);
  float* yb = ybuf + (long)z * YSTRIDE;
#pragma unroll
  for (int mi = 0; mi < 4; ++mi)
#pragma unroll
    for (int ni = 0; ni < 4; ++ni) {
      const int col = n0 + wn * 64 + ni * 16 + fr;
      const float bias = (z == 0) ? b2[e * D_MODEL + col] : 0.0f;
#pragma unroll
      for (int r = 0; r < 4; ++r) {
        const int irow = wm * 64 + mi * 16 + quad * 4 + r;
        yb[(long)(rbase + irow) * D_MODEL + col] = acc[mi][ni][r] + bias;
      }
    }
}

// ---------------------------------------------------------------------------
// Combine: out[tok] += g1*(y0[row1]+y1[row1]) + g2*(y0[row2]+y1[row2])
// ---------------------------------------------------------------------------
__global__ __launch_bounds__(256) void k_combine(
    const int2* __restrict__ topi, const float2* __restrict__ topg,
    const int2* __restrict__ pos, const int* __restrict__ eoff,
    const float* __restrict__ ybuf, float* __restrict__ out)
{
  const int tok = blockIdx.x, tid = threadIdx.x;
  const int2 ti = topi[tok];
  const int2 pp = pos[tok];
  const float2 tg = topg[tok];
  const long r1 = (long)eoff[ti.x] + pp.x;
  const long r2 = (long)eoff[ti.y] + pp.y;
  const float4 y1a = ((const float4*)(ybuf + r1 * D_MODEL))[tid];
  const float4 y1b = ((const float4*)(ybuf + YSTRIDE + r1 * D_MODEL))[tid];
  const float4 y2a = ((const float4*)(ybuf + r2 * D_MODEL))[tid];
  const float4 y2b = ((const float4*)(ybuf + YSTRIDE + r2 * D_MODEL))[tid];
  float4* po = (float4*)(out + (long)tok * D_MODEL) + tid;
  float4 o = *po;
  o.x += tg.x * (y1a.x + y1b.x) + tg.y * (y2a.x + y2b.x);
  o.y += tg.x * (y1a.y + y1b.y) + tg.y * (y2a.y + y2b.y);
  o.z += tg.x * (y1a.z + y1b.z) + tg.y * (y2a.z + y2b.z);
  o.w += tg.x * (y1a.w + y1b.w) + tg.y * (y2a.w + y2b.w);
  *po = o;
}

// ---------------------------------------------------------------------------
extern "C" void kernel_launch(void* const* d_in, const int* in_sizes, int n_in,
                              void* d_out, int out_size, void* d_ws, size_t ws_size,
                              hipStream_t stream) {
  const float* x     = (const float*)d_in[0];
  // d_in[1] = mask (causal structure reproduced in-kernel)
  const float* ln1g  = (const float*)d_in[2];
  const float* ln1b  = (const float*)d_in[3];
  const float* wqkv  = (const float*)d_in[4];
  const float* wproj = (const float*)d_in[5];
  const float* bproj = (const float*)d_in[6];
  const float* ln2g  = (const float*)d_in[7];
  const float* ln2b  = (const float*)d_in[8];
  const float* wrout = (const float*)d_in[9];
  const float* w1    = (const float*)d_in[10];
  const float* b1    = (const float*)d_in[11];
  const float* w2    = (const float*)d_in[12];
  const float* b2    = (const float*)d_in[13];
  float* out = (float*)d_out;

  char* p = (char*)d_ws;
  auto alloc = [&](size_t n) { char* r = p; p += (n + 255) & ~(size_t)255; return r; };

  bf16* wqkvT_h = (bf16*)alloc(3072L * 1024 * 2);
  bf16* wqkvT_l = (bf16*)alloc(3072L * 1024 * 2);
  bf16* wprojT_h = (bf16*)alloc(1024L * 1024 * 2);
  bf16* wprojT_l = (bf16*)alloc(1024L * 1024 * 2);
  bf16* w1T = (bf16*)alloc(8L * 4096 * 1024 * 2);
  bf16* w2T = (bf16*)alloc(8L * 1024 * 4096 * 2);
  bf16* ln_h = (bf16*)alloc(4096L * 1024 * 2);  // ln1 then reused for ln2
  bf16* ln_l = (bf16*)alloc(4096L * 1024 * 2);
  bf16* attn_h = (bf16*)alloc(4096L * 1024 * 2);
  bf16* attn_l = (bf16*)alloc(4096L * 1024 * 2);
  int*   perm  = (int*)alloc(8L * 4096 * 4);
  int2*  topi  = (int2*)alloc(4096L * 8);
  float2* topg = (float2*)alloc(4096L * 8);
  int2*  pos   = (int2*)alloc(4096L * 8);
  float* pbuf  = (float*)alloc(4096L * 8 * 4);
  char*  ctrl  = alloc(256);                 // ecnt[8] | eoff[8]
  int*   ecnt  = (int*)ctrl;
  int*   eoff  = (int*)(ctrl + 64);
  float* ybuf  = (float*)alloc(2L * YSTRIDE * 4);      // fp32 FFN2 split-K partials
  // big overlay region: [qkv fp32 48MB | rope hi/lo bufs 48MB] then h (73MB)
  char* big = alloc(100663296);
  float* qkvf = (float*)big;                           // 4096*3072*4
  bf16* qh = (bf16*)(big + 50331648);
  bf16* ql = qh + 4194304;
  bf16* kh = ql + 4194304;
  bf16* kl = kh + 4194304;
  bf16* vh = kl + 4194304;
  bf16* vl = vh + 4194304;
  bf16* hbuf = (bf16*)big;                             // 9216*4096*2, after attn

  dim3 blk(256);

  // 1) weight transpose + cast
  k_transpose_cast<<<dim3(3072 / 32, 1024 / 32, 1), blk, 0, stream>>>(wqkv, wqkvT_h, wqkvT_l, 1024, 3072);
  k_transpose_cast<<<dim3(1024 / 32, 1024 / 32, 1), blk, 0, stream>>>(wproj, wprojT_h, wprojT_l, 1024, 1024);
  k_transpose_cast<<<dim3(4096 / 32, 1024 / 32, 8), blk, 0, stream>>>(w1, w1T, nullptr, 1024, 4096);
  k_transpose_cast<<<dim3(1024 / 32, 4096 / 32, 8), blk, 0, stream>>>(w2, w2T, nullptr, 4096, 1024);
  hipMemsetAsync(ctrl, 0, 256, stream);

  // 2) attention path (split precision)
  k_layernorm<<<4096, blk, 0, stream>>>(x, ln1g, ln1b, ln_h, ln_l);
  k_gemm_qkv<<<dim3(24, 32), blk, 0, stream>>>(ln_h, ln_l, wqkvT_h, wqkvT_l, qkvf);
  k_rope<<<4096, blk, 0, stream>>>(qkvf, qh, ql, kh, kl, vh, vl);
  k_flash<<<dim3(16, 64), blk, 0, stream>>>(qh, ql, kh, kl, vh, vl, attn_h, attn_l);
  k_gemm_proj<<<dim3(8, 32), blk, 0, stream>>>(attn_h, attn_l, wprojT_h, wprojT_l, bproj, x, out);

  // 3) MoE
  k_layernorm<<<4096, blk, 0, stream>>>(out, ln2g, ln2b, ln_h, nullptr);
  k_router<<<4096, blk, 0, stream>>>(out, ln2g, ln2b, wrout, topi, topg, pbuf);
  k_scatter<<<16, blk, 0, stream>>>(topi, ecnt, perm, pos);
  k_finalize<<<1, blk, 0, stream>>>(ecnt, pbuf, eoff, out + 4194304);
  k_gemm_ffn1<<<dim3(32, 256), blk, 0, stream>>>(ln_h, w1T, b1, ecnt, eoff, perm, hbuf);
  k_gemm_ffn2<<<dim3(8, 256, 2), blk, 0, stream>>>(hbuf, w2T, b2, ecnt, eoff, ybuf);
  k_combine<<<4096, blk, 0, stream>>>(topi, topg, pos, eoff, ybuf, out);
}

// Round 4
// 1015.578 us; speedup vs baseline: 1.0900x; 1.0311x over previous
//
#include <hip/hip_runtime.h>
#include <math.h>

// ---------------------------------------------------------------------------
// TransformerBlock: x + attn(LN1(x)) -> x1 ; x1 + top2-MoE(LN2(x1)) ; aux loss
// R6: flash de-VALU-ified. Was 173us @ VALUBusy 21% / MfmaUtil 6% / 5.1M
// conflicts: 32 scalar ds_write_b16 per thread per kt (in-loop V transpose)
// + reg-staged K/V + a removable barrier.
//  * k_vtrans: V transposed ONCE to vT[bh][d][t] (hi/lo) via LDS-tiled
//    transpose kernel; k_rope no longer writes row-major V.
//  * flash stages Q/K/VT via global_load_lds (16B) with PRE-SWIZZLED global
//    source chunks (linear LDS dest + src chunk j^f(row)) reproducing the
//    exact swz() layout the fragment reads expect. No reg round-trip.
//  * 3rd barrier dropped: P is per-wave LDS + DS-ops in-order per wave;
//    sched_barrier(0) pins compiler order.
// R5 (kept): dbuf gemm_core, ffn2 split-K. R4: de-atomicized ffn2 epilogue.
// ---------------------------------------------------------------------------

typedef __bf16 bf16;
typedef __bf16 bf16x8 __attribute__((ext_vector_type(8)));
typedef float  f32x4  __attribute__((ext_vector_type(4)));

#define D_MODEL 1024
#define SEQ     1024
#define NTOK    4096
#define DFF     4096
#define NEXP    8
#define YSTRIDE (9216L * 1024)

__device__ __forceinline__ f32x4 mfma16(bf16x8 a, bf16x8 b, f32x4 c) {
  return __builtin_amdgcn_mfma_f32_16x16x32_bf16(a, b, c, 0, 0, 0);
}

__device__ __forceinline__ void async_cp16(void* lds, const void* g) {
  __builtin_amdgcn_global_load_lds(
      (__attribute__((address_space(1))) void*)(void*)g,
      (__attribute__((address_space(3))) void*)lds, 16, 0, 0);
}

// Bank-conflict-free index into a [R][64] bf16 LDS tile (flash tiles).
__device__ __forceinline__ int swz(int row, int col) {
  return row * 64 + (col ^ (((row ^ (row >> 3)) & 7) << 3));
}

// ---------------------------------------------------------------------------
// Shared MFMA GEMM core, double-buffered (see R5 header comment).
// ---------------------------------------------------------------------------
template<bool SPLIT>
__device__ __forceinline__ void gemm_core(
    const bf16* __restrict__ Ahi, const bf16* __restrict__ Alo,
    const bf16* __restrict__ Bhi, const bf16* __restrict__ Blo,
    long aOff0, long aOff1, long bOff0, long bOff1,
    int K, bf16* As, bf16* Bs, f32x4 acc[4][4])
{
  const int tid  = threadIdx.x;
  const int lane = tid & 63, w = tid >> 6;
  const int fr   = lane & 15, quad = lane >> 4;
  const int wm   = w >> 1,    wn   = w & 1;
  const int ldst0 = (w * 16) * 32;
  const int ldst1 = (64 + w * 16) * 32;
  const int ksteps = K >> 5;
  const int nsteps = (SPLIT ? 3 : 1) * ksteps;

  auto stage = [&](int s, int buf) {
    const int ph = SPLIT ? (s / ksteps) : 0;
    const int k0 = (SPLIT ? (s - ph * ksteps) : s) << 5;
    const bf16* Ap = (ph == 1) ? Alo : Ahi;
    const bf16* Bp = (ph == 2) ? Blo : Bhi;
    bf16* Ab = As + buf * (128 * 32);
    bf16* Bb = Bs + buf * (128 * 32);
    async_cp16(Ab + ldst0, Ap + aOff0 + k0);
    async_cp16(Ab + ldst1, Ap + aOff1 + k0);
    async_cp16(Bb + ldst0, Bp + bOff0 + k0);
    async_cp16(Bb + ldst1, Bp + bOff1 + k0);
  };

  stage(0, 0);
  __syncthreads();
  int cur = 0;
  for (int s = 0; s < nsteps; ++s) {
    if (s + 1 < nsteps) stage(s + 1, cur ^ 1);
    const bf16* Ab = As + cur * (128 * 32);
    const bf16* Bb = Bs + cur * (128 * 32);
    bf16x8 af[4], bfv[4];
#pragma unroll
    for (int mi = 0; mi < 4; ++mi)
      af[mi] = *(const bf16x8*)&Ab[(wm * 64 + mi * 16 + fr) * 32 + quad * 8];
#pragma unroll
    for (int ni = 0; ni < 4; ++ni)
      bfv[ni] = *(const bf16x8*)&Bb[(wn * 64 + ni * 16 + fr) * 32 + quad * 8];
#pragma unroll
    for (int mi = 0; mi < 4; ++mi)
#pragma unroll
      for (int ni = 0; ni < 4; ++ni)
        acc[mi][ni] = mfma16(af[mi], bfv[ni], acc[mi][ni]);
    __syncthreads();
    cur ^= 1;
  }
}

// ---------------------------------------------------------------------------
// Weight transpose + fp32->bf16(hi[,lo]) cast: in [Z][K][N] -> out [Z][N][K]
// ---------------------------------------------------------------------------
__global__ void k_transpose_cast(const float* __restrict__ in,
                                 bf16* __restrict__ oh, bf16* __restrict__ ol,
                                 int K, int N)
{
  const long zo = (long)blockIdx.z * K * N;
  __shared__ float tile[32][33];
  const int tx = threadIdx.x & 31, ty = threadIdx.x >> 5;
  const int r0 = blockIdx.y * 32, c0 = blockIdx.x * 32;
#pragma unroll
  for (int j = 0; j < 4; ++j)
    tile[ty + 8 * j][tx] = in[zo + (long)(r0 + ty + 8 * j) * N + (c0 + tx)];
  __syncthreads();
#pragma unroll
  for (int j = 0; j < 4; ++j) {
    float v = tile[tx][ty + 8 * j];
    long  o = zo + (long)(c0 + ty + 8 * j) * K + (r0 + tx);
    bf16 hh = (bf16)v;
    oh[o] = hh;
    if (ol) ol[o] = (bf16)(v - (float)hh);
  }
}

// ---------------------------------------------------------------------------
// V transpose: qkv fp32 [tok][3072] (V at +2048) -> vT hi/lo [bh][64][SEQ]
// ---------------------------------------------------------------------------
__global__ __launch_bounds__(256) void k_vtrans(
    const float* __restrict__ qkv,
    bf16* __restrict__ vth, bf16* __restrict__ vtl)
{
  __shared__ float tile[32][33];
  const int tx = threadIdx.x & 31, ty = threadIdx.x >> 5;
  const int bh = blockIdx.z;            // bb*16 + hh
  const int bb = bh >> 4, hh = bh & 15;
  const int t0 = blockIdx.x * 32, d0 = blockIdx.y * 32;
#pragma unroll
  for (int j = 0; j < 4; ++j) {
    const int t = t0 + ty + 8 * j;
    tile[ty + 8 * j][tx] =
        qkv[(long)(bb * SEQ + t) * 3072 + 2048 + hh * 64 + d0 + tx];
  }
  __syncthreads();
#pragma unroll
  for (int j = 0; j < 4; ++j) {
    const int d = d0 + ty + 8 * j;
    const float v = tile[tx][ty + 8 * j];
    const long o = ((long)bh * 64 + d) * SEQ + t0 + tx;
    bf16 h2 = (bf16)v;
    vth[o] = h2;
    vtl[o] = (bf16)(v - (float)h2);
  }
}

// ---------------------------------------------------------------------------
// LayerNorm: one block per token, writes bf16 hi (and lo if non-null)
// ---------------------------------------------------------------------------
__global__ __launch_bounds__(256) void k_layernorm(
    const float* __restrict__ x, const float* __restrict__ g,
    const float* __restrict__ b, bf16* __restrict__ oh, bf16* __restrict__ ol)
{
  const int tok = blockIdx.x, tid = threadIdx.x;
  const float4 v = ((const float4*)(x + (long)tok * D_MODEL))[tid];
  float s  = v.x + v.y + v.z + v.w;
  float s2 = v.x * v.x + v.y * v.y + v.z * v.z + v.w * v.w;
#pragma unroll
  for (int off = 1; off < 64; off <<= 1) {
    s  += __shfl_xor(s, off);
    s2 += __shfl_xor(s2, off);
  }
  __shared__ float red[8];
  if ((tid & 63) == 0) { red[tid >> 6] = s; red[4 + (tid >> 6)] = s2; }
  __syncthreads();
  s  = red[0] + red[1] + red[2] + red[3];
  s2 = red[4] + red[5] + red[6] + red[7];
  const float mu   = s * (1.0f / D_MODEL);
  const float var  = s2 * (1.0f / D_MODEL) - mu * mu;
  const float rstd = 1.0f / sqrtf(var + 1e-5f);
  const float4 gg = ((const float4*)g)[tid];
  const float4 bb = ((const float4*)b)[tid];
  float o0 = (v.x - mu) * rstd * gg.x + bb.x;
  float o1 = (v.y - mu) * rstd * gg.y + bb.y;
  float o2 = (v.z - mu) * rstd * gg.z + bb.z;
  float o3 = (v.w - mu) * rstd * gg.w + bb.w;
  const long base = (long)tok * D_MODEL + tid * 4;
  bf16 h0 = (bf16)o0, h1 = (bf16)o1, h2 = (bf16)o2, h3 = (bf16)o3;
  oh[base + 0] = h0; oh[base + 1] = h1; oh[base + 2] = h2; oh[base + 3] = h3;
  if (ol) {
    ol[base + 0] = (bf16)(o0 - (float)h0);
    ol[base + 1] = (bf16)(o1 - (float)h1);
    ol[base + 2] = (bf16)(o2 - (float)h2);
    ol[base + 3] = (bf16)(o3 - (float)h3);
  }
}

// ---------------------------------------------------------------------------
// QKV GEMM (split): ln1[4096][1024] @ wqkvT -> qkv fp32 [4096][3072]
// ---------------------------------------------------------------------------
__global__ __launch_bounds__(256, 2) void k_gemm_qkv(
    const bf16* __restrict__ Ah, const bf16* __restrict__ Al,
    const bf16* __restrict__ Bh, const bf16* __restrict__ Bl,
    float* __restrict__ out)
{
  __shared__ __align__(16) bf16 As[2 * 128 * 32];
  __shared__ __align__(16) bf16 Bs[2 * 128 * 32];
  const int tid = threadIdx.x, lane = tid & 63, w = tid >> 6;
  const int fr = lane & 15, quad = lane >> 4;
  const int wm = w >> 1, wn = w & 1;
  const int m0 = blockIdx.y * 128, n0 = blockIdx.x * 128;
  const int lrow = w * 16 + (lane >> 2), colk = (lane & 3) * 8;
  long aOff0 = (long)(m0 + lrow) * D_MODEL + colk;
  long aOff1 = aOff0 + 64L * D_MODEL;
  long bOff0 = (long)(n0 + lrow) * D_MODEL + colk;
  long bOff1 = bOff0 + 64L * D_MODEL;
  f32x4 acc[4][4];
  f32x4 zv = {0.f, 0.f, 0.f, 0.f};
#pragma unroll
  for (int i = 0; i < 4; ++i)
#pragma unroll
    for (int j = 0; j < 4; ++j) acc[i][j] = zv;
  gemm_core<true>(Ah, Al, Bh, Bl, aOff0, aOff1, bOff0, bOff1, D_MODEL, As, Bs, acc);
#pragma unroll
  for (int mi = 0; mi < 4; ++mi)
#pragma unroll
    for (int ni = 0; ni < 4; ++ni) {
      const int col = n0 + wn * 64 + ni * 16 + fr;
#pragma unroll
      for (int r = 0; r < 4; ++r) {
        const int row = m0 + wm * 64 + mi * 16 + quad * 4 + r;
        out[(long)row * 3072 + col] = acc[mi][ni][r];
      }
    }
}

// ---------------------------------------------------------------------------
// RoPE + layout: qkv fp32 [tok][3072] -> q,k (rotated) hi/lo, [bh][t][64]
// (V handled by k_vtrans)
// ---------------------------------------------------------------------------
__global__ __launch_bounds__(256) void k_rope(
    const float* __restrict__ qkv,
    bf16* __restrict__ qh, bf16* __restrict__ ql,
    bf16* __restrict__ kh, bf16* __restrict__ kl)
{
  const int tok = blockIdx.x;
  const int t = tok & (SEQ - 1), bb = tok >> 10;
  const int tid = threadIdx.x;
  const float ft = (float)t;
  for (int it = tid; it < 512; it += 256) {
    const int hh = it >> 5, i = it & 31;
    const float inv = powf(10000.0f, -(float)i * (1.0f / 32.0f));
    const float ang = ft * inv;
    float sn, cs;
    sincosf(ang, &sn, &cs);
    const long src = (long)tok * 3072 + hh * 64 + i;
    const float q0 = qkv[src], q1 = qkv[src + 32];
    const float k0 = qkv[src + 1024], k1 = qkv[src + 1024 + 32];
    const float qo0 = q0 * cs - q1 * sn, qo1 = q1 * cs + q0 * sn;
    const float ko0 = k0 * cs - k1 * sn, ko1 = k1 * cs + k0 * sn;
    const long dst = ((long)(bb * 16 + hh) * SEQ + t) * 64 + i;
    bf16 x;
    x = (bf16)qo0; qh[dst] = x;      ql[dst] = (bf16)(qo0 - (float)x);
    x = (bf16)qo1; qh[dst + 32] = x; ql[dst + 32] = (bf16)(qo1 - (float)x);
    x = (bf16)ko0; kh[dst] = x;      kl[dst] = (bf16)(ko0 - (float)x);
    x = (bf16)ko1; kh[dst + 32] = x; kl[dst + 32] = (bf16)(ko1 - (float)x);
  }
}

// ---------------------------------------------------------------------------
// Flash attention (causal), split-precision QK^T and PV. Block = 64 q-rows.
// Q/K/VT staged via global_load_lds with pre-swizzled source chunks
// (linear LDS dest; content matches swz() layout). 2 barriers per kt-step.
// P per-wave in QP tiles (DS in-order within a wave; no barrier needed).
// ---------------------------------------------------------------------------
__global__ __launch_bounds__(256, 3) void k_flash(
    const bf16* __restrict__ qh, const bf16* __restrict__ ql,
    const bf16* __restrict__ kh, const bf16* __restrict__ kl,
    const bf16* __restrict__ vth, const bf16* __restrict__ vtl,
    bf16* __restrict__ oh, bf16* __restrict__ ol)
{
  const int qt = blockIdx.x, bhid = blockIdx.y;
  const int tid = threadIdx.x, lane = tid & 63, w = tid >> 6;
  const int fr = lane & 15, quad = lane >> 4;
  __shared__ __align__(16) bf16 QP0[64 * 64];
  __shared__ __align__(16) bf16 QP1[64 * 64];
  __shared__ __align__(16) bf16 Kh[64 * 64], Kl[64 * 64];
  __shared__ __align__(16) bf16 Vh[64 * 64], Vl[64 * 64];

  // stage one 64x64 bf16 tile (row stride rstride elems) into LDS such that
  // linear chunk j of row r holds source chunk j ^ f(r)  (== swz layout).
  const int srow = lane >> 3, schunk = lane & 7;
  auto stage_tile = [&](bf16* ldst, const bf16* gsrc, long rstride) {
#pragma unroll
    for (int p = 0; p < 2; ++p) {
      const int r = p * 32 + w * 8 + srow;
      const int f = (r ^ (r >> 3)) & 7;
      async_cp16(ldst + (p * 32 + w * 8) * 64,
                 gsrc + (long)r * rstride + ((schunk ^ f) << 3));
    }
  };

  const long qbase = ((long)bhid * SEQ + qt * 64) * 64;
  stage_tile(QP0, qh + qbase, 64);
  stage_tile(QP1, ql + qbase, 64);
  __syncthreads();
  bf16x8 aQh[2], aQl[2];
#pragma unroll
  for (int kk = 0; kk < 2; ++kk) {
    aQh[kk] = *(const bf16x8*)&QP0[swz(w * 16 + fr, kk * 32 + quad * 8)];
    aQl[kk] = *(const bf16x8*)&QP1[swz(w * 16 + fr, kk * 32 + quad * 8)];
  }
  f32x4 o[4];
  f32x4 zv = {0.f, 0.f, 0.f, 0.f};
#pragma unroll
  for (int ct = 0; ct < 4; ++ct) o[ct] = zv;
  float m_r[4], l_r[4];
#pragma unroll
  for (int r = 0; r < 4; ++r) { m_r[r] = -1e30f; l_r[r] = 0.f; }

  const long kstride = 64;
  const bf16* vtb_h = vth + (long)bhid * 64 * SEQ;
  const bf16* vtb_l = vtl + (long)bhid * 64 * SEQ;

  for (int kt = 0; kt <= qt; ++kt) {
    __syncthreads();                  // prev PV done: K/V LDS reusable
    const long kbase = ((long)bhid * SEQ + kt * 64) * 64;
    stage_tile(Kh, kh + kbase, kstride);
    stage_tile(Kl, kl + kbase, kstride);
    stage_tile(Vh, vtb_h + kt * 64, SEQ);
    stage_tile(Vl, vtb_l + kt * 64, SEQ);
    __syncthreads();                  // drains global_load_lds (vmcnt 0)

    f32x4 s[4];
#pragma unroll
    for (int nt = 0; nt < 4; ++nt) s[nt] = zv;
#pragma unroll
    for (int nt = 0; nt < 4; ++nt)
#pragma unroll
      for (int kk = 0; kk < 2; ++kk) {
        bf16x8 bh8 = *(const bf16x8*)&Kh[swz(nt * 16 + fr, kk * 32 + quad * 8)];
        bf16x8 bl8 = *(const bf16x8*)&Kl[swz(nt * 16 + fr, kk * 32 + quad * 8)];
        s[nt] = mfma16(aQh[kk], bh8, s[nt]);
        s[nt] = mfma16(aQl[kk], bh8, s[nt]);
        s[nt] = mfma16(aQh[kk], bl8, s[nt]);
      }
    const int qloc = w * 16 + quad * 4;  // + r
#pragma unroll
    for (int nt = 0; nt < 4; ++nt)
#pragma unroll
      for (int r = 0; r < 4; ++r) {
        float sv = s[nt][r] * 0.125f;
        if (kt == qt && (nt * 16 + fr) > (qloc + r)) sv = -1e30f;
        s[nt][r] = sv;
      }
    float al4[4];
#pragma unroll
    for (int r = 0; r < 4; ++r) {
      float m = fmaxf(fmaxf(s[0][r], s[1][r]), fmaxf(s[2][r], s[3][r]));
#pragma unroll
      for (int off = 1; off < 16; off <<= 1) m = fmaxf(m, __shfl_xor(m, off));
      const float mn = fmaxf(m_r[r], m);
      al4[r] = expf(m_r[r] - mn);
      m_r[r] = mn;
    }
    float pmat[4][4], ls4[4];
#pragma unroll
    for (int r = 0; r < 4; ++r) ls4[r] = 0.f;
#pragma unroll
    for (int nt = 0; nt < 4; ++nt)
#pragma unroll
      for (int r = 0; r < 4; ++r) {
        const float p = expf(s[nt][r] - m_r[r]);
        pmat[nt][r] = p;
        ls4[r] += p;
      }
#pragma unroll
    for (int r = 0; r < 4; ++r) {
      float l = ls4[r];
#pragma unroll
      for (int off = 1; off < 16; off <<= 1) l += __shfl_xor(l, off);
      l_r[r] = l_r[r] * al4[r] + l;
      o[0][r] *= al4[r]; o[1][r] *= al4[r]; o[2][r] *= al4[r]; o[3][r] *= al4[r];
    }
    bf16* Pw0 = QP0 + w * 1024;       // per-wave region: no block barrier
    bf16* Pw1 = QP1 + w * 1024;
#pragma unroll
    for (int nt = 0; nt < 4; ++nt)
#pragma unroll
      for (int r = 0; r < 4; ++r) {
        const float p = pmat[nt][r];
        bf16 hh2 = (bf16)p;
        Pw0[swz(quad * 4 + r, nt * 16 + fr)] = hh2;
        Pw1[swz(quad * 4 + r, nt * 16 + fr)] = (bf16)(p - (float)hh2);
      }
    __builtin_amdgcn_sched_barrier(0);  // keep P writes before P reads
#pragma unroll
    for (int kk = 0; kk < 2; ++kk) {
      bf16x8 aPh = *(const bf16x8*)&Pw0[swz(fr, kk * 32 + quad * 8)];
      bf16x8 aPl = *(const bf16x8*)&Pw1[swz(fr, kk * 32 + quad * 8)];
#pragma unroll
      for (int ct = 0; ct < 4; ++ct) {
        bf16x8 bVh = *(const bf16x8*)&Vh[swz(ct * 16 + fr, kk * 32 + quad * 8)];
        bf16x8 bVl = *(const bf16x8*)&Vl[swz(ct * 16 + fr, kk * 32 + quad * 8)];
        o[ct] = mfma16(aPh, bVh, o[ct]);
        o[ct] = mfma16(aPl, bVh, o[ct]);
        o[ct] = mfma16(aPh, bVl, o[ct]);
      }
    }
  }
  const int b_ = bhid >> 4, h_ = bhid & 15;
#pragma unroll
  for (int ct = 0; ct < 4; ++ct)
#pragma unroll
    for (int r = 0; r < 4; ++r) {
      const int tokn = b_ * SEQ + qt * 64 + w * 16 + quad * 4 + r;
      const int col = h_ * 64 + ct * 16 + fr;
      const float val = o[ct][r] / l_r[r];
      bf16 hh3 = (bf16)val;
      oh[(long)tokn * D_MODEL + col] = hh3;
      ol[(long)tokn * D_MODEL + col] = (bf16)(val - (float)hh3);
    }
}

// ---------------------------------------------------------------------------
// Proj GEMM (split) + bias + residual -> d_out fp32 (= x1)
// ---------------------------------------------------------------------------
__global__ __launch_bounds__(256, 2) void k_gemm_proj(
    const bf16* __restrict__ Ah, const bf16* __restrict__ Al,
    const bf16* __restrict__ Bh, const bf16* __restrict__ Bl,
    const float* __restrict__ bproj, const float* __restrict__ xin,
    float* __restrict__ out)
{
  __shared__ __align__(16) bf16 As[2 * 128 * 32];
  __shared__ __align__(16) bf16 Bs[2 * 128 * 32];
  const int tid = threadIdx.x, lane = tid & 63, w = tid >> 6;
  const int fr = lane & 15, quad = lane >> 4;
  const int wm = w >> 1, wn = w & 1;
  const int m0 = blockIdx.y * 128, n0 = blockIdx.x * 128;
  const int lrow = w * 16 + (lane >> 2), colk = (lane & 3) * 8;
  long aOff0 = (long)(m0 + lrow) * D_MODEL + colk;
  long aOff1 = aOff0 + 64L * D_MODEL;
  long bOff0 = (long)(n0 + lrow) * D_MODEL + colk;
  long bOff1 = bOff0 + 64L * D_MODEL;
  f32x4 acc[4][4];
  f32x4 zv = {0.f, 0.f, 0.f, 0.f};
#pragma unroll
  for (int i = 0; i < 4; ++i)
#pragma unroll
    for (int j = 0; j < 4; ++j) acc[i][j] = zv;
  gemm_core<true>(Ah, Al, Bh, Bl, aOff0, aOff1, bOff0, bOff1, D_MODEL, As, Bs, acc);
#pragma unroll
  for (int mi = 0; mi < 4; ++mi)
#pragma unroll
    for (int ni = 0; ni < 4; ++ni) {
      const int col = n0 + wn * 64 + ni * 16 + fr;
#pragma unroll
      for (int r = 0; r < 4; ++r) {
        const int row = m0 + wm * 64 + mi * 16 + quad * 4 + r;
        out[(long)row * D_MODEL + col] =
            acc[mi][ni][r] + bproj[col] + xin[(long)row * D_MODEL + col];
      }
    }
}

// ---------------------------------------------------------------------------
// Router: own fp32 LN of x1, fp32 logits, softmax, strict top-2.
// ---------------------------------------------------------------------------
__global__ __launch_bounds__(256) void k_router(
    const float* __restrict__ x1, const float* __restrict__ g,
    const float* __restrict__ b, const float* __restrict__ wr,
    int2* __restrict__ topi, float2* __restrict__ topg,
    float* __restrict__ pbuf)
{
  const int tok = blockIdx.x, tid = threadIdx.x;
  const float4 v = ((const float4*)(x1 + (long)tok * D_MODEL))[tid];
  float s  = v.x + v.y + v.z + v.w;
  float s2 = v.x * v.x + v.y * v.y + v.z * v.z + v.w * v.w;
#pragma unroll
  for (int off = 1; off < 64; off <<= 1) {
    s  += __shfl_xor(s, off);
    s2 += __shfl_xor(s2, off);
  }
  __shared__ float red[8];
  __shared__ float lr[4][8];
  if ((tid & 63) == 0) { red[tid >> 6] = s; red[4 + (tid >> 6)] = s2; }
  __syncthreads();
  s  = red[0] + red[1] + red[2] + red[3];
  s2 = red[4] + red[5] + red[6] + red[7];
  const float mu   = s * (1.0f / D_MODEL);
  const float var  = s2 * (1.0f / D_MODEL) - mu * mu;
  const float rstd = 1.0f / sqrtf(var + 1e-5f);
  const float4 gg = ((const float4*)g)[tid];
  const float4 bb = ((const float4*)b)[tid];
  float n4[4];
  n4[0] = (v.x - mu) * rstd * gg.x + bb.x;
  n4[1] = (v.y - mu) * rstd * gg.y + bb.y;
  n4[2] = (v.z - mu) * rstd * gg.z + bb.z;
  n4[3] = (v.w - mu) * rstd * gg.w + bb.w;
  float part[8];
#pragma unroll
  for (int e = 0; e < 8; ++e) part[e] = 0.f;
  const float* wrow = wr + (long)tid * 4 * 8;
#pragma unroll
  for (int c = 0; c < 4; ++c)
#pragma unroll
    for (int e = 0; e < 8; ++e) part[e] += n4[c] * wrow[c * 8 + e];
#pragma unroll
  for (int off = 1; off < 64; off <<= 1)
#pragma unroll
    for (int e = 0; e < 8; ++e) part[e] += __shfl_xor(part[e], off);
  if ((tid & 63) == 0)
#pragma unroll
    for (int e = 0; e < 8; ++e) lr[tid >> 6][e] = part[e];
  __syncthreads();
  if (tid == 0) {
    float lg[8];
#pragma unroll
    for (int e = 0; e < 8; ++e) lg[e] = lr[0][e] + lr[1][e] + lr[2][e] + lr[3][e];
    float mx = lg[0];
#pragma unroll
    for (int e = 1; e < 8; ++e) mx = fmaxf(mx, lg[e]);
    float pe[8], ssum = 0.f;
#pragma unroll
    for (int e = 0; e < 8; ++e) { pe[e] = expf(lg[e] - mx); ssum += pe[e]; }
    const float inv = 1.0f / ssum;
    int i1 = -1, i2 = -1;
    float v1 = -1.f, v2 = -1.f;
#pragma unroll
    for (int e = 0; e < 8; ++e) {
      const float p = pe[e] * inv;
      pbuf[(long)tok * 8 + e] = p;
      if (p > v1)      { v2 = v1; i2 = i1; v1 = p; i1 = e; }
      else if (p > v2) { v2 = p; i2 = e; }
    }
    const float wsum = v1 + v2;
    topi[tok] = make_int2(i1, i2);
    topg[tok] = make_float2(v1 / wsum, v2 / wsum);
  }
}

// ---------------------------------------------------------------------------
// Scatter: build per-expert token lists + per-token ranks (pos).
// ---------------------------------------------------------------------------
__global__ __launch_bounds__(256) void k_scatter(
    const int2* __restrict__ topi,
    int* __restrict__ ecnt, int* __restrict__ perm, int2* __restrict__ pos)
{
  __shared__ int hcnt[NEXP];
  __shared__ int hbase[NEXP];
  const int tid = threadIdx.x;
  const int tok = blockIdx.x * 256 + tid;
  if (tid < NEXP) hcnt[tid] = 0;
  __syncthreads();
  const int2 ti = topi[tok];
  const int r1 = atomicAdd(&hcnt[ti.x], 1);
  const int r2 = atomicAdd(&hcnt[ti.y], 1);
  __syncthreads();
  if (tid < NEXP) hbase[tid] = atomicAdd(&ecnt[tid], hcnt[tid]);
  __syncthreads();
  const int p1 = hbase[ti.x] + r1;
  perm[ti.x * NTOK + p1] = tok;
  const int p2 = hbase[ti.y] + r2;
  perm[ti.y * NTOK + p2] = tok;
  pos[tok] = make_int2(p1, p2);
}

// ---------------------------------------------------------------------------
// Finalize: reduce pbuf -> psum, compute eoff + aux loss.
// ---------------------------------------------------------------------------
__global__ __launch_bounds__(256) void k_finalize(
    const int* __restrict__ ecnt, const float* __restrict__ pbuf,
    int* __restrict__ eoff, float* __restrict__ aux_out)
{
  __shared__ float partial[256];
  const int tid = threadIdx.x;
  const int e = tid & 7, i0 = tid >> 3;
  float sum = 0.f;
  for (int i = i0; i < NTOK; i += 32) sum += pbuf[(long)i * 8 + e];
  partial[tid] = sum;
  __syncthreads();
  if (tid < 8) {
    float ps = 0.f;
#pragma unroll
    for (int j = 0; j < 32; ++j) ps += partial[j * 8 + tid];
    partial[tid] = ps;   // psum[e]
  }
  __syncthreads();
  if (tid == 0) {
    int off = 0;
    float aux = 0.f;
    for (int e2 = 0; e2 < 8; ++e2) {
      eoff[e2] = off;
      off += (ecnt[e2] + 127) & ~127;
      aux += ((float)ecnt[e2] * (1.0f / (NTOK * 2.0f))) * (partial[e2] * (1.0f / NTOK));
    }
    aux_out[0] = 8.0f * aux;
  }
}

// ---------------------------------------------------------------------------
// FFN1: gathered ln2 rows @ w1T[e] + b1 -> exact GELU -> h (bf16)
// ---------------------------------------------------------------------------
__global__ __launch_bounds__(256, 2) void k_gemm_ffn1(
    const bf16* __restrict__ A, const bf16* __restrict__ w1t,
    const float* __restrict__ b1, const int* __restrict__ ecnt,
    const int* __restrict__ eoff, const int* __restrict__ perm,
    bf16* __restrict__ h)
{
  const int e = blockIdx.y >> 5, mt = blockIdx.y & 31;
  const int cnt = ecnt[e];
  if (mt * 128 >= cnt) return;
  __shared__ __align__(16) bf16 As[2 * 128 * 32];
  __shared__ __align__(16) bf16 Bs[2 * 128 * 32];
  const int tid = threadIdx.x, lane = tid & 63, w = tid >> 6;
  const int fr = lane & 15, quad = lane >> 4;
  const int wm = w >> 1, wn = w & 1;
  const int n0 = blockIdx.x * 128;
  const int lrow = w * 16 + (lane >> 2), colk = (lane & 3) * 8;
  int i0 = mt * 128 + lrow;
  int i1 = i0 + 64;
  i0 = min(i0, cnt - 1);
  i1 = min(i1, cnt - 1);
  const int* pe = perm + e * NTOK;
  long aOff0 = (long)pe[i0] * D_MODEL + colk;
  long aOff1 = (long)pe[i1] * D_MODEL + colk;
  const bf16* B = w1t + (long)e * DFF * D_MODEL;
  long bOff0 = (long)(n0 + lrow) * D_MODEL + colk;
  long bOff1 = bOff0 + 64L * D_MODEL;
  f32x4 acc[4][4];
  f32x4 zv = {0.f, 0.f, 0.f, 0.f};
#pragma unroll
  for (int i = 0; i < 4; ++i)
#pragma unroll
    for (int j = 0; j < 4; ++j) acc[i][j] = zv;
  gemm_core<false>(A, A, B, B, aOff0, aOff1, bOff0, bOff1, D_MODEL, As, Bs, acc);
  const int hbase = eoff[e] + mt * 128;
#pragma unroll
  for (int mi = 0; mi < 4; ++mi)
#pragma unroll
    for (int ni = 0; ni < 4; ++ni) {
      const int col = n0 + wn * 64 + ni * 16 + fr;
#pragma unroll
      for (int r = 0; r < 4; ++r) {
        const int irow = wm * 64 + mi * 16 + quad * 4 + r;
        const float vv = acc[mi][ni][r] + b1[e * DFF + col];
        const float ge = 0.5f * vv * (1.0f + erff(vv * 0.70710678118654752f));
        h[(long)(hbase + irow) * DFF + col] = (bf16)ge;
      }
    }
}

// ---------------------------------------------------------------------------
// FFN2 (split-K=2 via blockIdx.z): h rows @ w2T[e] halves -> fp32 partials in
// ybuf[z] (plain coalesced stores; bias folded into z==0 partial)
// ---------------------------------------------------------------------------
__global__ __launch_bounds__(256, 2) void k_gemm_ffn2(
    const bf16* __restrict__ hbuf, const bf16* __restrict__ w2t,
    const float* __restrict__ b2, const int* __restrict__ ecnt,
    const int* __restrict__ eoff, float* __restrict__ ybuf)
{
  const int e = blockIdx.y >> 5, mt = blockIdx.y & 31;
  const int cnt = ecnt[e];
  if (mt * 128 >= cnt) return;
  __shared__ __align__(16) bf16 As[2 * 128 * 32];
  __shared__ __align__(16) bf16 Bs[2 * 128 * 32];
  const int tid = threadIdx.x, lane = tid & 63, w = tid >> 6;
  const int fr = lane & 15, quad = lane >> 4;
  const int wm = w >> 1, wn = w & 1;
  const int n0 = blockIdx.x * 128;
  const int z = blockIdx.z;
  const long kOff = (long)z * (DFF / 2);
  const int lrow = w * 16 + (lane >> 2), colk = (lane & 3) * 8;
  const int rbase = eoff[e] + mt * 128;
  const bf16* A = hbuf + (long)rbase * DFF;
  long aOff0 = (long)lrow * DFF + colk + kOff;
  long aOff1 = aOff0 + 64L * DFF;
  const bf16* B = w2t + (long)e * D_MODEL * DFF;
  long bOff0 = (long)(n0 + lrow) * DFF + colk + kOff;
  long bOff1 = bOff0 + 64L * DFF;
  f32x4 acc[4][4];
  f32x4 zv = {0.f, 0.f, 0.f, 0.f};
#pragma unroll
  for (int i = 0; i < 4; ++i)
#pragma unroll
    for (int j = 0; j < 4; ++j) acc[i][j] = zv;
  gemm_core<false>(A, A, B, B, aOff0, aOff1, bOff0, bOff1, DFF / 2, As, Bs, acc);
  float* yb = ybuf + (long)z * YSTRIDE;
#pragma unroll
  for (int mi = 0; mi < 4; ++mi)
#pragma unroll
    for (int ni = 0; ni < 4; ++ni) {
      const int col = n0 + wn * 64 + ni * 16 + fr;
      const float bias = (z == 0) ? b2[e * D_MODEL + col] : 0.0f;
#pragma unroll
      for (int r = 0; r < 4; ++r) {
        const int irow = wm * 64 + mi * 16 + quad * 4 + r;
        yb[(long)(rbase + irow) * D_MODEL + col] = acc[mi][ni][r] + bias;
      }
    }
}

// ---------------------------------------------------------------------------
// Combine: out[tok] += g1*(y0[row1]+y1[row1]) + g2*(y0[row2]+y1[row2])
// ---------------------------------------------------------------------------
__global__ __launch_bounds__(256) void k_combine(
    const int2* __restrict__ topi, const float2* __restrict__ topg,
    const int2* __restrict__ pos, const int* __restrict__ eoff,
    const float* __restrict__ ybuf, float* __restrict__ out)
{
  const int tok = blockIdx.x, tid = threadIdx.x;
  const int2 ti = topi[tok];
  const int2 pp = pos[tok];
  const float2 tg = topg[tok];
  const long r1 = (long)eoff[ti.x] + pp.x;
  const long r2 = (long)eoff[ti.y] + pp.y;
  const float4 y1a = ((const float4*)(ybuf + r1 * D_MODEL))[tid];
  const float4 y1b = ((const float4*)(ybuf + YSTRIDE + r1 * D_MODEL))[tid];
  const float4 y2a = ((const float4*)(ybuf + r2 * D_MODEL))[tid];
  const float4 y2b = ((const float4*)(ybuf + YSTRIDE + r2 * D_MODEL))[tid];
  float4* po = (float4*)(out + (long)tok * D_MODEL) + tid;
  float4 o = *po;
  o.x += tg.x * (y1a.x + y1b.x) + tg.y * (y2a.x + y2b.x);
  o.y += tg.x * (y1a.y + y1b.y) + tg.y * (y2a.y + y2b.y);
  o.z += tg.x * (y1a.z + y1b.z) + tg.y * (y2a.z + y2b.z);
  o.w += tg.x * (y1a.w + y1b.w) + tg.y * (y2a.w + y2b.w);
  *po = o;
}

// ---------------------------------------------------------------------------
extern "C" void kernel_launch(void* const* d_in, const int* in_sizes, int n_in,
                              void* d_out, int out_size, void* d_ws, size_t ws_size,
                              hipStream_t stream) {
  const float* x     = (const float*)d_in[0];
  // d_in[1] = mask (causal structure reproduced in-kernel)
  const float* ln1g  = (const float*)d_in[2];
  const float* ln1b  = (const float*)d_in[3];
  const float* wqkv  = (const float*)d_in[4];
  const float* wproj = (const float*)d_in[5];
  const float* bproj = (const float*)d_in[6];
  const float* ln2g  = (const float*)d_in[7];
  const float* ln2b  = (const float*)d_in[8];
  const float* wrout = (const float*)d_in[9];
  const float* w1    = (const float*)d_in[10];
  const float* b1    = (const float*)d_in[11];
  const float* w2    = (const float*)d_in[12];
  const float* b2    = (const float*)d_in[13];
  float* out = (float*)d_out;

  char* p = (char*)d_ws;
  auto alloc = [&](size_t n) { char* r = p; p += (n + 255) & ~(size_t)255; return r; };

  bf16* wqkvT_h = (bf16*)alloc(3072L * 1024 * 2);
  bf16* wqkvT_l = (bf16*)alloc(3072L * 1024 * 2);
  bf16* wprojT_h = (bf16*)alloc(1024L * 1024 * 2);
  bf16* wprojT_l = (bf16*)alloc(1024L * 1024 * 2);
  bf16* w1T = (bf16*)alloc(8L * 4096 * 1024 * 2);
  bf16* w2T = (bf16*)alloc(8L * 1024 * 4096 * 2);
  bf16* ln_h = (bf16*)alloc(4096L * 1024 * 2);  // ln1 then reused for ln2
  bf16* ln_l = (bf16*)alloc(4096L * 1024 * 2);
  bf16* attn_h = (bf16*)alloc(4096L * 1024 * 2);
  bf16* attn_l = (bf16*)alloc(4096L * 1024 * 2);
  int*   perm  = (int*)alloc(8L * 4096 * 4);
  int2*  topi  = (int2*)alloc(4096L * 8);
  float2* topg = (float2*)alloc(4096L * 8);
  int2*  pos   = (int2*)alloc(4096L * 8);
  float* pbuf  = (float*)alloc(4096L * 8 * 4);
  char*  ctrl  = alloc(256);                 // ecnt[8] | eoff[8]
  int*   ecnt  = (int*)ctrl;
  int*   eoff  = (int*)(ctrl + 64);
  float* ybuf  = (float*)alloc(2L * YSTRIDE * 4);      // fp32 FFN2 split-K partials
  // big overlay region: [qkv fp32 48MB | rope/vT bufs 48MB] then h (73MB)
  char* big = alloc(100663296);
  float* qkvf = (float*)big;                           // 4096*3072*4
  bf16* qh  = (bf16*)(big + 50331648);
  bf16* ql  = qh + 4194304;
  bf16* kh  = ql + 4194304;
  bf16* kl  = kh + 4194304;
  bf16* vth = kl + 4194304;                            // [bh][64][SEQ] hi
  bf16* vtl = vth + 4194304;                           // [bh][64][SEQ] lo
  bf16* hbuf = (bf16*)big;                             // 9216*4096*2, after attn

  dim3 blk(256);

  // 1) weight transpose + cast
  k_transpose_cast<<<dim3(3072 / 32, 1024 / 32, 1), blk, 0, stream>>>(wqkv, wqkvT_h, wqkvT_l, 1024, 3072);
  k_transpose_cast<<<dim3(1024 / 32, 1024 / 32, 1), blk, 0, stream>>>(wproj, wprojT_h, wprojT_l, 1024, 1024);
  k_transpose_cast<<<dim3(4096 / 32, 1024 / 32, 8), blk, 0, stream>>>(w1, w1T, nullptr, 1024, 4096);
  k_transpose_cast<<<dim3(1024 / 32, 4096 / 32, 8), blk, 0, stream>>>(w2, w2T, nullptr, 4096, 1024);
  hipMemsetAsync(ctrl, 0, 256, stream);

  // 2) attention path (split precision)
  k_layernorm<<<4096, blk, 0, stream>>>(x, ln1g, ln1b, ln_h, ln_l);
  k_gemm_qkv<<<dim3(24, 32), blk, 0, stream>>>(ln_h, ln_l, wqkvT_h, wqkvT_l, qkvf);
  k_rope<<<4096, blk, 0, stream>>>(qkvf, qh, ql, kh, kl);
  k_vtrans<<<dim3(SEQ / 32, 2, 64), blk, 0, stream>>>(qkvf, vth, vtl);
  k_flash<<<dim3(16, 64), blk, 0, stream>>>(qh, ql, kh, kl, vth, vtl, attn_h, attn_l);
  k_gemm_proj<<<dim3(8, 32), blk, 0, stream>>>(attn_h, attn_l, wprojT_h, wprojT_l, bproj, x, out);

  // 3) MoE
  k_layernorm<<<4096, blk, 0, stream>>>(out, ln2g, ln2b, ln_h, nullptr);
  k_router<<<4096, blk, 0, stream>>>(out, ln2g, ln2b, wrout, topi, topg, pbuf);
  k_scatter<<<16, blk, 0, stream>>>(topi, ecnt, perm, pos);
  k_finalize<<<1, blk, 0, stream>>>(ecnt, pbuf, eoff, out + 4194304);
  k_gemm_ffn1<<<dim3(32, 256), blk, 0, stream>>>(ln_h, w1T, b1, ecnt, eoff, perm, hbuf);
  k_gemm_ffn2<<<dim3(8, 256, 2), blk, 0, stream>>>(hbuf, w2T, b2, ecnt, eoff, ybuf);
  k_combine<<<4096, blk, 0, stream>>>(topi, topg, pos, eoff, ybuf, out);
}

// Round 5
// 1004.215 us; speedup vs baseline: 1.1023x; 1.0113x over previous
//
#include <hip/hip_runtime.h>
#include <math.h>

// ---------------------------------------------------------------------------
// TransformerBlock: x + attn(LN1(x)) -> x1 ; x1 + top2-MoE(LN2(x1)) ; aux loss
// R7: gemm_core pipeline v2 — triple-buffered LDS + counted vmcnt + raw
// s_barrier. R5's dbuf still drained vmcnt(0) at every __syncthreads (hipcc
// emits "s_waitcnt vmcnt(0) lgkmcnt(0)" before s_barrier), so each K-step
// paid full L2/HBM latency (ffn1: 1.6K cyc/step vs 80 cyc MFMA, MfmaUtil 17%).
// New schedule per step s:
//   s_waitcnt vmcnt(4)   -> own stage(s) loads landed (stage(s+1) in flight)
//   s_barrier            -> block-wide: tile s complete; all past compute(s-1)
//   sched_barrier(0)     -> pin ds_reads below the barrier
//   stage(s+2)           -> DMA into buf[(s+2)%3]; safe, see proof below
//   ds_read buf[s%3] + MFMA            (no trailing drain)
// Buffer-rotation safety: buf[(s+2)%3] was last READ at compute(s-1); every
// wave that issues stage(s+2) has passed barrier(s), which it could only
// reach after its MFMAs of step s-1 (in-order issue; lgkmcnt forced operand
// readiness) -> all reads of that buffer completed block-wide.
// R6 (kept): vT precompute + DMA-staged flash. R4/R5 (kept): de-atomicized
// split-K ffn2, fp32 combine.
// ---------------------------------------------------------------------------

typedef __bf16 bf16;
typedef __bf16 bf16x8 __attribute__((ext_vector_type(8)));
typedef float  f32x4  __attribute__((ext_vector_type(4)));

#define D_MODEL 1024
#define SEQ     1024
#define NTOK    4096
#define DFF     4096
#define NEXP    8
#define YSTRIDE (9216L * 1024)

__device__ __forceinline__ f32x4 mfma16(bf16x8 a, bf16x8 b, f32x4 c) {
  return __builtin_amdgcn_mfma_f32_16x16x32_bf16(a, b, c, 0, 0, 0);
}

__device__ __forceinline__ void async_cp16(void* lds, const void* g) {
  __builtin_amdgcn_global_load_lds(
      (__attribute__((address_space(1))) void*)(void*)g,
      (__attribute__((address_space(3))) void*)lds, 16, 0, 0);
}

// Bank-conflict-free index into a [R][64] bf16 LDS tile (flash tiles).
__device__ __forceinline__ int swz(int row, int col) {
  return row * 64 + (col ^ (((row ^ (row >> 3)) & 7) << 3));
}

// ---------------------------------------------------------------------------
// Shared MFMA GEMM core, 3-buffer counted-vmcnt pipeline (see header).
// As/Bs must each be 3*128*32 bf16. SPLIT => 3 flattened phases
// (Ah*Bh, Al*Bh, Ah*Bl); the pipeline lookahead crosses phase boundaries.
// ---------------------------------------------------------------------------
template<bool SPLIT>
__device__ __forceinline__ void gemm_core(
    const bf16* __restrict__ Ahi, const bf16* __restrict__ Alo,
    const bf16* __restrict__ Bhi, const bf16* __restrict__ Blo,
    long aOff0, long aOff1, long bOff0, long bOff1,
    int K, bf16* As, bf16* Bs, f32x4 acc[4][4])
{
  const int tid  = threadIdx.x;
  const int lane = tid & 63, w = tid >> 6;
  const int fr   = lane & 15, quad = lane >> 4;
  const int wm   = w >> 1,    wn   = w & 1;
  const int ldst0 = (w * 16) * 32;
  const int ldst1 = (64 + w * 16) * 32;
  const int ksteps = K >> 5;
  const int nsteps = (SPLIT ? 3 : 1) * ksteps;

  auto stage = [&](int s, int buf) {
    const int ph = SPLIT ? (s / ksteps) : 0;
    const int k0 = (SPLIT ? (s - ph * ksteps) : s) << 5;
    const bf16* Ap = (ph == 1) ? Alo : Ahi;
    const bf16* Bp = (ph == 2) ? Blo : Bhi;
    bf16* Ab = As + buf * (128 * 32);
    bf16* Bb = Bs + buf * (128 * 32);
    async_cp16(Ab + ldst0, Ap + aOff0 + k0);
    async_cp16(Ab + ldst1, Ap + aOff1 + k0);
    async_cp16(Bb + ldst0, Bp + bOff0 + k0);
    async_cp16(Bb + ldst1, Bp + bOff1 + k0);
  };

  stage(0, 0);
  if (nsteps > 1) stage(1, 1);
  for (int s = 0; s < nsteps; ++s) {
    if (s + 1 < nsteps) {
      asm volatile("s_waitcnt vmcnt(4)" ::: "memory");   // stage(s) landed
    } else {
      asm volatile("s_waitcnt vmcnt(0)" ::: "memory");   // final tile
    }
    __builtin_amdgcn_s_barrier();
    __builtin_amdgcn_sched_barrier(0);
    if (s + 2 < nsteps) stage(s + 2, (s + 2) % 3);
    const bf16* Ab = As + (s % 3) * (128 * 32);
    const bf16* Bb = Bs + (s % 3) * (128 * 32);
    bf16x8 af[4], bfv[4];
#pragma unroll
    for (int mi = 0; mi < 4; ++mi)
      af[mi] = *(const bf16x8*)&Ab[(wm * 64 + mi * 16 + fr) * 32 + quad * 8];
#pragma unroll
    for (int ni = 0; ni < 4; ++ni)
      bfv[ni] = *(const bf16x8*)&Bb[(wn * 64 + ni * 16 + fr) * 32 + quad * 8];
#pragma unroll
    for (int mi = 0; mi < 4; ++mi)
#pragma unroll
      for (int ni = 0; ni < 4; ++ni)
        acc[mi][ni] = mfma16(af[mi], bfv[ni], acc[mi][ni]);
  }
}

// ---------------------------------------------------------------------------
// Weight transpose + fp32->bf16(hi[,lo]) cast: in [Z][K][N] -> out [Z][N][K]
// ---------------------------------------------------------------------------
__global__ void k_transpose_cast(const float* __restrict__ in,
                                 bf16* __restrict__ oh, bf16* __restrict__ ol,
                                 int K, int N)
{
  const long zo = (long)blockIdx.z * K * N;
  __shared__ float tile[32][33];
  const int tx = threadIdx.x & 31, ty = threadIdx.x >> 5;
  const int r0 = blockIdx.y * 32, c0 = blockIdx.x * 32;
#pragma unroll
  for (int j = 0; j < 4; ++j)
    tile[ty + 8 * j][tx] = in[zo + (long)(r0 + ty + 8 * j) * N + (c0 + tx)];
  __syncthreads();
#pragma unroll
  for (int j = 0; j < 4; ++j) {
    float v = tile[tx][ty + 8 * j];
    long  o = zo + (long)(c0 + ty + 8 * j) * K + (r0 + tx);
    bf16 hh = (bf16)v;
    oh[o] = hh;
    if (ol) ol[o] = (bf16)(v - (float)hh);
  }
}

// ---------------------------------------------------------------------------
// V transpose: qkv fp32 [tok][3072] (V at +2048) -> vT hi/lo [bh][64][SEQ]
// ---------------------------------------------------------------------------
__global__ __launch_bounds__(256) void k_vtrans(
    const float* __restrict__ qkv,
    bf16* __restrict__ vth, bf16* __restrict__ vtl)
{
  __shared__ float tile[32][33];
  const int tx = threadIdx.x & 31, ty = threadIdx.x >> 5;
  const int bh = blockIdx.z;            // bb*16 + hh
  const int bb = bh >> 4, hh = bh & 15;
  const int t0 = blockIdx.x * 32, d0 = blockIdx.y * 32;
#pragma unroll
  for (int j = 0; j < 4; ++j) {
    const int t = t0 + ty + 8 * j;
    tile[ty + 8 * j][tx] =
        qkv[(long)(bb * SEQ + t) * 3072 + 2048 + hh * 64 + d0 + tx];
  }
  __syncthreads();
#pragma unroll
  for (int j = 0; j < 4; ++j) {
    const int d = d0 + ty + 8 * j;
    const float v = tile[tx][ty + 8 * j];
    const long o = ((long)bh * 64 + d) * SEQ + t0 + tx;
    bf16 h2 = (bf16)v;
    vth[o] = h2;
    vtl[o] = (bf16)(v - (float)h2);
  }
}

// ---------------------------------------------------------------------------
// LayerNorm: one block per token, writes bf16 hi (and lo if non-null)
// ---------------------------------------------------------------------------
__global__ __launch_bounds__(256) void k_layernorm(
    const float* __restrict__ x, const float* __restrict__ g,
    const float* __restrict__ b, bf16* __restrict__ oh, bf16* __restrict__ ol)
{
  const int tok = blockIdx.x, tid = threadIdx.x;
  const float4 v = ((const float4*)(x + (long)tok * D_MODEL))[tid];
  float s  = v.x + v.y + v.z + v.w;
  float s2 = v.x * v.x + v.y * v.y + v.z * v.z + v.w * v.w;
#pragma unroll
  for (int off = 1; off < 64; off <<= 1) {
    s  += __shfl_xor(s, off);
    s2 += __shfl_xor(s2, off);
  }
  __shared__ float red[8];
  if ((tid & 63) == 0) { red[tid >> 6] = s; red[4 + (tid >> 6)] = s2; }
  __syncthreads();
  s  = red[0] + red[1] + red[2] + red[3];
  s2 = red[4] + red[5] + red[6] + red[7];
  const float mu   = s * (1.0f / D_MODEL);
  const float var  = s2 * (1.0f / D_MODEL) - mu * mu;
  const float rstd = 1.0f / sqrtf(var + 1e-5f);
  const float4 gg = ((const float4*)g)[tid];
  const float4 bb = ((const float4*)b)[tid];
  float o0 = (v.x - mu) * rstd * gg.x + bb.x;
  float o1 = (v.y - mu) * rstd * gg.y + bb.y;
  float o2 = (v.z - mu) * rstd * gg.z + bb.z;
  float o3 = (v.w - mu) * rstd * gg.w + bb.w;
  const long base = (long)tok * D_MODEL + tid * 4;
  bf16 h0 = (bf16)o0, h1 = (bf16)o1, h2 = (bf16)o2, h3 = (bf16)o3;
  oh[base + 0] = h0; oh[base + 1] = h1; oh[base + 2] = h2; oh[base + 3] = h3;
  if (ol) {
    ol[base + 0] = (bf16)(o0 - (float)h0);
    ol[base + 1] = (bf16)(o1 - (float)h1);
    ol[base + 2] = (bf16)(o2 - (float)h2);
    ol[base + 3] = (bf16)(o3 - (float)h3);
  }
}

// ---------------------------------------------------------------------------
// QKV GEMM (split): ln1[4096][1024] @ wqkvT -> qkv fp32 [4096][3072]
// ---------------------------------------------------------------------------
__global__ __launch_bounds__(256, 3) void k_gemm_qkv(
    const bf16* __restrict__ Ah, const bf16* __restrict__ Al,
    const bf16* __restrict__ Bh, const bf16* __restrict__ Bl,
    float* __restrict__ out)
{
  __shared__ __align__(16) bf16 As[3 * 128 * 32];
  __shared__ __align__(16) bf16 Bs[3 * 128 * 32];
  const int tid = threadIdx.x, lane = tid & 63, w = tid >> 6;
  const int fr = lane & 15, quad = lane >> 4;
  const int wm = w >> 1, wn = w & 1;
  const int m0 = blockIdx.y * 128, n0 = blockIdx.x * 128;
  const int lrow = w * 16 + (lane >> 2), colk = (lane & 3) * 8;
  long aOff0 = (long)(m0 + lrow) * D_MODEL + colk;
  long aOff1 = aOff0 + 64L * D_MODEL;
  long bOff0 = (long)(n0 + lrow) * D_MODEL + colk;
  long bOff1 = bOff0 + 64L * D_MODEL;
  f32x4 acc[4][4];
  f32x4 zv = {0.f, 0.f, 0.f, 0.f};
#pragma unroll
  for (int i = 0; i < 4; ++i)
#pragma unroll
    for (int j = 0; j < 4; ++j) acc[i][j] = zv;
  gemm_core<true>(Ah, Al, Bh, Bl, aOff0, aOff1, bOff0, bOff1, D_MODEL, As, Bs, acc);
#pragma unroll
  for (int mi = 0; mi < 4; ++mi)
#pragma unroll
    for (int ni = 0; ni < 4; ++ni) {
      const int col = n0 + wn * 64 + ni * 16 + fr;
#pragma unroll
      for (int r = 0; r < 4; ++r) {
        const int row = m0 + wm * 64 + mi * 16 + quad * 4 + r;
        out[(long)row * 3072 + col] = acc[mi][ni][r];
      }
    }
}

// ---------------------------------------------------------------------------
// RoPE + layout: qkv fp32 [tok][3072] -> q,k (rotated) hi/lo, [bh][t][64]
// (V handled by k_vtrans)
// ---------------------------------------------------------------------------
__global__ __launch_bounds__(256) void k_rope(
    const float* __restrict__ qkv,
    bf16* __restrict__ qh, bf16* __restrict__ ql,
    bf16* __restrict__ kh, bf16* __restrict__ kl)
{
  const int tok = blockIdx.x;
  const int t = tok & (SEQ - 1), bb = tok >> 10;
  const int tid = threadIdx.x;
  const float ft = (float)t;
  for (int it = tid; it < 512; it += 256) {
    const int hh = it >> 5, i = it & 31;
    const float inv = powf(10000.0f, -(float)i * (1.0f / 32.0f));
    const float ang = ft * inv;
    float sn, cs;
    sincosf(ang, &sn, &cs);
    const long src = (long)tok * 3072 + hh * 64 + i;
    const float q0 = qkv[src], q1 = qkv[src + 32];
    const float k0 = qkv[src + 1024], k1 = qkv[src + 1024 + 32];
    const float qo0 = q0 * cs - q1 * sn, qo1 = q1 * cs + q0 * sn;
    const float ko0 = k0 * cs - k1 * sn, ko1 = k1 * cs + k0 * sn;
    const long dst = ((long)(bb * 16 + hh) * SEQ + t) * 64 + i;
    bf16 x;
    x = (bf16)qo0; qh[dst] = x;      ql[dst] = (bf16)(qo0 - (float)x);
    x = (bf16)qo1; qh[dst + 32] = x; ql[dst + 32] = (bf16)(qo1 - (float)x);
    x = (bf16)ko0; kh[dst] = x;      kl[dst] = (bf16)(ko0 - (float)x);
    x = (bf16)ko1; kh[dst + 32] = x; kl[dst + 32] = (bf16)(ko1 - (float)x);
  }
}

// ---------------------------------------------------------------------------
// Flash attention (causal), split-precision QK^T and PV. Block = 64 q-rows.
// Q/K/VT staged via global_load_lds with pre-swizzled source chunks.
// ---------------------------------------------------------------------------
__global__ __launch_bounds__(256, 3) void k_flash(
    const bf16* __restrict__ qh, const bf16* __restrict__ ql,
    const bf16* __restrict__ kh, const bf16* __restrict__ kl,
    const bf16* __restrict__ vth, const bf16* __restrict__ vtl,
    bf16* __restrict__ oh, bf16* __restrict__ ol)
{
  const int qt = blockIdx.x, bhid = blockIdx.y;
  const int tid = threadIdx.x, lane = tid & 63, w = tid >> 6;
  const int fr = lane & 15, quad = lane >> 4;
  __shared__ __align__(16) bf16 QP0[64 * 64];
  __shared__ __align__(16) bf16 QP1[64 * 64];
  __shared__ __align__(16) bf16 Kh[64 * 64], Kl[64 * 64];
  __shared__ __align__(16) bf16 Vh[64 * 64], Vl[64 * 64];

  const int srow = lane >> 3, schunk = lane & 7;
  auto stage_tile = [&](bf16* ldst, const bf16* gsrc, long rstride) {
#pragma unroll
    for (int p = 0; p < 2; ++p) {
      const int r = p * 32 + w * 8 + srow;
      const int f = (r ^ (r >> 3)) & 7;
      async_cp16(ldst + (p * 32 + w * 8) * 64,
                 gsrc + (long)r * rstride + ((schunk ^ f) << 3));
    }
  };

  const long qbase = ((long)bhid * SEQ + qt * 64) * 64;
  stage_tile(QP0, qh + qbase, 64);
  stage_tile(QP1, ql + qbase, 64);
  __syncthreads();
  bf16x8 aQh[2], aQl[2];
#pragma unroll
  for (int kk = 0; kk < 2; ++kk) {
    aQh[kk] = *(const bf16x8*)&QP0[swz(w * 16 + fr, kk * 32 + quad * 8)];
    aQl[kk] = *(const bf16x8*)&QP1[swz(w * 16 + fr, kk * 32 + quad * 8)];
  }
  f32x4 o[4];
  f32x4 zv = {0.f, 0.f, 0.f, 0.f};
#pragma unroll
  for (int ct = 0; ct < 4; ++ct) o[ct] = zv;
  float m_r[4], l_r[4];
#pragma unroll
  for (int r = 0; r < 4; ++r) { m_r[r] = -1e30f; l_r[r] = 0.f; }

  const long kstride = 64;
  const bf16* vtb_h = vth + (long)bhid * 64 * SEQ;
  const bf16* vtb_l = vtl + (long)bhid * 64 * SEQ;

  for (int kt = 0; kt <= qt; ++kt) {
    __syncthreads();                  // prev PV done: K/V LDS reusable
    const long kbase = ((long)bhid * SEQ + kt * 64) * 64;
    stage_tile(Kh, kh + kbase, kstride);
    stage_tile(Kl, kl + kbase, kstride);
    stage_tile(Vh, vtb_h + kt * 64, SEQ);
    stage_tile(Vl, vtb_l + kt * 64, SEQ);
    __syncthreads();                  // drains global_load_lds (vmcnt 0)

    f32x4 s[4];
#pragma unroll
    for (int nt = 0; nt < 4; ++nt) s[nt] = zv;
#pragma unroll
    for (int nt = 0; nt < 4; ++nt)
#pragma unroll
      for (int kk = 0; kk < 2; ++kk) {
        bf16x8 bh8 = *(const bf16x8*)&Kh[swz(nt * 16 + fr, kk * 32 + quad * 8)];
        bf16x8 bl8 = *(const bf16x8*)&Kl[swz(nt * 16 + fr, kk * 32 + quad * 8)];
        s[nt] = mfma16(aQh[kk], bh8, s[nt]);
        s[nt] = mfma16(aQl[kk], bh8, s[nt]);
        s[nt] = mfma16(aQh[kk], bl8, s[nt]);
      }
    const int qloc = w * 16 + quad * 4;  // + r
#pragma unroll
    for (int nt = 0; nt < 4; ++nt)
#pragma unroll
      for (int r = 0; r < 4; ++r) {
        float sv = s[nt][r] * 0.125f;
        if (kt == qt && (nt * 16 + fr) > (qloc + r)) sv = -1e30f;
        s[nt][r] = sv;
      }
    float al4[4];
#pragma unroll
    for (int r = 0; r < 4; ++r) {
      float m = fmaxf(fmaxf(s[0][r], s[1][r]), fmaxf(s[2][r], s[3][r]));
#pragma unroll
      for (int off = 1; off < 16; off <<= 1) m = fmaxf(m, __shfl_xor(m, off));
      const float mn = fmaxf(m_r[r], m);
      al4[r] = expf(m_r[r] - mn);
      m_r[r] = mn;
    }
    float pmat[4][4], ls4[4];
#pragma unroll
    for (int r = 0; r < 4; ++r) ls4[r] = 0.f;
#pragma unroll
    for (int nt = 0; nt < 4; ++nt)
#pragma unroll
      for (int r = 0; r < 4; ++r) {
        const float p = expf(s[nt][r] - m_r[r]);
        pmat[nt][r] = p;
        ls4[r] += p;
      }
#pragma unroll
    for (int r = 0; r < 4; ++r) {
      float l = ls4[r];
#pragma unroll
      for (int off = 1; off < 16; off <<= 1) l += __shfl_xor(l, off);
      l_r[r] = l_r[r] * al4[r] + l;
      o[0][r] *= al4[r]; o[1][r] *= al4[r]; o[2][r] *= al4[r]; o[3][r] *= al4[r];
    }
    bf16* Pw0 = QP0 + w * 1024;       // per-wave region: no block barrier
    bf16* Pw1 = QP1 + w * 1024;
#pragma unroll
    for (int nt = 0; nt < 4; ++nt)
#pragma unroll
      for (int r = 0; r < 4; ++r) {
        const float p = pmat[nt][r];
        bf16 hh2 = (bf16)p;
        Pw0[swz(quad * 4 + r, nt * 16 + fr)] = hh2;
        Pw1[swz(quad * 4 + r, nt * 16 + fr)] = (bf16)(p - (float)hh2);
      }
    __builtin_amdgcn_sched_barrier(0);  // keep P writes before P reads
#pragma unroll
    for (int kk = 0; kk < 2; ++kk) {
      bf16x8 aPh = *(const bf16x8*)&Pw0[swz(fr, kk * 32 + quad * 8)];
      bf16x8 aPl = *(const bf16x8*)&Pw1[swz(fr, kk * 32 + quad * 8)];
#pragma unroll
      for (int ct = 0; ct < 4; ++ct) {
        bf16x8 bVh = *(const bf16x8*)&Vh[swz(ct * 16 + fr, kk * 32 + quad * 8)];
        bf16x8 bVl = *(const bf16x8*)&Vl[swz(ct * 16 + fr, kk * 32 + quad * 8)];
        o[ct] = mfma16(aPh, bVh, o[ct]);
        o[ct] = mfma16(aPl, bVh, o[ct]);
        o[ct] = mfma16(aPh, bVl, o[ct]);
      }
    }
  }
  const int b_ = bhid >> 4, h_ = bhid & 15;
#pragma unroll
  for (int ct = 0; ct < 4; ++ct)
#pragma unroll
    for (int r = 0; r < 4; ++r) {
      const int tokn = b_ * SEQ + qt * 64 + w * 16 + quad * 4 + r;
      const int col = h_ * 64 + ct * 16 + fr;
      const float val = o[ct][r] / l_r[r];
      bf16 hh3 = (bf16)val;
      oh[(long)tokn * D_MODEL + col] = hh3;
      ol[(long)tokn * D_MODEL + col] = (bf16)(val - (float)hh3);
    }
}

// ---------------------------------------------------------------------------
// Proj GEMM (split) + bias + residual -> d_out fp32 (= x1)
// ---------------------------------------------------------------------------
__global__ __launch_bounds__(256, 3) void k_gemm_proj(
    const bf16* __restrict__ Ah, const bf16* __restrict__ Al,
    const bf16* __restrict__ Bh, const bf16* __restrict__ Bl,
    const float* __restrict__ bproj, const float* __restrict__ xin,
    float* __restrict__ out)
{
  __shared__ __align__(16) bf16 As[3 * 128 * 32];
  __shared__ __align__(16) bf16 Bs[3 * 128 * 32];
  const int tid = threadIdx.x, lane = tid & 63, w = tid >> 6;
  const int fr = lane & 15, quad = lane >> 4;
  const int wm = w >> 1, wn = w & 1;
  const int m0 = blockIdx.y * 128, n0 = blockIdx.x * 128;
  const int lrow = w * 16 + (lane >> 2), colk = (lane & 3) * 8;
  long aOff0 = (long)(m0 + lrow) * D_MODEL + colk;
  long aOff1 = aOff0 + 64L * D_MODEL;
  long bOff0 = (long)(n0 + lrow) * D_MODEL + colk;
  long bOff1 = bOff0 + 64L * D_MODEL;
  f32x4 acc[4][4];
  f32x4 zv = {0.f, 0.f, 0.f, 0.f};
#pragma unroll
  for (int i = 0; i < 4; ++i)
#pragma unroll
    for (int j = 0; j < 4; ++j) acc[i][j] = zv;
  gemm_core<true>(Ah, Al, Bh, Bl, aOff0, aOff1, bOff0, bOff1, D_MODEL, As, Bs, acc);
#pragma unroll
  for (int mi = 0; mi < 4; ++mi)
#pragma unroll
    for (int ni = 0; ni < 4; ++ni) {
      const int col = n0 + wn * 64 + ni * 16 + fr;
#pragma unroll
      for (int r = 0; r < 4; ++r) {
        const int row = m0 + wm * 64 + mi * 16 + quad * 4 + r;
        out[(long)row * D_MODEL + col] =
            acc[mi][ni][r] + bproj[col] + xin[(long)row * D_MODEL + col];
      }
    }
}

// ---------------------------------------------------------------------------
// Router: own fp32 LN of x1, fp32 logits, softmax, strict top-2.
// ---------------------------------------------------------------------------
__global__ __launch_bounds__(256) void k_router(
    const float* __restrict__ x1, const float* __restrict__ g,
    const float* __restrict__ b, const float* __restrict__ wr,
    int2* __restrict__ topi, float2* __restrict__ topg,
    float* __restrict__ pbuf)
{
  const int tok = blockIdx.x, tid = threadIdx.x;
  const float4 v = ((const float4*)(x1 + (long)tok * D_MODEL))[tid];
  float s  = v.x + v.y + v.z + v.w;
  float s2 = v.x * v.x + v.y * v.y + v.z * v.z + v.w * v.w;
#pragma unroll
  for (int off = 1; off < 64; off <<= 1) {
    s  += __shfl_xor(s, off);
    s2 += __shfl_xor(s2, off);
  }
  __shared__ float red[8];
  __shared__ float lr[4][8];
  if ((tid & 63) == 0) { red[tid >> 6] = s; red[4 + (tid >> 6)] = s2; }
  __syncthreads();
  s  = red[0] + red[1] + red[2] + red[3];
  s2 = red[4] + red[5] + red[6] + red[7];
  const float mu   = s * (1.0f / D_MODEL);
  const float var  = s2 * (1.0f / D_MODEL) - mu * mu;
  const float rstd = 1.0f / sqrtf(var + 1e-5f);
  const float4 gg = ((const float4*)g)[tid];
  const float4 bb = ((const float4*)b)[tid];
  float n4[4];
  n4[0] = (v.x - mu) * rstd * gg.x + bb.x;
  n4[1] = (v.y - mu) * rstd * gg.y + bb.y;
  n4[2] = (v.z - mu) * rstd * gg.z + bb.z;
  n4[3] = (v.w - mu) * rstd * gg.w + bb.w;
  float part[8];
#pragma unroll
  for (int e = 0; e < 8; ++e) part[e] = 0.f;
  const float* wrow = wr + (long)tid * 4 * 8;
#pragma unroll
  for (int c = 0; c < 4; ++c)
#pragma unroll
    for (int e = 0; e < 8; ++e) part[e] += n4[c] * wrow[c * 8 + e];
#pragma unroll
  for (int off = 1; off < 64; off <<= 1)
#pragma unroll
    for (int e = 0; e < 8; ++e) part[e] += __shfl_xor(part[e], off);
  if ((tid & 63) == 0)
#pragma unroll
    for (int e = 0; e < 8; ++e) lr[tid >> 6][e] = part[e];
  __syncthreads();
  if (tid == 0) {
    float lg[8];
#pragma unroll
    for (int e = 0; e < 8; ++e) lg[e] = lr[0][e] + lr[1][e] + lr[2][e] + lr[3][e];
    float mx = lg[0];
#pragma unroll
    for (int e = 1; e < 8; ++e) mx = fmaxf(mx, lg[e]);
    float pe[8], ssum = 0.f;
#pragma unroll
    for (int e = 0; e < 8; ++e) { pe[e] = expf(lg[e] - mx); ssum += pe[e]; }
    const float inv = 1.0f / ssum;
    int i1 = -1, i2 = -1;
    float v1 = -1.f, v2 = -1.f;
#pragma unroll
    for (int e = 0; e < 8; ++e) {
      const float p = pe[e] * inv;
      pbuf[(long)tok * 8 + e] = p;
      if (p > v1)      { v2 = v1; i2 = i1; v1 = p; i1 = e; }
      else if (p > v2) { v2 = p; i2 = e; }
    }
    const float wsum = v1 + v2;
    topi[tok] = make_int2(i1, i2);
    topg[tok] = make_float2(v1 / wsum, v2 / wsum);
  }
}

// ---------------------------------------------------------------------------
// Scatter: build per-expert token lists + per-token ranks (pos).
// ---------------------------------------------------------------------------
__global__ __launch_bounds__(256) void k_scatter(
    const int2* __restrict__ topi,
    int* __restrict__ ecnt, int* __restrict__ perm, int2* __restrict__ pos)
{
  __shared__ int hcnt[NEXP];
  __shared__ int hbase[NEXP];
  const int tid = threadIdx.x;
  const int tok = blockIdx.x * 256 + tid;
  if (tid < NEXP) hcnt[tid] = 0;
  __syncthreads();
  const int2 ti = topi[tok];
  const int r1 = atomicAdd(&hcnt[ti.x], 1);
  const int r2 = atomicAdd(&hcnt[ti.y], 1);
  __syncthreads();
  if (tid < NEXP) hbase[tid] = atomicAdd(&ecnt[tid], hcnt[tid]);
  __syncthreads();
  const int p1 = hbase[ti.x] + r1;
  perm[ti.x * NTOK + p1] = tok;
  const int p2 = hbase[ti.y] + r2;
  perm[ti.y * NTOK + p2] = tok;
  pos[tok] = make_int2(p1, p2);
}

// ---------------------------------------------------------------------------
// Finalize: reduce pbuf -> psum, compute eoff + aux loss.
// ---------------------------------------------------------------------------
__global__ __launch_bounds__(256) void k_finalize(
    const int* __restrict__ ecnt, const float* __restrict__ pbuf,
    int* __restrict__ eoff, float* __restrict__ aux_out)
{
  __shared__ float partial[256];
  const int tid = threadIdx.x;
  const int e = tid & 7, i0 = tid >> 3;
  float sum = 0.f;
  for (int i = i0; i < NTOK; i += 32) sum += pbuf[(long)i * 8 + e];
  partial[tid] = sum;
  __syncthreads();
  if (tid < 8) {
    float ps = 0.f;
#pragma unroll
    for (int j = 0; j < 32; ++j) ps += partial[j * 8 + tid];
    partial[tid] = ps;   // psum[e]
  }
  __syncthreads();
  if (tid == 0) {
    int off = 0;
    float aux = 0.f;
    for (int e2 = 0; e2 < 8; ++e2) {
      eoff[e2] = off;
      off += (ecnt[e2] + 127) & ~127;
      aux += ((float)ecnt[e2] * (1.0f / (NTOK * 2.0f))) * (partial[e2] * (1.0f / NTOK));
    }
    aux_out[0] = 8.0f * aux;
  }
}

// ---------------------------------------------------------------------------
// FFN1: gathered ln2 rows @ w1T[e] + b1 -> exact GELU -> h (bf16)
// ---------------------------------------------------------------------------
__global__ __launch_bounds__(256, 3) void k_gemm_ffn1(
    const bf16* __restrict__ A, const bf16* __restrict__ w1t,
    const float* __restrict__ b1, const int* __restrict__ ecnt,
    const int* __restrict__ eoff, const int* __restrict__ perm,
    bf16* __restrict__ h)
{
  const int e = blockIdx.y >> 5, mt = blockIdx.y & 31;
  const int cnt = ecnt[e];
  if (mt * 128 >= cnt) return;
  __shared__ __align__(16) bf16 As[3 * 128 * 32];
  __shared__ __align__(16) bf16 Bs[3 * 128 * 32];
  const int tid = threadIdx.x, lane = tid & 63, w = tid >> 6;
  const int fr = lane & 15, quad = lane >> 4;
  const int wm = w >> 1, wn = w & 1;
  const int n0 = blockIdx.x * 128;
  const int lrow = w * 16 + (lane >> 2), colk = (lane & 3) * 8;
  int i0 = mt * 128 + lrow;
  int i1 = i0 + 64;
  i0 = min(i0, cnt - 1);
  i1 = min(i1, cnt - 1);
  const int* pe = perm + e * NTOK;
  long aOff0 = (long)pe[i0] * D_MODEL + colk;
  long aOff1 = (long)pe[i1] * D_MODEL + colk;
  const bf16* B = w1t + (long)e * DFF * D_MODEL;
  long bOff0 = (long)(n0 + lrow) * D_MODEL + colk;
  long bOff1 = bOff0 + 64L * D_MODEL;
  f32x4 acc[4][4];
  f32x4 zv = {0.f, 0.f, 0.f, 0.f};
#pragma unroll
  for (int i = 0; i < 4; ++i)
#pragma unroll
    for (int j = 0; j < 4; ++j) acc[i][j] = zv;
  gemm_core<false>(A, A, B, B, aOff0, aOff1, bOff0, bOff1, D_MODEL, As, Bs, acc);
  const int hbase = eoff[e] + mt * 128;
#pragma unroll
  for (int mi = 0; mi < 4; ++mi)
#pragma unroll
    for (int ni = 0; ni < 4; ++ni) {
      const int col = n0 + wn * 64 + ni * 16 + fr;
#pragma unroll
      for (int r = 0; r < 4; ++r) {
        const int irow = wm * 64 + mi * 16 + quad * 4 + r;
        const float vv = acc[mi][ni][r] + b1[e * DFF + col];
        const float ge = 0.5f * vv * (1.0f + erff(vv * 0.70710678118654752f));
        h[(long)(hbase + irow) * DFF + col] = (bf16)ge;
      }
    }
}

// ---------------------------------------------------------------------------
// FFN2 (split-K=2 via blockIdx.z): h rows @ w2T[e] halves -> fp32 partials in
// ybuf[z] (plain coalesced stores; bias folded into z==0 partial)
// ---------------------------------------------------------------------------
__global__ __launch_bounds__(256, 3) void k_gemm_ffn2(
    const bf16* __restrict__ hbuf, const bf16* __restrict__ w2t,
    const float* __restrict__ b2, const int* __restrict__ ecnt,
    const int* __restrict__ eoff, float* __restrict__ ybuf)
{
  const int e = blockIdx.y >> 5, mt = blockIdx.y & 31;
  const int cnt = ecnt[e];
  if (mt * 128 >= cnt) return;
  __shared__ __align__(16) bf16 As[3 * 128 * 32];
  __shared__ __align__(16) bf16 Bs[3 * 128 * 32];
  const int tid = threadIdx.x, lane = tid & 63, w = tid >> 6;
  const int fr = lane & 15, quad = lane >> 4;
  const int wm = w >> 1, wn = w & 1;
  const int n0 = blockIdx.x * 128;
  const int z = blockIdx.z;
  const long kOff = (long)z * (DFF / 2);
  const int lrow = w * 16 + (lane >> 2), colk = (lane & 3) * 8;
  const int rbase = eoff[e] + mt * 128;
  const bf16* A = hbuf + (long)rbase * DFF;
  long aOff0 = (long)lrow * DFF + colk + kOff;
  long aOff1 = aOff0 + 64L * DFF;
  const bf16* B = w2t + (long)e * D_MODEL * DFF;
  long bOff0 = (long)(n0 + lrow) * DFF + colk + kOff;
  long bOff1 = bOff0 + 64L * DFF;
  f32x4 acc[4][4];
  f32x4 zv = {0.f, 0.f, 0.f, 0.f};
#pragma unroll
  for (int i = 0; i < 4; ++i)
#pragma unroll
    for (int j = 0; j < 4; ++j) acc[i][j] = zv;
  gemm_core<false>(A, A, B, B, aOff0, aOff1, bOff0, bOff1, DFF / 2, As, Bs, acc);
  float* yb = ybuf + (long)z * YSTRIDE;
#pragma unroll
  for (int mi = 0; mi < 4; ++mi)
#pragma unroll
    for (int ni = 0; ni < 4; ++ni) {
      const int col = n0 + wn * 64 + ni * 16 + fr;
      const float bias = (z == 0) ? b2[e * D_MODEL + col] : 0.0f;
#pragma unroll
      for (int r = 0; r < 4; ++r) {
        const int irow = wm * 64 + mi * 16 + quad * 4 + r;
        yb[(long)(rbase + irow) * D_MODEL + col] = acc[mi][ni][r] + bias;
      }
    }
}

// ---------------------------------------------------------------------------
// Combine: out[tok] += g1*(y0[row1]+y1[row1]) + g2*(y0[row2]+y1[row2])
// ---------------------------------------------------------------------------
__global__ __launch_bounds__(256) void k_combine(
    const int2* __restrict__ topi, const float2* __restrict__ topg,
    const int2* __restrict__ pos, const int* __restrict__ eoff,
    const float* __restrict__ ybuf, float* __restrict__ out)
{
  const int tok = blockIdx.x, tid = threadIdx.x;
  const int2 ti = topi[tok];
  const int2 pp = pos[tok];
  const float2 tg = topg[tok];
  const long r1 = (long)eoff[ti.x] + pp.x;
  const long r2 = (long)eoff[ti.y] + pp.y;
  const float4 y1a = ((const float4*)(ybuf + r1 * D_MODEL))[tid];
  const float4 y1b = ((const float4*)(ybuf + YSTRIDE + r1 * D_MODEL))[tid];
  const float4 y2a = ((const float4*)(ybuf + r2 * D_MODEL))[tid];
  const float4 y2b = ((const float4*)(ybuf + YSTRIDE + r2 * D_MODEL))[tid];
  float4* po = (float4*)(out + (long)tok * D_MODEL) + tid;
  float4 o = *po;
  o.x += tg.x * (y1a.x + y1b.x) + tg.y * (y2a.x + y2b.x);
  o.y += tg.x * (y1a.y + y1b.y) + tg.y * (y2a.y + y2b.y);
  o.z += tg.x * (y1a.z + y1b.z) + tg.y * (y2a.z + y2b.z);
  o.w += tg.x * (y1a.w + y1b.w) + tg.y * (y2a.w + y2b.w);
  *po = o;
}

// ---------------------------------------------------------------------------
extern "C" void kernel_launch(void* const* d_in, const int* in_sizes, int n_in,
                              void* d_out, int out_size, void* d_ws, size_t ws_size,
                              hipStream_t stream) {
  const float* x     = (const float*)d_in[0];
  // d_in[1] = mask (causal structure reproduced in-kernel)
  const float* ln1g  = (const float*)d_in[2];
  const float* ln1b  = (const float*)d_in[3];
  const float* wqkv  = (const float*)d_in[4];
  const float* wproj = (const float*)d_in[5];
  const float* bproj = (const float*)d_in[6];
  const float* ln2g  = (const float*)d_in[7];
  const float* ln2b  = (const float*)d_in[8];
  const float* wrout = (const float*)d_in[9];
  const float* w1    = (const float*)d_in[10];
  const float* b1    = (const float*)d_in[11];
  const float* w2    = (const float*)d_in[12];
  const float* b2    = (const float*)d_in[13];
  float* out = (float*)d_out;

  char* p = (char*)d_ws;
  auto alloc = [&](size_t n) { char* r = p; p += (n + 255) & ~(size_t)255; return r; };

  bf16* wqkvT_h = (bf16*)alloc(3072L * 1024 * 2);
  bf16* wqkvT_l = (bf16*)alloc(3072L * 1024 * 2);
  bf16* wprojT_h = (bf16*)alloc(1024L * 1024 * 2);
  bf16* wprojT_l = (bf16*)alloc(1024L * 1024 * 2);
  bf16* w1T = (bf16*)alloc(8L * 4096 * 1024 * 2);
  bf16* w2T = (bf16*)alloc(8L * 1024 * 4096 * 2);
  bf16* ln_h = (bf16*)alloc(4096L * 1024 * 2);  // ln1 then reused for ln2
  bf16* ln_l = (bf16*)alloc(4096L * 1024 * 2);
  bf16* attn_h = (bf16*)alloc(4096L * 1024 * 2);
  bf16* attn_l = (bf16*)alloc(4096L * 1024 * 2);
  int*   perm  = (int*)alloc(8L * 4096 * 4);
  int2*  topi  = (int2*)alloc(4096L * 8);
  float2* topg = (float2*)alloc(4096L * 8);
  int2*  pos   = (int2*)alloc(4096L * 8);
  float* pbuf  = (float*)alloc(4096L * 8 * 4);
  char*  ctrl  = alloc(256);                 // ecnt[8] | eoff[8]
  int*   ecnt  = (int*)ctrl;
  int*   eoff  = (int*)(ctrl + 64);
  float* ybuf  = (float*)alloc(2L * YSTRIDE * 4);      // fp32 FFN2 split-K partials
  // big overlay region: [qkv fp32 48MB | rope/vT bufs 48MB] then h (73MB)
  char* big = alloc(100663296);
  float* qkvf = (float*)big;                           // 4096*3072*4
  bf16* qh  = (bf16*)(big + 50331648);
  bf16* ql  = qh + 4194304;
  bf16* kh  = ql + 4194304;
  bf16* kl  = kh + 4194304;
  bf16* vth = kl + 4194304;                            // [bh][64][SEQ] hi
  bf16* vtl = vth + 4194304;                           // [bh][64][SEQ] lo
  bf16* hbuf = (bf16*)big;                             // 9216*4096*2, after attn

  dim3 blk(256);

  // 1) weight transpose + cast
  k_transpose_cast<<<dim3(3072 / 32, 1024 / 32, 1), blk, 0, stream>>>(wqkv, wqkvT_h, wqkvT_l, 1024, 3072);
  k_transpose_cast<<<dim3(1024 / 32, 1024 / 32, 1), blk, 0, stream>>>(wproj, wprojT_h, wprojT_l, 1024, 1024);
  k_transpose_cast<<<dim3(4096 / 32, 1024 / 32, 8), blk, 0, stream>>>(w1, w1T, nullptr, 1024, 4096);
  k_transpose_cast<<<dim3(1024 / 32, 4096 / 32, 8), blk, 0, stream>>>(w2, w2T, nullptr, 4096, 1024);
  hipMemsetAsync(ctrl, 0, 256, stream);

  // 2) attention path (split precision)
  k_layernorm<<<4096, blk, 0, stream>>>(x, ln1g, ln1b, ln_h, ln_l);
  k_gemm_qkv<<<dim3(24, 32), blk, 0, stream>>>(ln_h, ln_l, wqkvT_h, wqkvT_l, qkvf);
  k_rope<<<4096, blk, 0, stream>>>(qkvf, qh, ql, kh, kl);
  k_vtrans<<<dim3(SEQ / 32, 2, 64), blk, 0, stream>>>(qkvf, vth, vtl);
  k_flash<<<dim3(16, 64), blk, 0, stream>>>(qh, ql, kh, kl, vth, vtl, attn_h, attn_l);
  k_gemm_proj<<<dim3(8, 32), blk, 0, stream>>>(attn_h, attn_l, wprojT_h, wprojT_l, bproj, x, out);

  // 3) MoE
  k_layernorm<<<4096, blk, 0, stream>>>(out, ln2g, ln2b, ln_h, nullptr);
  k_router<<<4096, blk, 0, stream>>>(out, ln2g, ln2b, wrout, topi, topg, pbuf);
  k_scatter<<<16, blk, 0, stream>>>(topi, ecnt, perm, pos);
  k_finalize<<<1, blk, 0, stream>>>(ecnt, pbuf, eoff, out + 4194304);
  k_gemm_ffn1<<<dim3(32, 256), blk, 0, stream>>>(ln_h, w1T, b1, ecnt, eoff, perm, hbuf);
  k_gemm_ffn2<<<dim3(8, 256, 2), blk, 0, stream>>>(hbuf, w2T, b2, ecnt, eoff, ybuf);
  k_combine<<<4096, blk, 0, stream>>>(topi, topg, pos, eoff, ybuf, out);
}